// Round 16
// baseline (954.610 us; speedup 1.0000x reference)
//
#include <hip/hip_runtime.h>
#include <hip/hip_bf16.h>
#include <math.h>

// ---------------------------------------------------------------------------
// GATEmbedding. CNN: conv1 fused into conv2 (conv12_k, R=2, SGPR conv1
// weights), conv3/conv4 implicit-GEMM split-bf16 MFMA (NFR=4, DMA staging).
// Entire GAT section (Wh + softmax + batt + h@Wh + Wh2 + final heads) fused
// into ONE kernel (gat_all_k, 1 block per batch, intermediates in LDS).
// 6 launches total. Activations as separate hi/lo bf16 planes.
// Outputs (flat): slices_hidden(8,128)@0, image_feature_second(8,256)@1024,
//   prediction(8,2)@3072, slices_out(8,2)@3088, batch_attention(8,19,19)@3104
// ---------------------------------------------------------------------------

#define NEG_INF_F (-9.0e15f)

typedef __attribute__((ext_vector_type(8))) short frag8;
typedef __attribute__((ext_vector_type(4))) float f32x4;
typedef const __attribute__((address_space(1))) void GasV;
typedef __attribute__((address_space(3))) void LasV;

__device__ __forceinline__ unsigned short f2bf(float f) {
  union { float f; unsigned u; } v; v.f = f;
  unsigned r = v.u + 0x7fffu + ((v.u >> 16) & 1u);   // RNE
  return (unsigned short)(r >> 16);
}
__device__ __forceinline__ float bf2f(unsigned short u) {
  union { unsigned u; float f; } v; v.u = ((unsigned)u) << 16;
  return v.f;
}

// LDS 16B-slot swizzle so a ds_read_b128 16-lane phase is <=2-way per bank.
template <int C>
__device__ __forceinline__ int swz(int slot, int px) {
  if constexpr (C == 32) return slot ^ ((px >> 1) & 3);
  else return slot ^ (px & 7);   // C=64: full; C=128: low 3 slot bits
}

// ---- B-prep device body: pack w[oc][c][3][3] f32 into per-lane fragments ---
template <int C, int OC>
__device__ __forceinline__ void bprep_dev(const float* __restrict__ w,
                                          unsigned short* __restrict__ bp, int idx) {
  constexpr int CS = C / 32, NSTEP = 9 * CS, NG = (OC / 64) * 2;
  if (idx >= NG * NSTEP * 64 * 4) return;
  int q = idx & 3;
  int lane = (idx >> 2) & 63;
  int gs = idx >> 8;
  int s = gs % NSTEP;
  int g = gs / NSTEP;
  int off = s / CS, c0 = (s % CS) * 32;
  int l15 = lane & 15, l4 = lane >> 4;
  int oc = (g >> 1) * 64 + (g & 1) * 32 + (q & 1) * 16 + l15;
  int kc = c0 + l4 * 8;
  unsigned short o8[8];
#pragma unroll
  for (int j = 0; j < 8; ++j) {
    float v = w[((size_t)oc * C + kc + j) * 9 + off];
    unsigned short h = f2bf(v);
    o8[j] = (q < 2) ? h : f2bf(v - bf2f(h));
  }
  *(uint4*)(bp + (size_t)idx * 8) = *(uint4*)o8;
}

// ---- prep: adjacency (block 0) + bprep2/3/4 in one launch ------------------
__global__ __launch_bounds__(256) void prep_k(
    const float* __restrict__ w2, const float* __restrict__ w3,
    const float* __restrict__ w4, unsigned short* __restrict__ bp2,
    unsigned short* __restrict__ bp3, unsigned short* __restrict__ bp4,
    float* __restrict__ adj) {
  const int bx = blockIdx.x, t = threadIdx.x;
  if (bx == 0) {
    __shared__ float A[19][19];
    for (int e = t; e < 361; e += 256) {
      int i = e / 19, j = e % 19;
      float v = 0.f;
      const int MIDN = 3, N = 19, MID = 10, WIDTH = 2;
      if (i < MIDN) {
        if (i == MIDN - 1) { if (j > MIDN - 1) v = 1.f; }
        else if (j == i + 1 || (j > MID - (i + 1) * WIDTH && j < MID + (i + 1) * WIDTH)) v = 1.f;
      } else {
        if (i == MIDN) { if (j == MIDN + 1) v = 1.f; }
        else if (i == N - 1) { if (j == N - 2) v = 1.f; }
        else if (j == i - 1 || j == i + 1) v = 1.f;
      }
      if (i == j) v += 1.f;
      A[i][j] = v;
    }
    __syncthreads();
    for (int e = t; e < 361; e += 256) {
      int i = e / 19;
      float rs = 0.f;
      for (int j = 0; j < 19; ++j) rs += A[i][j];
      float rinv = rs > 0.f ? 1.f / rs : 0.f;
      adj[e] = A[i][e % 19] * rinv;
    }
  } else if (bx <= 18) {
    bprep_dev<32, 64>(w2, bp2, (bx - 1) * 256 + t);
  } else if (bx <= 90) {
    bprep_dev<64, 128>(w3, bp3, (bx - 19) * 256 + t);
  } else {
    bprep_dev<128, 128>(w4, bp4, (bx - 91) * 256 + t);
  }
}

// ---- conv12: conv1 (1->32, SGPR weights) in-LDS, conv2 MFMA (32->64), R=2 --
__global__ __launch_bounds__(256) void conv12_k(
    const float* __restrict__ in, const float* __restrict__ w1,
    const float* __restrict__ b1, const unsigned short* __restrict__ bprep,
    const float* __restrict__ bias,
    unsigned short* __restrict__ outH, unsigned short* __restrict__ outL) {
  constexpr int C = 32, OC = 64, W = 64;
  constexpr int PW = W + 2, OH = W / 2;
  constexpr int NSTEP = 9;
  __shared__ float sr[10][132];
  __shared__ __align__(16) unsigned short patchH[4 * PW * C];
  __shared__ __align__(16) unsigned short patchL[4 * PW * C];
  const int t = threadIdx.x;
  const int img = blockIdx.z;
  const int y0 = blockIdx.x * 2;
  const int pr0 = blockIdx.x;
  const size_t out_img = (size_t)img * 34 * 34 * OC;

  const float* ip = in + (size_t)img * 16384;
  for (int e = t; e < 10 * 130; e += 256) {
    int s = e / 130, c = e - s * 130;
    int y = 2 * y0 - 3 + s, x = c - 1;
    sr[s][c] = (y >= 0 && y < 128 && x >= 0 && x < 128) ? ip[y * 128 + x] : 0.f;
  }
  __syncthreads();

  {
    const int px = t & 63, ocg = t >> 6;
    const int gx = px + 1;
    const int ssl = swz<C>(ocg, gx);
    const int ocg_s = __builtin_amdgcn_readfirstlane(ocg);
    const float* wg = w1 + ocg_s * 72;
    const float* bg = b1 + ocg_s * 8;
#pragma unroll
    for (int r = 0; r < 4; ++r) {
      int rp = y0 + r;
      unsigned short h8[8], l8[8];
      if (rp == 0 || rp == 65) {
#pragma unroll
        for (int i = 0; i < 8; ++i) { h8[i] = 0; l8[i] = 0; }
      } else {
        float v[4][4];
#pragma unroll
        for (int dy = 0; dy < 4; ++dy)
#pragma unroll
          for (int dx = 0; dx < 4; ++dx) v[dy][dx] = sr[2 * r + dy][2 * px + dx];
#pragma unroll
        for (int i = 0; i < 8; ++i) {
          float m = -1e30f;
#pragma unroll
          for (int dy = 0; dy < 2; ++dy)
#pragma unroll
            for (int dx = 0; dx < 2; ++dx) {
              float a = 0.f;
#pragma unroll
              for (int ky = 0; ky < 3; ++ky)
#pragma unroll
                for (int kx = 0; kx < 3; ++kx)
                  a = fmaf(v[dy + ky][dx + kx], wg[i * 9 + ky * 3 + kx], a);
              m = fmaxf(m, a);
            }
          float o = fmaxf(m + bg[i], 0.f);
          h8[i] = f2bf(o);
          l8[i] = f2bf(o - bf2f(h8[i]));
        }
      }
      int o = (r * PW + gx) * C + ssl * 8;
      *(uint4*)(patchH + o) = *(uint4*)h8;
      *(uint4*)(patchL + o) = *(uint4*)l8;
    }
    if (t < 64) {
      int r = t >> 4, rem = t & 15;
      int side = rem >> 3, rem2 = rem & 7;
      int plane = rem2 >> 2, q = rem2 & 3;
      const uint4 z4 = {0u, 0u, 0u, 0u};
      unsigned short* dst = plane ? patchL : patchH;
      *(uint4*)(dst + (r * PW + side * (PW - 1)) * C + q * 8) = z4;
    }
  }
  __syncthreads();

  const int lane = t & 63, wid = t >> 6;
  const int wm = wid >> 1, wn = wid & 1;
  const int l15 = lane & 15, l4 = lane >> 4;
  const int nbase = wn * 32;

  f32x4 acc[4][2] = {};
  const unsigned short* bpw = bprep + ((size_t)wn * NSTEP * 64 + lane) * 32;

  for (int s = 0; s < NSTEP; ++s) {
    const frag8* bp = (const frag8*)(bpw + (size_t)s * 2048);
    frag8 bh0 = bp[0], bh1 = bp[1], bl0 = bp[2], bl1 = bp[3];
    const int ky = s / 3, kx = s - ky * 3;
    frag8 ah[4], al[4];
#pragma unroll
    for (int f = 0; f < 4; ++f) {
      int m0 = wm * 32 + (f & 1) * 16 + (f >> 1) * 64;
      int ry = m0 / W + ky;
      int px = (m0 % W) + l15 + kx;
      size_t o = ((size_t)ry * PW + px) * C + swz<C>(l4, px) * 8;
      ah[f] = *(const frag8*)(patchH + o);
      al[f] = *(const frag8*)(patchL + o);
    }
#pragma unroll
    for (int f = 0; f < 4; ++f) {
      acc[f][0] = __builtin_amdgcn_mfma_f32_16x16x32_bf16(ah[f], bh0, acc[f][0], 0, 0, 0);
      acc[f][0] = __builtin_amdgcn_mfma_f32_16x16x32_bf16(al[f], bh0, acc[f][0], 0, 0, 0);
      acc[f][0] = __builtin_amdgcn_mfma_f32_16x16x32_bf16(ah[f], bl0, acc[f][0], 0, 0, 0);
      acc[f][1] = __builtin_amdgcn_mfma_f32_16x16x32_bf16(ah[f], bh1, acc[f][1], 0, 0, 0);
      acc[f][1] = __builtin_amdgcn_mfma_f32_16x16x32_bf16(al[f], bh1, acc[f][1], 0, 0, 0);
      acc[f][1] = __builtin_amdgcn_mfma_f32_16x16x32_bf16(ah[f], bl1, acc[f][1], 0, 0, 0);
    }
  }

  float bb0 = bias[nbase + l15], bb1 = bias[nbase + 16 + l15];
#pragma unroll
  for (int pi = 0; pi < 2; ++pi) {
    const int fa = pi, fb = pi + 2;
    const int m0a = wm * 32 + fa * 16;
    const int prow = (y0 + m0a / W) >> 1;
    const int pxb = (m0a % W) >> 1;
#pragma unroll
    for (int n = 0; n < 2; ++n) {
      const float bb = n ? bb1 : bb0;
#pragma unroll
      for (int xp = 0; xp < 2; ++xp) {
        float v = fmaxf(fmaxf(acc[fa][n][2 * xp], acc[fa][n][2 * xp + 1]),
                        fmaxf(acc[fb][n][2 * xp], acc[fb][n][2 * xp + 1]));
        float vv = fmaxf(v + bb, 0.f);
        size_t idx = out_img + ((size_t)(prow + 1) * 34 + pxb + 2 * l4 + xp + 1) * OC +
                     nbase + n * 16 + l15;
        unsigned short h = f2bf(vv);
        outH[idx] = h;
        outL[idx] = f2bf(vv - bf2f(h));
      }
    }
  }

  const uint4 z4 = {0u, 0u, 0u, 0u};
  if (t < 32) {
    int side = (t >> 4) & 1, pl = (t >> 3) & 1, q = t & 7;
    unsigned short* dst = pl ? outL : outH;
    *(uint4*)(dst + out_img + ((size_t)(pr0 + 1) * 34 + side * 33) * OC + q * 8) = z4;
  }
  if (pr0 == 0)
    for (int e = t; e < 544; e += 256) {
      int pl = e >= 272, i = e - pl * 272;
      unsigned short* dst = pl ? outL : outH;
      *(uint4*)(dst + out_img + (size_t)i * 8) = z4;
    }
  if (pr0 + 1 == OH)
    for (int e = t; e < 544; e += 256) {
      int pl = e >= 272, i = e - pl * 272;
      unsigned short* dst = pl ? outL : outH;
      *(uint4*)(dst + out_img + (size_t)33 * 34 * OC + (size_t)i * 8) = z4;
    }
}

// ------- implicit-GEMM split-bf16 MFMA conv+relu+pool, plane hi/lo I/O ------
template <int C, int OC, int W, int R>
__global__ __launch_bounds__(256) void conv_mfma_k(
    const unsigned short* __restrict__ inH, const unsigned short* __restrict__ inL,
    const unsigned short* __restrict__ bprep, const float* __restrict__ bias,
    unsigned short* __restrict__ outH, unsigned short* __restrict__ outL) {
  constexpr int SL = C / 8;
  constexpr int PW = W + 2;
  constexpr int OW = W / 2, OH = W / 2;
  constexpr int PR = R / 2;
  constexpr int CS = C / 32;
  constexpr int NSTEP = 9 * CS;
  constexpr int M = R * W;
  constexpr int MF = M / 32;
  constexpr int E = (R + 2) * PW * SL;
  constexpr int EP = (E + 63) & ~63;
  __shared__ __align__(16) unsigned short patchH[(R + 2) * PW * C + 256];
  __shared__ __align__(16) unsigned short patchL[(R + 2) * PW * C + 256];
  const int t = threadIdx.x;
  const int img = blockIdx.z;
  const int y0 = blockIdx.x * R;
  const int pr0 = blockIdx.x * PR;
  const size_t in_img = (size_t)img * (W + 2) * (W + 2) * C;
  const size_t out_img = (size_t)img * (OW + 2) * (OW + 2) * OC;

  {
    const unsigned short* gH = inH + in_img + (size_t)y0 * PW * C;
    const unsigned short* gL = inL + in_img + (size_t)y0 * PW * C;
    for (int e0 = t; e0 < EP; e0 += 256) {
      int e = e0 < E ? e0 : E - 1;
      int row = e / (PW * SL);
      int rem = e - row * (PW * SL);
      int px = rem / SL, sl = rem & (SL - 1);
      int goff = row * PW * C + px * C + swz<C>(sl, px) * 8;
      int lbase = __builtin_amdgcn_readfirstlane(e0 & ~63) * 8;
      __builtin_amdgcn_global_load_lds((GasV*)(gH + goff), (LasV*)(patchH + lbase), 16, 0, 0);
      __builtin_amdgcn_global_load_lds((GasV*)(gL + goff), (LasV*)(patchL + lbase), 16, 0, 0);
    }
  }
  __syncthreads();

  const int lane = t & 63, wid = t >> 6;
  const int wm = wid >> 1, wn = wid & 1;
  const int l15 = lane & 15, l4 = lane >> 4;
  const int nbase = wn * 64;

  f32x4 acc[MF][4] = {};
  const unsigned short* bpw0 =
      bprep + (((size_t)(wn * 2 + 0) * NSTEP) * 64 + lane) * 32;
  const unsigned short* bpw1 =
      bprep + (((size_t)(wn * 2 + 1) * NSTEP) * 64 + lane) * 32;

  for (int s = 0; s < NSTEP; ++s) {
    const frag8* bp0 = (const frag8*)(bpw0 + (size_t)s * 2048);
    const frag8* bp1 = (const frag8*)(bpw1 + (size_t)s * 2048);
    frag8 bh0 = bp0[0], bh1 = bp0[1], bh2 = bp1[0], bh3 = bp1[1];
    frag8 bl0 = bp0[2], bl1 = bp0[3], bl2 = bp1[2], bl3 = bp1[3];
    const int off = s / CS, c0 = (s % CS) * 32;
    const int ky = off / 3, kx = off - ky * 3;
    const int slin = (c0 >> 3) + l4;
    frag8 ah[MF], al[MF];
#pragma unroll
    for (int f = 0; f < MF; ++f) {
      int m0 = wm * (M / 2) + f * 16;
      int ry = m0 / W + ky;
      int px = (m0 % W) + l15 + kx;
      size_t o = ((size_t)ry * PW + px) * C + swz<C>(slin, px) * 8;
      ah[f] = *(const frag8*)(patchH + o);
      al[f] = *(const frag8*)(patchL + o);
    }
#pragma unroll
    for (int f = 0; f < MF; ++f) {
      acc[f][0] = __builtin_amdgcn_mfma_f32_16x16x32_bf16(ah[f], bh0, acc[f][0], 0, 0, 0);
      acc[f][0] = __builtin_amdgcn_mfma_f32_16x16x32_bf16(al[f], bh0, acc[f][0], 0, 0, 0);
      acc[f][0] = __builtin_amdgcn_mfma_f32_16x16x32_bf16(ah[f], bl0, acc[f][0], 0, 0, 0);
      acc[f][1] = __builtin_amdgcn_mfma_f32_16x16x32_bf16(ah[f], bh1, acc[f][1], 0, 0, 0);
      acc[f][1] = __builtin_amdgcn_mfma_f32_16x16x32_bf16(al[f], bh1, acc[f][1], 0, 0, 0);
      acc[f][1] = __builtin_amdgcn_mfma_f32_16x16x32_bf16(ah[f], bl1, acc[f][1], 0, 0, 0);
      acc[f][2] = __builtin_amdgcn_mfma_f32_16x16x32_bf16(ah[f], bh2, acc[f][2], 0, 0, 0);
      acc[f][2] = __builtin_amdgcn_mfma_f32_16x16x32_bf16(al[f], bh2, acc[f][2], 0, 0, 0);
      acc[f][2] = __builtin_amdgcn_mfma_f32_16x16x32_bf16(ah[f], bl2, acc[f][2], 0, 0, 0);
      acc[f][3] = __builtin_amdgcn_mfma_f32_16x16x32_bf16(ah[f], bh3, acc[f][3], 0, 0, 0);
      acc[f][3] = __builtin_amdgcn_mfma_f32_16x16x32_bf16(al[f], bh3, acc[f][3], 0, 0, 0);
      acc[f][3] = __builtin_amdgcn_mfma_f32_16x16x32_bf16(ah[f], bl3, acc[f][3], 0, 0, 0);
    }
  }

  float bb[4];
#pragma unroll
  for (int n = 0; n < 4; ++n) bb[n] = bias[nbase + n * 16 + l15];
#pragma unroll
  for (int pi = 0; pi < MF / 2; ++pi) {
    const int fa = (W == 16) ? (pi * 2) : pi;
    const int fb = (W == 16) ? (pi * 2 + 1) : (pi + 2);
    const int m0a = wm * (M / 2) + fa * 16;
    const int prow = (y0 + m0a / W) >> 1;
    const int pxb = (m0a % W) >> 1;
#pragma unroll
    for (int n = 0; n < 4; ++n) {
#pragma unroll
      for (int xp = 0; xp < 2; ++xp) {
        float v = fmaxf(fmaxf(acc[fa][n][2 * xp], acc[fa][n][2 * xp + 1]),
                        fmaxf(acc[fb][n][2 * xp], acc[fb][n][2 * xp + 1]));
        float vv = fmaxf(v + bb[n], 0.f);
        size_t idx = out_img + ((size_t)(prow + 1) * (OW + 2) + pxb + 2 * l4 + xp + 1) * OC +
                     nbase + n * 16 + l15;
        unsigned short h = f2bf(vv);
        outH[idx] = h;
        outL[idx] = f2bf(vv - bf2f(h));
      }
    }
  }

  const uint4 z4 = {0u, 0u, 0u, 0u};
  if (t < PR * 64) {
    int r = t >> 6, rem = t & 63;
    int side = rem >> 5, pl = (rem >> 4) & 1, q = rem & 15;
    unsigned short* dst = pl ? outL : outH;
    *(uint4*)(dst + out_img + ((size_t)(pr0 + r + 1) * (OW + 2) + side * (OW + 1)) * OC +
              q * 8) = z4;
  }
  if (pr0 == 0)
    for (int e = t; e < (OW + 2) * 32; e += 256) {
      int pl = e >= (OW + 2) * 16, i = e - pl * (OW + 2) * 16;
      unsigned short* dst = pl ? outL : outH;
      *(uint4*)(dst + out_img + (size_t)(i >> 4) * OC + (i & 15) * 8) = z4;
    }
  if (pr0 + PR == OH)
    for (int e = t; e < (OW + 2) * 32; e += 256) {
      int pl = e >= (OW + 2) * 16, i = e - pl * (OW + 2) * 16;
      unsigned short* dst = pl ? outL : outH;
      *(uint4*)(dst + out_img + ((size_t)(OH + 1) * (OW + 2) + (i >> 4)) * OC +
                (i & 15) * 8) = z4;
    }
}

// ---------------- spatial mean (8x8 interior, hi/lo planes) + fc ------------
__global__ __launch_bounds__(128) void meanfc_k(
    const unsigned short* __restrict__ c4H, const unsigned short* __restrict__ c4L,
    const float* __restrict__ fcw, const float* __restrict__ fcb,
    float* __restrict__ feats, int img0) {
  int img = blockIdx.x, t = threadIdx.x;
  __shared__ float sM[128];
  const unsigned short* pH = c4H + (size_t)img * 12800;
  const unsigned short* pL = c4L + (size_t)img * 12800;
  float s0 = 0.f, s1 = 0.f;
  for (int pix = 0; pix < 64; pix += 2) {
    int py0 = pix >> 3, px0 = pix & 7;
    int py1 = (pix + 1) >> 3, px1 = (pix + 1) & 7;
    size_t i0 = ((size_t)(py0 + 1) * 10 + px0 + 1) * 128 + t;
    size_t i1 = ((size_t)(py1 + 1) * 10 + px1 + 1) * 128 + t;
    s0 += bf2f(pH[i0]) + bf2f(pL[i0]);
    s1 += bf2f(pH[i1]) + bf2f(pL[i1]);
  }
  sM[t] = (s0 + s1) * (1.f / 64.f);
  __syncthreads();
  float a0 = 0.f, a1 = 0.f, a2 = 0.f, a3 = 0.f;
  for (int c = 0; c < 128; c += 4) {
    a0 = fmaf(sM[c], fcw[c * 128 + t], a0);
    a1 = fmaf(sM[c + 1], fcw[(c + 1) * 128 + t], a1);
    a2 = fmaf(sM[c + 2], fcw[(c + 2) * 128 + t], a2);
    a3 = fmaf(sM[c + 3], fcw[(c + 3) * 128 + t], a3);
  }
  feats[(size_t)(img0 + img) * 128 + t] = fcb[t] + ((a0 + a1) + (a2 + a3));
}

// ---- gat_all: ENTIRE GAT per batch in one block -----------------------------
// Phase 1: Wh = slices@attW (LDS), f1/f2, slices_hidden/out.
// Phase 2: masked softmax (satt). Phase 3: batt + x=att@Wh+elu -> xb (global).
// Phase 4: Wh2 = x@outW (overlay on Wh LDS), o1/o2. Phase 5: final heads.
__global__ __launch_bounds__(256) void gat_all_k(
    const float* __restrict__ feats, const float* __restrict__ attW,
    const float* __restrict__ atta, const float* __restrict__ adj,
    const float* __restrict__ outW, const float* __restrict__ oa,
    const float* __restrict__ llw, const float* __restrict__ llb,
    const float* __restrict__ fcw, const float* __restrict__ fcb,
    const float* __restrict__ sfcw, const float* __restrict__ sfcb,
    float* __restrict__ xb, float* __restrict__ out) {
  const int b = blockIdx.x, t = threadIdx.x;
  __shared__ float sWh[152 * 64];      // phases 1-3; overlaid by Wh2 in 4-5
  __shared__ float satt[8][19][19];
  __shared__ float sfeat[16 * 128];
  __shared__ float sadj[361], sf1[152], sf2[152], shh[128];
  __shared__ float sA[19], sF[128], sG[256], so2[19];
  __shared__ float so1_0;
  float* sWh2 = sWh;                   // 19*128 overlay (after phase-3 sync)

  // ---- phase 0: stage feats rows + adj
  for (int e = t; e < 2048; e += 256) sfeat[e] = feats[(size_t)(b * 16) * 128 + e];
  for (int e = t; e < 361; e += 256) sadj[e] = adj[e];
  __syncthreads();

  // ---- phase 1: Wh (512 cols (k,h), 2 per thread), zero rows n<3
#pragma unroll
  for (int rep = 0; rep < 2; ++rep) {
    int col = t + rep * 256;
    int k = col >> 6, h = col & 63;
    const float* W = attW + (size_t)k * 8192 + h;
    for (int n = 0; n < 3; ++n) sWh[(k * 19 + n) * 64 + h] = 0.f;
    for (int n = 3; n < 19; ++n) {
      const float* s = sfeat + (n - 3) * 128;
      float a0 = 0.f, a1 = 0.f, a2 = 0.f, a3 = 0.f;
      for (int f = 0; f < 128; f += 4) {
        a0 = fmaf(s[f], W[f * 64], a0);
        a1 = fmaf(s[f + 1], W[(f + 1) * 64], a1);
        a2 = fmaf(s[f + 2], W[(f + 2) * 64], a2);
        a3 = fmaf(s[f + 3], W[(f + 3) * 64], a3);
      }
      sWh[(k * 19 + n) * 64 + h] = (a0 + a1) + (a2 + a3);
    }
  }
  // slices_hidden (independent): t<128
  if (t < 128) {
    float s = 0.f;
    for (int c = 0; c < 16; ++c) s += sfeat[c * 128 + t];
    s *= (1.f / 16.f);
    out[b * 128 + t] = s;
    shh[t] = s;
  }
  __syncthreads();
  // f1/f2 per row + slices_out
  if (t < 152) {
    int k = t / 19;
    const float* wr = sWh + t * 64;
    const float* a1p = atta + k * 128;
    const float* a2p = atta + k * 128 + 64;
    float p1 = 0.f, p2 = 0.f, q1 = 0.f, q2 = 0.f;
    for (int h = 0; h < 64; h += 2) {
      p1 = fmaf(wr[h], a1p[h], p1);
      q1 = fmaf(wr[h + 1], a1p[h + 1], q1);
      p2 = fmaf(wr[h], a2p[h], p2);
      q2 = fmaf(wr[h + 1], a2p[h + 1], q2);
    }
    sf1[t] = p1 + q1;
    sf2[t] = p2 + q2;
  }
  if (t >= 224 && t < 226) {
    int tt = t - 224;
    float a0 = 0.f, a1 = 0.f, a2 = 0.f, a3 = 0.f;
    for (int e = 0; e < 128; e += 4) {
      a0 = fmaf(shh[e], sfcw[e * 2 + tt], a0);
      a1 = fmaf(shh[e + 1], sfcw[(e + 1) * 2 + tt], a1);
      a2 = fmaf(shh[e + 2], sfcw[(e + 2) * 2 + tt], a2);
      a3 = fmaf(shh[e + 3], sfcw[(e + 3) * 2 + tt], a3);
    }
    out[3088 + b * 2 + tt] = sfcb[tt] + ((a0 + a1) + (a2 + a3));
  }
  __syncthreads();

  // ---- phase 2: masked softmax per (k,i)
  if (t < 152) {
    int k = t / 19, i = t % 19;
    float fi = sf1[t];
    float v[19];
    float mx = -1e30f;
#pragma unroll
    for (int j = 0; j < 19; ++j) {
      float e = fi + sf2[k * 19 + j];
      e = e >= 0.f ? e : 0.2f * e;
      e = sadj[i * 19 + j] > 0.f ? e : NEG_INF_F;
      v[j] = e;
      mx = fmaxf(mx, e);
    }
    float sum = 0.f;
#pragma unroll
    for (int j = 0; j < 19; ++j) { v[j] = expf(v[j] - mx); sum += v[j]; }
    float inv = 1.f / sum;
#pragma unroll
    for (int j = 0; j < 19; ++j) satt[k][i][j] = v[j] * inv;
  }
  __syncthreads();

  // ---- phase 3: batch_attention + x = att@Wh + elu -> xb (global, L2-hot)
  for (int e = t; e < 361; e += 256) {
    int i = e / 19, j = e - i * 19;
    float s = 0.f;
#pragma unroll
    for (int k = 0; k < 8; ++k) s += satt[k][i][j];
    out[3104 + b * 361 + e] = s * 0.125f;
  }
  {
    int h = t & 63, g = t >> 6;
    for (int row = g; row < 152; row += 4) {
      int k = row / 19, i = row - k * 19;
      const float* whp = sWh + (k * 19) * 64 + h;
      float s = 0.f;
#pragma unroll
      for (int j = 0; j < 19; ++j) s = fmaf(satt[k][i][j], whp[j * 64], s);
      xb[((size_t)b * 19 + i) * 512 + k * 64 + h] = s > 0.f ? s : expm1f(s);
    }
  }
  __syncthreads();   // xb complete + sWh reads done (overlay safe)

  // ---- phase 4: Wh2 = xb @ outW (overlay sWh), o1 row0 + o2 all rows
  {
    int c = t & 127, ig = t >> 7;
    for (int i = ig; i < 19; i += 2) {
      const float* sx = xb + ((size_t)b * 19 + i) * 512;
      float a0 = 0.f, a1 = 0.f, a2 = 0.f, a3 = 0.f;
      for (int m = 0; m < 512; m += 4) {
        a0 = fmaf(sx[m], outW[m * 128 + c], a0);
        a1 = fmaf(sx[m + 1], outW[(m + 1) * 128 + c], a1);
        a2 = fmaf(sx[m + 2], outW[(m + 2) * 128 + c], a2);
        a3 = fmaf(sx[m + 3], outW[(m + 3) * 128 + c], a3);
      }
      sWh2[i * 128 + c] = (a0 + a1) + (a2 + a3);
    }
  }
  __syncthreads();
  if (t < 19) {
    const float* wr = sWh2 + t * 128;
    float p2 = 0.f, q2 = 0.f;
    for (int c = 0; c < 128; c += 2) {
      p2 = fmaf(wr[c], oa[128 + c], p2);
      q2 = fmaf(wr[c + 1], oa[128 + c + 1], q2);
    }
    so2[t] = p2 + q2;
    if (t == 0) {
      float p1 = 0.f, q1 = 0.f;
      for (int c = 0; c < 128; c += 2) {
        p1 = fmaf(wr[c], oa[c], p1);
        q1 = fmaf(wr[c + 1], oa[c + 1], q1);
      }
      so1_0 = p1 + q1;
    }
  }
  __syncthreads();

  // ---- phase 5: layer-2 attention row 0 + heads
  if (t < 19) {
    float e = so1_0 + so2[t];
    e = e >= 0.f ? e : 0.2f * e;
    sA[t] = sadj[t] > 0.f ? e : NEG_INF_F;  // adj row 0
  }
  __syncthreads();
  if (t == 0) {
    float mx = -1e30f;
    for (int j = 0; j < 19; ++j) mx = fmaxf(mx, sA[j]);
    float sum = 0.f;
    for (int j = 0; j < 19; ++j) { sA[j] = expf(sA[j] - mx); sum += sA[j]; }
    float inv = 1.f / sum;
    for (int j = 0; j < 19; ++j) sA[j] *= inv;
  }
  __syncthreads();
  if (t < 128) {
    float s = 0.f;
    for (int j = 0; j < 19; ++j) s = fmaf(sA[j], sWh2[j * 128 + t], s);
    sF[t] = s > 0.f ? s : expm1f(s);
  }
  __syncthreads();
  {
    float a0 = 0.f, a1 = 0.f, a2 = 0.f, a3 = 0.f;
    for (int e = 0; e < 128; e += 4) {
      a0 = fmaf(sF[e], llw[e * 256 + t], a0);
      a1 = fmaf(sF[e + 1], llw[(e + 1) * 256 + t], a1);
      a2 = fmaf(sF[e + 2], llw[(e + 2) * 256 + t], a2);
      a3 = fmaf(sF[e + 3], llw[(e + 3) * 256 + t], a3);
    }
    float a = fmaxf(llb[t] + ((a0 + a1) + (a2 + a3)), 0.f);
    sG[t] = a;
    out[1024 + b * 256 + t] = a;
  }
  __syncthreads();
  if (t < 2) {
    float a0 = 0.f, a1 = 0.f, a2 = 0.f, a3 = 0.f;
    for (int o = 0; o < 256; o += 4) {
      a0 = fmaf(sG[o], fcw[o * 2 + t], a0);
      a1 = fmaf(sG[o + 1], fcw[(o + 1) * 2 + t], a1);
      a2 = fmaf(sG[o + 2], fcw[(o + 2) * 2 + t], a2);
      a3 = fmaf(sG[o + 3], fcw[(o + 3) * 2 + t], a3);
    }
    out[3072 + b * 2 + t] = fcb[t] + ((a0 + a1) + (a2 + a3));
  }
}

// ---------------------------------------------------------------------------
extern "C" void kernel_launch(void* const* d_in, const int* in_sizes, int n_in,
                              void* d_out, int out_size, void* d_ws, size_t ws_size,
                              hipStream_t stream) {
  const float* in_img   = (const float*)d_in[0];
  const float* w1       = (const float*)d_in[1];
  const float* b1       = (const float*)d_in[2];
  const float* w2       = (const float*)d_in[3];
  const float* b2       = (const float*)d_in[4];
  const float* w3       = (const float*)d_in[5];
  const float* b3       = (const float*)d_in[6];
  const float* w4       = (const float*)d_in[7];
  const float* b4       = (const float*)d_in[8];
  const float* fc_cnn_w = (const float*)d_in[9];
  const float* fc_cnn_b = (const float*)d_in[10];
  const float* att_W    = (const float*)d_in[11];
  const float* att_a    = (const float*)d_in[12];
  const float* out_W    = (const float*)d_in[13];
  const float* out_a    = (const float*)d_in[14];
  const float* ll_w     = (const float*)d_in[15];
  const float* ll_b     = (const float*)d_in[16];
  const float* fc_w     = (const float*)d_in[17];
  const float* fc_b     = (const float*)d_in[18];
  const float* sfc_w    = (const float*)d_in[19];
  const float* sfc_b    = (const float*)d_in[20];
  float* out = (float*)d_out;

  // ---- workspace layout ----------------------------------------------------
  float* p = (float*)d_ws;
  float* adj   = p; p += 361;
  float* feats = p; p += 16384;
  float* xb    = p; p += 77824;
  char* base = (char*)p;
  auto align16 = [&]() { base = (char*)(((uintptr_t)base + 15) & ~(uintptr_t)15); };
  align16();
  auto aus = [&](size_t n) { unsigned short* q = (unsigned short*)base; base += n * 2; return q; };
  unsigned short* bp2 = aus((size_t)2 * 9 * 64 * 4 * 8);
  unsigned short* bp3 = aus((size_t)4 * 18 * 64 * 4 * 8);
  unsigned short* bp4 = aus((size_t)4 * 36 * 64 * 4 * 8);
  align16();
  size_t fixed_bytes = (size_t)(base - (char*)d_ws);
  // per-image (ushort elems, x2 planes): c2o 73984, c3o 41472, c4o 12800
  constexpr size_t PER_IMG_SH = 2 * (73984 + 41472 + 12800);
  int chunk = 128;
  while (chunk > 1 && fixed_bytes + (size_t)chunk * PER_IMG_SH * 2 > ws_size)
    chunk >>= 1;
  unsigned short* buf2H = (unsigned short*)base;
  unsigned short* buf2L = buf2H + (size_t)chunk * 73984;
  unsigned short* buf3H = buf2L + (size_t)chunk * 73984;
  unsigned short* buf3L = buf3H + (size_t)chunk * 41472;
  unsigned short* buf4H = buf3L + (size_t)chunk * 41472;
  unsigned short* buf4L = buf4H + (size_t)chunk * 12800;

  prep_k<<<235, 256, 0, stream>>>(w2, w3, w4, bp2, bp3, bp4, adj);

  for (int c0 = 0; c0 < 128; c0 += chunk) {
    conv12_k<<<dim3(32, 1, chunk), 256, 0, stream>>>(
        in_img + (size_t)c0 * 16384, w1, b1, bp2, b2, buf2H, buf2L);
    conv_mfma_k<64, 128, 32, 4><<<dim3(8, 1, chunk), 256, 0, stream>>>(
        buf2H, buf2L, bp3, b3, buf3H, buf3L);
    conv_mfma_k<128, 128, 16, 4><<<dim3(4, 1, chunk), 256, 0, stream>>>(
        buf3H, buf3L, bp4, b4, buf4H, buf4L);
    meanfc_k<<<chunk, 128, 0, stream>>>(buf4H, buf4L, fc_cnn_w, fc_cnn_b, feats, c0);
  }

  gat_all_k<<<8, 256, 0, stream>>>(feats, att_W, att_a, adj, out_W, out_a,
                                   ll_w, ll_b, fc_w, fc_b, sfc_w, sfc_b, xb, out);
}

// Round 17
// 226.724 us; speedup vs baseline: 4.2104x; 4.2104x over previous
//
#include <hip/hip_runtime.h>
#include <hip/hip_bf16.h>
#include <math.h>

// ---------------------------------------------------------------------------
// GATEmbedding. CNN: conv1 fused into conv2 (conv12_k, R=2, SGPR conv1
// weights -- measured-best shape), conv3/conv4 implicit-GEMM split-bf16 MFMA
// (NFR=4, global_load_lds DMA staging, pre-swizzled global source). All prep
// (adj + 3x bprep) in ONE kernel; sh_k absorbed into gat1_k (9 launches).
// Activations as separate hi/lo bf16 planes.
// NOTE (round 16 post-mortem): fusing the whole GAT into one 8-block kernel
// collapsed grid parallelism (0.015% occupancy, 883us) -- GAT kernels are
// latency-bound and need grid-level TLP. This is the validated structure.
// Outputs (flat): slices_hidden(8,128)@0, image_feature_second(8,256)@1024,
//   prediction(8,2)@3072, slices_out(8,2)@3088, batch_attention(8,19,19)@3104
// ---------------------------------------------------------------------------

#define NEG_INF_F (-9.0e15f)

typedef __attribute__((ext_vector_type(8))) short frag8;
typedef __attribute__((ext_vector_type(4))) float f32x4;
typedef const __attribute__((address_space(1))) void GasV;
typedef __attribute__((address_space(3))) void LasV;

__device__ __forceinline__ unsigned short f2bf(float f) {
  union { float f; unsigned u; } v; v.f = f;
  unsigned r = v.u + 0x7fffu + ((v.u >> 16) & 1u);   // RNE
  return (unsigned short)(r >> 16);
}
__device__ __forceinline__ float bf2f(unsigned short u) {
  union { unsigned u; float f; } v; v.u = ((unsigned)u) << 16;
  return v.f;
}

// LDS 16B-slot swizzle so a ds_read_b128 16-lane phase is <=2-way per bank.
template <int C>
__device__ __forceinline__ int swz(int slot, int px) {
  if constexpr (C == 32) return slot ^ ((px >> 1) & 3);
  else return slot ^ (px & 7);   // C=64: full; C=128: low 3 slot bits
}

// ---- B-prep device body: pack w[oc][c][3][3] f32 into per-lane fragments ---
template <int C, int OC>
__device__ __forceinline__ void bprep_dev(const float* __restrict__ w,
                                          unsigned short* __restrict__ bp, int idx) {
  constexpr int CS = C / 32, NSTEP = 9 * CS, NG = (OC / 64) * 2;
  if (idx >= NG * NSTEP * 64 * 4) return;
  int q = idx & 3;
  int lane = (idx >> 2) & 63;
  int gs = idx >> 8;
  int s = gs % NSTEP;
  int g = gs / NSTEP;
  int off = s / CS, c0 = (s % CS) * 32;
  int l15 = lane & 15, l4 = lane >> 4;
  int oc = (g >> 1) * 64 + (g & 1) * 32 + (q & 1) * 16 + l15;
  int kc = c0 + l4 * 8;
  unsigned short o8[8];
#pragma unroll
  for (int j = 0; j < 8; ++j) {
    float v = w[((size_t)oc * C + kc + j) * 9 + off];
    unsigned short h = f2bf(v);
    o8[j] = (q < 2) ? h : f2bf(v - bf2f(h));
  }
  *(uint4*)(bp + (size_t)idx * 8) = *(uint4*)o8;
}

// ---- prep: adjacency (block 0) + bprep2 (1..18) + bprep3 (19..90) +
//      bprep4 (91..234) in one launch --------------------------------------
__global__ __launch_bounds__(256) void prep_k(
    const float* __restrict__ w2, const float* __restrict__ w3,
    const float* __restrict__ w4, unsigned short* __restrict__ bp2,
    unsigned short* __restrict__ bp3, unsigned short* __restrict__ bp4,
    float* __restrict__ adj) {
  const int bx = blockIdx.x, t = threadIdx.x;
  if (bx == 0) {
    __shared__ float A[19][19];
    for (int e = t; e < 361; e += 256) {
      int i = e / 19, j = e % 19;
      float v = 0.f;
      const int MIDN = 3, N = 19, MID = 10, WIDTH = 2;
      if (i < MIDN) {
        if (i == MIDN - 1) { if (j > MIDN - 1) v = 1.f; }
        else if (j == i + 1 || (j > MID - (i + 1) * WIDTH && j < MID + (i + 1) * WIDTH)) v = 1.f;
      } else {
        if (i == MIDN) { if (j == MIDN + 1) v = 1.f; }
        else if (i == N - 1) { if (j == N - 2) v = 1.f; }
        else if (j == i - 1 || j == i + 1) v = 1.f;
      }
      if (i == j) v += 1.f;
      A[i][j] = v;
    }
    __syncthreads();
    for (int e = t; e < 361; e += 256) {
      int i = e / 19;
      float rs = 0.f;
      for (int j = 0; j < 19; ++j) rs += A[i][j];
      float rinv = rs > 0.f ? 1.f / rs : 0.f;
      adj[e] = A[i][e % 19] * rinv;
    }
  } else if (bx <= 18) {
    bprep_dev<32, 64>(w2, bp2, (bx - 1) * 256 + t);
  } else if (bx <= 90) {
    bprep_dev<64, 128>(w3, bp3, (bx - 19) * 256 + t);
  } else {
    bprep_dev<128, 128>(w4, bp4, (bx - 91) * 256 + t);
  }
}

// ---- conv12: conv1 (1->32, SGPR weights) in-LDS, conv2 MFMA (32->64), R=2 --
// grid (32, 1, imgs). conv1 thread = (px = t&63, ocg = t>>6 wave-uniform).
__global__ __launch_bounds__(256) void conv12_k(
    const float* __restrict__ in, const float* __restrict__ w1,
    const float* __restrict__ b1, const unsigned short* __restrict__ bprep,
    const float* __restrict__ bias,
    unsigned short* __restrict__ outH, unsigned short* __restrict__ outL) {
  constexpr int C = 32, OC = 64, W = 64;
  constexpr int PW = W + 2, OH = W / 2;
  constexpr int NSTEP = 9;
  __shared__ float sr[10][132];
  __shared__ __align__(16) unsigned short patchH[4 * PW * C];
  __shared__ __align__(16) unsigned short patchL[4 * PW * C];
  const int t = threadIdx.x;
  const int img = blockIdx.z;
  const int y0 = blockIdx.x * 2;        // base padded pooled row / conv-row base
  const int pr0 = blockIdx.x;           // base unpadded pooled-out row
  const size_t out_img = (size_t)img * 34 * 34 * OC;

  // stage raw image rows 2*y0-3 .. 2*y0+6 (col c = x+1, zero OOB)
  const float* ip = in + (size_t)img * 16384;
  for (int e = t; e < 10 * 130; e += 256) {
    int s = e / 130, c = e - s * 130;
    int y = 2 * y0 - 3 + s, x = c - 1;
    sr[s][c] = (y >= 0 && y < 128 && x >= 0 && x < 128) ? ip[y * 128 + x] : 0.f;
  }
  __syncthreads();

  // conv1+relu+pool into swizzled hi/lo patch; weights/bias via SGPR
  {
    const int px = t & 63, ocg = t >> 6;
    const int gx = px + 1;
    const int ssl = swz<C>(ocg, gx);
    const int ocg_s = __builtin_amdgcn_readfirstlane(ocg);
    const float* wg = w1 + ocg_s * 72;   // 8 oc x 9 taps
    const float* bg = b1 + ocg_s * 8;
#pragma unroll
    for (int r = 0; r < 4; ++r) {
      int rp = y0 + r;                   // padded pooled row
      unsigned short h8[8], l8[8];
      if (rp == 0 || rp == 65) {
#pragma unroll
        for (int i = 0; i < 8; ++i) { h8[i] = 0; l8[i] = 0; }
      } else {
        float v[4][4];
#pragma unroll
        for (int dy = 0; dy < 4; ++dy)
#pragma unroll
          for (int dx = 0; dx < 4; ++dx) v[dy][dx] = sr[2 * r + dy][2 * px + dx];
#pragma unroll
        for (int i = 0; i < 8; ++i) {
          float m = -1e30f;
#pragma unroll
          for (int dy = 0; dy < 2; ++dy)
#pragma unroll
            for (int dx = 0; dx < 2; ++dx) {
              float a = 0.f;
#pragma unroll
              for (int ky = 0; ky < 3; ++ky)
#pragma unroll
                for (int kx = 0; kx < 3; ++kx)
                  a = fmaf(v[dy + ky][dx + kx], wg[i * 9 + ky * 3 + kx], a);
              m = fmaxf(m, a);
            }
          float o = fmaxf(m + bg[i], 0.f);
          h8[i] = f2bf(o);
          l8[i] = f2bf(o - bf2f(h8[i]));
        }
      }
      int o = (r * PW + gx) * C + ssl * 8;
      *(uint4*)(patchH + o) = *(uint4*)h8;
      *(uint4*)(patchL + o) = *(uint4*)l8;
    }
    if (t < 64) {   // left/right pad pixels: 4 rows x 2 sides x 4 slots x 2 planes
      int r = t >> 4, rem = t & 15;
      int side = rem >> 3, rem2 = rem & 7;
      int plane = rem2 >> 2, q = rem2 & 3;
      const uint4 z4 = {0u, 0u, 0u, 0u};
      unsigned short* dst = plane ? patchL : patchH;
      *(uint4*)(dst + (r * PW + side * (PW - 1)) * C + q * 8) = z4;
    }
  }
  __syncthreads();

  // MFMA main loop (validated mapping, C=32 OC=64 W=64 R=2)
  const int lane = t & 63, wid = t >> 6;
  const int wm = wid >> 1, wn = wid & 1;
  const int l15 = lane & 15, l4 = lane >> 4;
  const int nbase = wn * 32;

  f32x4 acc[4][2] = {};
  const unsigned short* bpw = bprep + ((size_t)wn * NSTEP * 64 + lane) * 32;

  for (int s = 0; s < NSTEP; ++s) {
    const frag8* bp = (const frag8*)(bpw + (size_t)s * 2048);
    frag8 bh0 = bp[0], bh1 = bp[1], bl0 = bp[2], bl1 = bp[3];
    const int ky = s / 3, kx = s - ky * 3;
    frag8 ah[4], al[4];
#pragma unroll
    for (int f = 0; f < 4; ++f) {
      int m0 = wm * 32 + (f & 1) * 16 + (f >> 1) * 64;
      int ry = m0 / W + ky;
      int px = (m0 % W) + l15 + kx;
      size_t o = ((size_t)ry * PW + px) * C + swz<C>(l4, px) * 8;
      ah[f] = *(const frag8*)(patchH + o);
      al[f] = *(const frag8*)(patchL + o);
    }
#pragma unroll
    for (int f = 0; f < 4; ++f) {
      acc[f][0] = __builtin_amdgcn_mfma_f32_16x16x32_bf16(ah[f], bh0, acc[f][0], 0, 0, 0);
      acc[f][0] = __builtin_amdgcn_mfma_f32_16x16x32_bf16(al[f], bh0, acc[f][0], 0, 0, 0);
      acc[f][0] = __builtin_amdgcn_mfma_f32_16x16x32_bf16(ah[f], bl0, acc[f][0], 0, 0, 0);
      acc[f][1] = __builtin_amdgcn_mfma_f32_16x16x32_bf16(ah[f], bh1, acc[f][1], 0, 0, 0);
      acc[f][1] = __builtin_amdgcn_mfma_f32_16x16x32_bf16(al[f], bh1, acc[f][1], 0, 0, 0);
      acc[f][1] = __builtin_amdgcn_mfma_f32_16x16x32_bf16(ah[f], bl1, acc[f][1], 0, 0, 0);
    }
  }

  // epilogue: bias + relu + 2x2 pool, write separate hi/lo planes
  float bb0 = bias[nbase + l15], bb1 = bias[nbase + 16 + l15];
#pragma unroll
  for (int pi = 0; pi < 2; ++pi) {
    const int fa = pi, fb = pi + 2;
    const int m0a = wm * 32 + fa * 16;
    const int prow = (y0 + m0a / W) >> 1;      // == pr0
    const int pxb = (m0a % W) >> 1;
#pragma unroll
    for (int n = 0; n < 2; ++n) {
      const float bb = n ? bb1 : bb0;
#pragma unroll
      for (int xp = 0; xp < 2; ++xp) {
        float v = fmaxf(fmaxf(acc[fa][n][2 * xp], acc[fa][n][2 * xp + 1]),
                        fmaxf(acc[fb][n][2 * xp], acc[fb][n][2 * xp + 1]));
        float vv = fmaxf(v + bb, 0.f);
        size_t idx = out_img + ((size_t)(prow + 1) * 34 + pxb + 2 * l4 + xp + 1) * OC +
                     nbase + n * 16 + l15;
        unsigned short h = f2bf(vv);
        outH[idx] = h;
        outL[idx] = f2bf(vv - bf2f(h));
      }
    }
  }

  // zero pad borders (both planes)
  const uint4 z4 = {0u, 0u, 0u, 0u};
  if (t < 32) {
    int side = (t >> 4) & 1, pl = (t >> 3) & 1, q = t & 7;
    unsigned short* dst = pl ? outL : outH;
    *(uint4*)(dst + out_img + ((size_t)(pr0 + 1) * 34 + side * 33) * OC + q * 8) = z4;
  }
  if (pr0 == 0)
    for (int e = t; e < 544; e += 256) {
      int pl = e >= 272, i = e - pl * 272;
      unsigned short* dst = pl ? outL : outH;
      *(uint4*)(dst + out_img + (size_t)i * 8) = z4;
    }
  if (pr0 + 1 == OH)
    for (int e = t; e < 544; e += 256) {
      int pl = e >= 272, i = e - pl * 272;
      unsigned short* dst = pl ? outL : outH;
      *(uint4*)(dst + out_img + (size_t)33 * 34 * OC + (size_t)i * 8) = z4;
    }
}

// ------- implicit-GEMM split-bf16 MFMA conv+relu+pool, plane hi/lo I/O ------
// One block covers ALL OC=128: wave wn -> 64 oc = 4 n-frags. DMA staging.
template <int C, int OC, int W, int R>
__global__ __launch_bounds__(256) void conv_mfma_k(
    const unsigned short* __restrict__ inH, const unsigned short* __restrict__ inL,
    const unsigned short* __restrict__ bprep, const float* __restrict__ bias,
    unsigned short* __restrict__ outH, unsigned short* __restrict__ outL) {
  constexpr int SL = C / 8;
  constexpr int PW = W + 2;
  constexpr int OW = W / 2, OH = W / 2;
  constexpr int PR = R / 2;
  constexpr int CS = C / 32;
  constexpr int NSTEP = 9 * CS;
  constexpr int M = R * W;
  constexpr int MF = M / 32;
  constexpr int E = (R + 2) * PW * SL;
  constexpr int EP = (E + 63) & ~63;
  __shared__ __align__(16) unsigned short patchH[(R + 2) * PW * C + 256];
  __shared__ __align__(16) unsigned short patchL[(R + 2) * PW * C + 256];
  const int t = threadIdx.x;
  const int img = blockIdx.z;
  const int y0 = blockIdx.x * R;
  const int pr0 = blockIdx.x * PR;
  const size_t in_img = (size_t)img * (W + 2) * (W + 2) * C;
  const size_t out_img = (size_t)img * (OW + 2) * (OW + 2) * OC;

  {
    const unsigned short* gH = inH + in_img + (size_t)y0 * PW * C;
    const unsigned short* gL = inL + in_img + (size_t)y0 * PW * C;
    for (int e0 = t; e0 < EP; e0 += 256) {
      int e = e0 < E ? e0 : E - 1;
      int row = e / (PW * SL);
      int rem = e - row * (PW * SL);
      int px = rem / SL, sl = rem & (SL - 1);
      int goff = row * PW * C + px * C + swz<C>(sl, px) * 8;
      int lbase = __builtin_amdgcn_readfirstlane(e0 & ~63) * 8;
      __builtin_amdgcn_global_load_lds((GasV*)(gH + goff), (LasV*)(patchH + lbase), 16, 0, 0);
      __builtin_amdgcn_global_load_lds((GasV*)(gL + goff), (LasV*)(patchL + lbase), 16, 0, 0);
    }
  }
  __syncthreads();

  const int lane = t & 63, wid = t >> 6;
  const int wm = wid >> 1, wn = wid & 1;
  const int l15 = lane & 15, l4 = lane >> 4;
  const int nbase = wn * 64;

  f32x4 acc[MF][4] = {};
  const unsigned short* bpw0 =
      bprep + (((size_t)(wn * 2 + 0) * NSTEP) * 64 + lane) * 32;
  const unsigned short* bpw1 =
      bprep + (((size_t)(wn * 2 + 1) * NSTEP) * 64 + lane) * 32;

  for (int s = 0; s < NSTEP; ++s) {
    const frag8* bp0 = (const frag8*)(bpw0 + (size_t)s * 2048);
    const frag8* bp1 = (const frag8*)(bpw1 + (size_t)s * 2048);
    frag8 bh0 = bp0[0], bh1 = bp0[1], bh2 = bp1[0], bh3 = bp1[1];
    frag8 bl0 = bp0[2], bl1 = bp0[3], bl2 = bp1[2], bl3 = bp1[3];
    const int off = s / CS, c0 = (s % CS) * 32;
    const int ky = off / 3, kx = off - ky * 3;
    const int slin = (c0 >> 3) + l4;
    frag8 ah[MF], al[MF];
#pragma unroll
    for (int f = 0; f < MF; ++f) {
      int m0 = wm * (M / 2) + f * 16;
      int ry = m0 / W + ky;
      int px = (m0 % W) + l15 + kx;
      size_t o = ((size_t)ry * PW + px) * C + swz<C>(slin, px) * 8;
      ah[f] = *(const frag8*)(patchH + o);
      al[f] = *(const frag8*)(patchL + o);
    }
#pragma unroll
    for (int f = 0; f < MF; ++f) {
      acc[f][0] = __builtin_amdgcn_mfma_f32_16x16x32_bf16(ah[f], bh0, acc[f][0], 0, 0, 0);
      acc[f][0] = __builtin_amdgcn_mfma_f32_16x16x32_bf16(al[f], bh0, acc[f][0], 0, 0, 0);
      acc[f][0] = __builtin_amdgcn_mfma_f32_16x16x32_bf16(ah[f], bl0, acc[f][0], 0, 0, 0);
      acc[f][1] = __builtin_amdgcn_mfma_f32_16x16x32_bf16(ah[f], bh1, acc[f][1], 0, 0, 0);
      acc[f][1] = __builtin_amdgcn_mfma_f32_16x16x32_bf16(al[f], bh1, acc[f][1], 0, 0, 0);
      acc[f][1] = __builtin_amdgcn_mfma_f32_16x16x32_bf16(ah[f], bl1, acc[f][1], 0, 0, 0);
      acc[f][2] = __builtin_amdgcn_mfma_f32_16x16x32_bf16(ah[f], bh2, acc[f][2], 0, 0, 0);
      acc[f][2] = __builtin_amdgcn_mfma_f32_16x16x32_bf16(al[f], bh2, acc[f][2], 0, 0, 0);
      acc[f][2] = __builtin_amdgcn_mfma_f32_16x16x32_bf16(ah[f], bl2, acc[f][2], 0, 0, 0);
      acc[f][3] = __builtin_amdgcn_mfma_f32_16x16x32_bf16(ah[f], bh3, acc[f][3], 0, 0, 0);
      acc[f][3] = __builtin_amdgcn_mfma_f32_16x16x32_bf16(al[f], bh3, acc[f][3], 0, 0, 0);
      acc[f][3] = __builtin_amdgcn_mfma_f32_16x16x32_bf16(ah[f], bl3, acc[f][3], 0, 0, 0);
    }
  }

  float bb[4];
#pragma unroll
  for (int n = 0; n < 4; ++n) bb[n] = bias[nbase + n * 16 + l15];
#pragma unroll
  for (int pi = 0; pi < MF / 2; ++pi) {
    const int fa = (W == 16) ? (pi * 2) : pi;
    const int fb = (W == 16) ? (pi * 2 + 1) : (pi + 2);
    const int m0a = wm * (M / 2) + fa * 16;
    const int prow = (y0 + m0a / W) >> 1;
    const int pxb = (m0a % W) >> 1;
#pragma unroll
    for (int n = 0; n < 4; ++n) {
#pragma unroll
      for (int xp = 0; xp < 2; ++xp) {
        float v = fmaxf(fmaxf(acc[fa][n][2 * xp], acc[fa][n][2 * xp + 1]),
                        fmaxf(acc[fb][n][2 * xp], acc[fb][n][2 * xp + 1]));
        float vv = fmaxf(v + bb[n], 0.f);
        size_t idx = out_img + ((size_t)(prow + 1) * (OW + 2) + pxb + 2 * l4 + xp + 1) * OC +
                     nbase + n * 16 + l15;
        unsigned short h = f2bf(vv);
        outH[idx] = h;
        outL[idx] = f2bf(vv - bf2f(h));
      }
    }
  }

  const uint4 z4 = {0u, 0u, 0u, 0u};
  if (t < PR * 64) {
    int r = t >> 6, rem = t & 63;
    int side = rem >> 5, pl = (rem >> 4) & 1, q = rem & 15;
    unsigned short* dst = pl ? outL : outH;
    *(uint4*)(dst + out_img + ((size_t)(pr0 + r + 1) * (OW + 2) + side * (OW + 1)) * OC +
              q * 8) = z4;
  }
  if (pr0 == 0)
    for (int e = t; e < (OW + 2) * 32; e += 256) {
      int pl = e >= (OW + 2) * 16, i = e - pl * (OW + 2) * 16;
      unsigned short* dst = pl ? outL : outH;
      *(uint4*)(dst + out_img + (size_t)(i >> 4) * OC + (i & 15) * 8) = z4;
    }
  if (pr0 + PR == OH)
    for (int e = t; e < (OW + 2) * 32; e += 256) {
      int pl = e >= (OW + 2) * 16, i = e - pl * (OW + 2) * 16;
      unsigned short* dst = pl ? outL : outH;
      *(uint4*)(dst + out_img + ((size_t)(OH + 1) * (OW + 2) + (i >> 4)) * OC +
                (i & 15) * 8) = z4;
    }
}

// ---------------- spatial mean (8x8 interior, hi/lo planes) + fc ------------
__global__ __launch_bounds__(128) void meanfc_k(
    const unsigned short* __restrict__ c4H, const unsigned short* __restrict__ c4L,
    const float* __restrict__ fcw, const float* __restrict__ fcb,
    float* __restrict__ feats, int img0) {
  int img = blockIdx.x, t = threadIdx.x;
  __shared__ float sM[128];
  const unsigned short* pH = c4H + (size_t)img * 12800;
  const unsigned short* pL = c4L + (size_t)img * 12800;
  float s0 = 0.f, s1 = 0.f;
  for (int pix = 0; pix < 64; pix += 2) {
    int py0 = pix >> 3, px0 = pix & 7;
    int py1 = (pix + 1) >> 3, px1 = (pix + 1) & 7;
    size_t i0 = ((size_t)(py0 + 1) * 10 + px0 + 1) * 128 + t;
    size_t i1 = ((size_t)(py1 + 1) * 10 + px1 + 1) * 128 + t;
    s0 += bf2f(pH[i0]) + bf2f(pL[i0]);
    s1 += bf2f(pH[i1]) + bf2f(pL[i1]);
  }
  sM[t] = (s0 + s1) * (1.f / 64.f);
  __syncthreads();
  float a0 = 0.f, a1 = 0.f, a2 = 0.f, a3 = 0.f;
  for (int c = 0; c < 128; c += 4) {
    a0 = fmaf(sM[c], fcw[c * 128 + t], a0);
    a1 = fmaf(sM[c + 1], fcw[(c + 1) * 128 + t], a1);
    a2 = fmaf(sM[c + 2], fcw[(c + 2) * 128 + t], a2);
    a3 = fmaf(sM[c + 3], fcw[(c + 3) * 128 + t], a3);
  }
  feats[(size_t)(img0 + img) * 128 + t] = fcb[t] + ((a0 + a1) + (a2 + a3));
}

// ---------------- Wh = slices @ att_W, plus f1/f2 projections ---------------
__global__ __launch_bounds__(64) void wh_k(
    const float* __restrict__ feats, const float* __restrict__ attW,
    const float* __restrict__ atta, float* __restrict__ Wh,
    float* __restrict__ f1, float* __restrict__ f2) {
  int bid = blockIdx.x;           // b*152 + k*19 + n
  int n = bid % 19;
  int k = (bid / 19) % 8;
  int b = bid / 152;
  int h = threadIdx.x;
  float acc = 0.f;
  if (n >= 3) {
    const float* s = feats + (size_t)(b * 16 + n - 3) * 128;
    const float* W = attW + (size_t)k * 8192 + h;
    float a0 = 0.f, a1 = 0.f, a2 = 0.f, a3 = 0.f;
    for (int f = 0; f < 128; f += 4) {
      a0 = fmaf(s[f], W[f * 64], a0);
      a1 = fmaf(s[f + 1], W[(f + 1) * 64], a1);
      a2 = fmaf(s[f + 2], W[(f + 2) * 64], a2);
      a3 = fmaf(s[f + 3], W[(f + 3) * 64], a3);
    }
    acc = (a0 + a1) + (a2 + a3);
  }
  Wh[(size_t)bid * 64 + h] = acc;
  float p1 = acc * atta[k * 128 + h];
  float p2 = acc * atta[k * 128 + 64 + h];
#pragma unroll
  for (int off = 32; off > 0; off >>= 1) {
    p1 += __shfl_down(p1, off);
    p2 += __shfl_down(p2, off);
  }
  if (h == 0) { f1[bid] = p1; f2[bid] = p2; }
}

// ---- fused GAT layer 1 + slices head: softmax + head-mean + h=att@Wh + elu
//      + slices_hidden/slices_out (absorbed sh_k) ---------------------------
__global__ __launch_bounds__(256) void gat1_k(
    const float* __restrict__ f1, const float* __restrict__ f2,
    const float* __restrict__ adj, const float* __restrict__ Wh,
    const float* __restrict__ feats, const float* __restrict__ sfcw,
    const float* __restrict__ sfcb, float* __restrict__ out,
    float* __restrict__ xb) {
  int b = blockIdx.x, t = threadIdx.x;
  __shared__ float satt[8][19][19];
  __shared__ float sadj[361], sf1[152], sf2[152];
  __shared__ float shh[128];
  for (int e = t; e < 361; e += 256) sadj[e] = adj[e];
  if (t < 152) { sf1[t] = f1[b * 152 + t]; sf2[t] = f2[b * 152 + t]; }
  __syncthreads();
  if (t < 152) {
    int k = t / 19, i = t % 19;
    float fi = sf1[t];
    float v[19];
    float mx = -1e30f;
#pragma unroll
    for (int j = 0; j < 19; ++j) {
      float e = fi + sf2[k * 19 + j];
      e = e >= 0.f ? e : 0.2f * e;
      e = sadj[i * 19 + j] > 0.f ? e : NEG_INF_F;
      v[j] = e;
      mx = fmaxf(mx, e);
    }
    float sum = 0.f;
#pragma unroll
    for (int j = 0; j < 19; ++j) { v[j] = expf(v[j] - mx); sum += v[j]; }
    float inv = 1.f / sum;
#pragma unroll
    for (int j = 0; j < 19; ++j) satt[k][i][j] = v[j] * inv;
  }
  __syncthreads();
  for (int e = t; e < 361; e += 256) {
    int i = e / 19, j = e - i * 19;
    float s = 0.f;
#pragma unroll
    for (int k = 0; k < 8; ++k) s += satt[k][i][j];
    out[3104 + b * 361 + e] = s * 0.125f;
  }
  int h = t & 63, g = t >> 6;
  for (int row = g; row < 152; row += 4) {
    int k = row / 19, i = row - k * 19;
    const float* whp = Wh + ((size_t)(b * 152 + k * 19)) * 64 + h;
    float s = 0.f;
#pragma unroll
    for (int j = 0; j < 19; ++j) s = fmaf(satt[k][i][j], whp[j * 64], s);
    xb[((size_t)b * 19 + i) * 512 + k * 64 + h] = s > 0.f ? s : expm1f(s);
  }
  // absorbed sh_k: slices_hidden + slices_out
  if (t < 128) {
    float s = 0.f;
    for (int c = 0; c < 16; ++c) s += feats[(size_t)(b * 16 + c) * 128 + t];
    s *= (1.f / 16.f);
    out[b * 128 + t] = s;
    shh[t] = s;
  }
  __syncthreads();
  if (t < 2) {
    float a0 = 0.f, a1 = 0.f, a2 = 0.f, a3 = 0.f;
    for (int e = 0; e < 128; e += 4) {
      a0 = fmaf(shh[e], sfcw[e * 2 + t], a0);
      a1 = fmaf(shh[e + 1], sfcw[(e + 1) * 2 + t], a1);
      a2 = fmaf(shh[e + 2], sfcw[(e + 2) * 2 + t], a2);
      a3 = fmaf(shh[e + 3], sfcw[(e + 3) * 2 + t], a3);
    }
    out[3088 + b * 2 + t] = sfcb[t] + ((a0 + a1) + (a2 + a3));
  }
}

// ---------------- Wh2 = x @ out_W, plus o1/o2 projections -------------------
__global__ __launch_bounds__(128) void wh2_k(
    const float* __restrict__ xb, const float* __restrict__ outW,
    const float* __restrict__ oa, float* __restrict__ Wh2,
    float* __restrict__ o1, float* __restrict__ o2) {
  int bn = blockIdx.x, t = threadIdx.x;  // bn = b*19+n
  __shared__ float sx[512];
  __shared__ float r1[128], r2[128];
  for (int m = t; m < 512; m += 128) sx[m] = xb[(size_t)bn * 512 + m];
  __syncthreads();
  float a0 = 0.f, a1 = 0.f, a2 = 0.f, a3 = 0.f;
  for (int m = 0; m < 512; m += 4) {
    a0 = fmaf(sx[m], outW[m * 128 + t], a0);
    a1 = fmaf(sx[m + 1], outW[(m + 1) * 128 + t], a1);
    a2 = fmaf(sx[m + 2], outW[(m + 2) * 128 + t], a2);
    a3 = fmaf(sx[m + 3], outW[(m + 3) * 128 + t], a3);
  }
  float a = (a0 + a1) + (a2 + a3);
  Wh2[(size_t)bn * 128 + t] = a;
  r1[t] = a * oa[t];
  r2[t] = a * oa[128 + t];
  __syncthreads();
  for (int s = 64; s > 0; s >>= 1) {
    if (t < s) { r1[t] += r1[t + s]; r2[t] += r2[t + s]; }
    __syncthreads();
  }
  if (t == 0) { o1[bn] = r1[0]; o2[bn] = r2[0]; }
}

// ---------------- layer-2 attention row 0 + heads ---------------------------
__global__ __launch_bounds__(256) void final_k(
    const float* __restrict__ adj, const float* __restrict__ o1,
    const float* __restrict__ o2, const float* __restrict__ Wh2,
    const float* __restrict__ llw, const float* __restrict__ llb,
    const float* __restrict__ fcw, const float* __restrict__ fcb,
    float* __restrict__ out) {
  int b = blockIdx.x, t = threadIdx.x;
  __shared__ float sA[19], sF[128], sG[256];
  if (t < 19) {
    float e = o1[b * 19] + o2[b * 19 + t];
    e = e >= 0.f ? e : 0.2f * e;
    sA[t] = adj[t] > 0.f ? e : NEG_INF_F;  // adj row 0
  }
  __syncthreads();
  if (t == 0) {
    float mx = -1e30f;
    for (int j = 0; j < 19; ++j) mx = fmaxf(mx, sA[j]);
    float sum = 0.f;
    for (int j = 0; j < 19; ++j) { sA[j] = expf(sA[j] - mx); sum += sA[j]; }
    float inv = 1.f / sum;
    for (int j = 0; j < 19; ++j) sA[j] *= inv;
  }
  __syncthreads();
  if (t < 128) {
    float s = 0.f;
    for (int j = 0; j < 19; ++j) s = fmaf(sA[j], Wh2[(size_t)(b * 19 + j) * 128 + t], s);
    sF[t] = s > 0.f ? s : expm1f(s);
  }
  __syncthreads();
  {
    float a0 = 0.f, a1 = 0.f, a2 = 0.f, a3 = 0.f;
    for (int e = 0; e < 128; e += 4) {
      a0 = fmaf(sF[e], llw[e * 256 + t], a0);
      a1 = fmaf(sF[e + 1], llw[(e + 1) * 256 + t], a1);
      a2 = fmaf(sF[e + 2], llw[(e + 2) * 256 + t], a2);
      a3 = fmaf(sF[e + 3], llw[(e + 3) * 256 + t], a3);
    }
    float a = fmaxf(llb[t] + ((a0 + a1) + (a2 + a3)), 0.f);
    sG[t] = a;
    out[1024 + b * 256 + t] = a;
  }
  __syncthreads();
  if (t < 2) {
    float a0 = 0.f, a1 = 0.f, a2 = 0.f, a3 = 0.f;
    for (int o = 0; o < 256; o += 4) {
      a0 = fmaf(sG[o], fcw[o * 2 + t], a0);
      a1 = fmaf(sG[o + 1], fcw[(o + 1) * 2 + t], a1);
      a2 = fmaf(sG[o + 2], fcw[(o + 2) * 2 + t], a2);
      a3 = fmaf(sG[o + 3], fcw[(o + 3) * 2 + t], a3);
    }
    out[3072 + b * 2 + t] = fcb[t] + ((a0 + a1) + (a2 + a3));
  }
}

// ---------------------------------------------------------------------------
extern "C" void kernel_launch(void* const* d_in, const int* in_sizes, int n_in,
                              void* d_out, int out_size, void* d_ws, size_t ws_size,
                              hipStream_t stream) {
  const float* in_img   = (const float*)d_in[0];
  const float* w1       = (const float*)d_in[1];
  const float* b1       = (const float*)d_in[2];
  const float* w2       = (const float*)d_in[3];
  const float* b2       = (const float*)d_in[4];
  const float* w3       = (const float*)d_in[5];
  const float* b3       = (const float*)d_in[6];
  const float* w4       = (const float*)d_in[7];
  const float* b4       = (const float*)d_in[8];
  const float* fc_cnn_w = (const float*)d_in[9];
  const float* fc_cnn_b = (const float*)d_in[10];
  const float* att_W    = (const float*)d_in[11];
  const float* att_a    = (const float*)d_in[12];
  const float* out_W    = (const float*)d_in[13];
  const float* out_a    = (const float*)d_in[14];
  const float* ll_w     = (const float*)d_in[15];
  const float* ll_b     = (const float*)d_in[16];
  const float* fc_w     = (const float*)d_in[17];
  const float* fc_b     = (const float*)d_in[18];
  const float* sfc_w    = (const float*)d_in[19];
  const float* sfc_b    = (const float*)d_in[20];
  float* out = (float*)d_out;

  // ---- workspace layout ----------------------------------------------------
  float* p = (float*)d_ws;
  float* adj   = p; p += 361;
  float* feats = p; p += 16384;
  float* Wh    = p; p += 77824;
  float* f1    = p; p += 1216;
  float* f2    = p; p += 1216;
  float* xb    = p; p += 77824;
  float* Wh2   = p; p += 19456;
  float* o1    = p; p += 152;
  float* o2    = p; p += 152;
  char* base = (char*)p;
  auto align16 = [&]() { base = (char*)(((uintptr_t)base + 15) & ~(uintptr_t)15); };
  align16();
  auto aus = [&](size_t n) { unsigned short* q = (unsigned short*)base; base += n * 2; return q; };
  unsigned short* bp2 = aus((size_t)2 * 9 * 64 * 4 * 8);
  unsigned short* bp3 = aus((size_t)4 * 18 * 64 * 4 * 8);
  unsigned short* bp4 = aus((size_t)4 * 36 * 64 * 4 * 8);
  align16();
  size_t fixed_bytes = (size_t)(base - (char*)d_ws);
  // per-image (ushort elems, x2 planes): c2o 73984, c3o 41472, c4o 12800
  constexpr size_t PER_IMG_SH = 2 * (73984 + 41472 + 12800);
  int chunk = 128;
  while (chunk > 1 && fixed_bytes + (size_t)chunk * PER_IMG_SH * 2 > ws_size)
    chunk >>= 1;
  unsigned short* buf2H = (unsigned short*)base;
  unsigned short* buf2L = buf2H + (size_t)chunk * 73984;
  unsigned short* buf3H = buf2L + (size_t)chunk * 73984;
  unsigned short* buf3L = buf3H + (size_t)chunk * 41472;
  unsigned short* buf4H = buf3L + (size_t)chunk * 41472;
  unsigned short* buf4L = buf4H + (size_t)chunk * 12800;

  prep_k<<<235, 256, 0, stream>>>(w2, w3, w4, bp2, bp3, bp4, adj);

  for (int c0 = 0; c0 < 128; c0 += chunk) {
    conv12_k<<<dim3(32, 1, chunk), 256, 0, stream>>>(
        in_img + (size_t)c0 * 16384, w1, b1, bp2, b2, buf2H, buf2L);
    conv_mfma_k<64, 128, 32, 4><<<dim3(8, 1, chunk), 256, 0, stream>>>(
        buf2H, buf2L, bp3, b3, buf3H, buf3L);
    conv_mfma_k<128, 128, 16, 4><<<dim3(4, 1, chunk), 256, 0, stream>>>(
        buf3H, buf3L, bp4, b4, buf4H, buf4L);
    meanfc_k<<<chunk, 128, 0, stream>>>(buf4H, buf4L, fc_cnn_w, fc_cnn_b, feats, c0);
  }

  wh_k<<<1216, 64, 0, stream>>>(feats, att_W, att_a, Wh, f1, f2);
  gat1_k<<<8, 256, 0, stream>>>(f1, f2, adj, Wh, feats, sfc_w, sfc_b, out, xb);
  wh2_k<<<152, 128, 0, stream>>>(xb, out_W, out_a, Wh2, o1, o2);
  final_k<<<8, 256, 0, stream>>>(adj, o1, o2, Wh2, ll_w, ll_b, fc_w, fc_b, out);
}

// Round 18
// 216.380 us; speedup vs baseline: 4.4117x; 1.0478x over previous
//
#include <hip/hip_runtime.h>
#include <hip/hip_bf16.h>
#include <math.h>

// ---------------------------------------------------------------------------
// GATEmbedding. CNN: conv1 fused into conv2 (conv12_k, R=2, SGPR conv1
// weights). ROUND-18 CHANGE: conv1's output is stored HI-ONLY (bf16, no lo
// plane) inside conv12 -- halves conv12 LDS (39->22.5KB, ~2x occupancy),
// removes the per-output split and the al*bh MFMA (216->144 MFMA/wave).
// Weights stay hi/lo split; conv2/3/4 activations stay hi/lo split.
// conv3/conv4: implicit-GEMM split-bf16 MFMA (NFR=4, DMA staging).
// prep fused (adj+3x bprep); sh_k absorbed into gat1_k. 9 launches.
// Outputs (flat): slices_hidden(8,128)@0, image_feature_second(8,256)@1024,
//   prediction(8,2)@3072, slices_out(8,2)@3088, batch_attention(8,19,19)@3104
// ---------------------------------------------------------------------------

#define NEG_INF_F (-9.0e15f)

typedef __attribute__((ext_vector_type(8))) short frag8;
typedef __attribute__((ext_vector_type(4))) float f32x4;
typedef const __attribute__((address_space(1))) void GasV;
typedef __attribute__((address_space(3))) void LasV;

__device__ __forceinline__ unsigned short f2bf(float f) {
  union { float f; unsigned u; } v; v.f = f;
  unsigned r = v.u + 0x7fffu + ((v.u >> 16) & 1u);   // RNE
  return (unsigned short)(r >> 16);
}
__device__ __forceinline__ float bf2f(unsigned short u) {
  union { unsigned u; float f; } v; v.u = ((unsigned)u) << 16;
  return v.f;
}

// LDS 16B-slot swizzle so a ds_read_b128 16-lane phase is <=2-way per bank.
template <int C>
__device__ __forceinline__ int swz(int slot, int px) {
  if constexpr (C == 32) return slot ^ ((px >> 1) & 3);
  else return slot ^ (px & 7);   // C=64: full; C=128: low 3 slot bits
}

// ---- B-prep device body: pack w[oc][c][3][3] f32 into per-lane fragments ---
template <int C, int OC>
__device__ __forceinline__ void bprep_dev(const float* __restrict__ w,
                                          unsigned short* __restrict__ bp, int idx) {
  constexpr int CS = C / 32, NSTEP = 9 * CS, NG = (OC / 64) * 2;
  if (idx >= NG * NSTEP * 64 * 4) return;
  int q = idx & 3;
  int lane = (idx >> 2) & 63;
  int gs = idx >> 8;
  int s = gs % NSTEP;
  int g = gs / NSTEP;
  int off = s / CS, c0 = (s % CS) * 32;
  int l15 = lane & 15, l4 = lane >> 4;
  int oc = (g >> 1) * 64 + (g & 1) * 32 + (q & 1) * 16 + l15;
  int kc = c0 + l4 * 8;
  unsigned short o8[8];
#pragma unroll
  for (int j = 0; j < 8; ++j) {
    float v = w[((size_t)oc * C + kc + j) * 9 + off];
    unsigned short h = f2bf(v);
    o8[j] = (q < 2) ? h : f2bf(v - bf2f(h));
  }
  *(uint4*)(bp + (size_t)idx * 8) = *(uint4*)o8;
}

// ---- prep: adjacency (block 0) + bprep2 (1..18) + bprep3 (19..90) +
//      bprep4 (91..234) in one launch --------------------------------------
__global__ __launch_bounds__(256) void prep_k(
    const float* __restrict__ w2, const float* __restrict__ w3,
    const float* __restrict__ w4, unsigned short* __restrict__ bp2,
    unsigned short* __restrict__ bp3, unsigned short* __restrict__ bp4,
    float* __restrict__ adj) {
  const int bx = blockIdx.x, t = threadIdx.x;
  if (bx == 0) {
    __shared__ float A[19][19];
    for (int e = t; e < 361; e += 256) {
      int i = e / 19, j = e % 19;
      float v = 0.f;
      const int MIDN = 3, N = 19, MID = 10, WIDTH = 2;
      if (i < MIDN) {
        if (i == MIDN - 1) { if (j > MIDN - 1) v = 1.f; }
        else if (j == i + 1 || (j > MID - (i + 1) * WIDTH && j < MID + (i + 1) * WIDTH)) v = 1.f;
      } else {
        if (i == MIDN) { if (j == MIDN + 1) v = 1.f; }
        else if (i == N - 1) { if (j == N - 2) v = 1.f; }
        else if (j == i - 1 || j == i + 1) v = 1.f;
      }
      if (i == j) v += 1.f;
      A[i][j] = v;
    }
    __syncthreads();
    for (int e = t; e < 361; e += 256) {
      int i = e / 19;
      float rs = 0.f;
      for (int j = 0; j < 19; ++j) rs += A[i][j];
      float rinv = rs > 0.f ? 1.f / rs : 0.f;
      adj[e] = A[i][e % 19] * rinv;
    }
  } else if (bx <= 18) {
    bprep_dev<32, 64>(w2, bp2, (bx - 1) * 256 + t);
  } else if (bx <= 90) {
    bprep_dev<64, 128>(w3, bp3, (bx - 19) * 256 + t);
  } else {
    bprep_dev<128, 128>(w4, bp4, (bx - 91) * 256 + t);
  }
}

// ---- conv12: conv1 (1->32, SGPR weights, HI-ONLY output) in-LDS,
//      conv2 MFMA (32->64) with 2 MFMAs/frag (ah*bh + ah*bl), R=2 -----------
// grid (32, 1, imgs). conv1 thread = (px = t&63, ocg = t>>6 wave-uniform).
__global__ __launch_bounds__(256) void conv12_k(
    const float* __restrict__ in, const float* __restrict__ w1,
    const float* __restrict__ b1, const unsigned short* __restrict__ bprep,
    const float* __restrict__ bias,
    unsigned short* __restrict__ outH, unsigned short* __restrict__ outL) {
  constexpr int C = 32, OC = 64, W = 64;
  constexpr int PW = W + 2, OH = W / 2;
  constexpr int NSTEP = 9;
  __shared__ float sr[10][132];
  __shared__ __align__(16) unsigned short patchH[4 * PW * C];
  const int t = threadIdx.x;
  const int img = blockIdx.z;
  const int y0 = blockIdx.x * 2;        // base padded pooled row / conv-row base
  const int pr0 = blockIdx.x;           // base unpadded pooled-out row
  const size_t out_img = (size_t)img * 34 * 34 * OC;

  // stage raw image rows 2*y0-3 .. 2*y0+6 (col c = x+1, zero OOB)
  const float* ip = in + (size_t)img * 16384;
  for (int e = t; e < 10 * 130; e += 256) {
    int s = e / 130, c = e - s * 130;
    int y = 2 * y0 - 3 + s, x = c - 1;
    sr[s][c] = (y >= 0 && y < 128 && x >= 0 && x < 128) ? ip[y * 128 + x] : 0.f;
  }
  __syncthreads();

  // conv1+relu+pool into swizzled HI patch; weights/bias via SGPR
  {
    const int px = t & 63, ocg = t >> 6;
    const int gx = px + 1;
    const int ssl = swz<C>(ocg, gx);
    const int ocg_s = __builtin_amdgcn_readfirstlane(ocg);
    const float* wg = w1 + ocg_s * 72;   // 8 oc x 9 taps
    const float* bg = b1 + ocg_s * 8;
#pragma unroll
    for (int r = 0; r < 4; ++r) {
      int rp = y0 + r;                   // padded pooled row
      unsigned short h8[8];
      if (rp == 0 || rp == 65) {
#pragma unroll
        for (int i = 0; i < 8; ++i) h8[i] = 0;
      } else {
        float v[4][4];
#pragma unroll
        for (int dy = 0; dy < 4; ++dy)
#pragma unroll
          for (int dx = 0; dx < 4; ++dx) v[dy][dx] = sr[2 * r + dy][2 * px + dx];
#pragma unroll
        for (int i = 0; i < 8; ++i) {
          float m = -1e30f;
#pragma unroll
          for (int dy = 0; dy < 2; ++dy)
#pragma unroll
            for (int dx = 0; dx < 2; ++dx) {
              float a = 0.f;
#pragma unroll
              for (int ky = 0; ky < 3; ++ky)
#pragma unroll
                for (int kx = 0; kx < 3; ++kx)
                  a = fmaf(v[dy + ky][dx + kx], wg[i * 9 + ky * 3 + kx], a);
              m = fmaxf(m, a);
            }
          h8[i] = f2bf(fmaxf(m + bg[i], 0.f));
        }
      }
      *(uint4*)(patchH + (r * PW + gx) * C + ssl * 8) = *(uint4*)h8;
    }
    if (t < 32) {   // left/right pad pixels: 4 rows x 2 sides x 4 slots (H only)
      int r = t >> 3, rem = t & 7;
      int side = rem >> 2, q = rem & 3;
      const uint4 z4 = {0u, 0u, 0u, 0u};
      *(uint4*)(patchH + (r * PW + side * (PW - 1)) * C + q * 8) = z4;
    }
  }
  __syncthreads();

  // MFMA main loop: 2 MFMAs per frag pair (ah*bh + ah*bl)
  const int lane = t & 63, wid = t >> 6;
  const int wm = wid >> 1, wn = wid & 1;
  const int l15 = lane & 15, l4 = lane >> 4;
  const int nbase = wn * 32;

  f32x4 acc[4][2] = {};
  const unsigned short* bpw = bprep + ((size_t)wn * NSTEP * 64 + lane) * 32;

  for (int s = 0; s < NSTEP; ++s) {
    const frag8* bp = (const frag8*)(bpw + (size_t)s * 2048);
    frag8 bh0 = bp[0], bh1 = bp[1], bl0 = bp[2], bl1 = bp[3];
    const int ky = s / 3, kx = s - ky * 3;
    frag8 ah[4];
#pragma unroll
    for (int f = 0; f < 4; ++f) {
      int m0 = wm * 32 + (f & 1) * 16 + (f >> 1) * 64;
      int ry = m0 / W + ky;
      int px = (m0 % W) + l15 + kx;
      ah[f] = *(const frag8*)(patchH + ((size_t)ry * PW + px) * C + swz<C>(l4, px) * 8);
    }
#pragma unroll
    for (int f = 0; f < 4; ++f) {
      acc[f][0] = __builtin_amdgcn_mfma_f32_16x16x32_bf16(ah[f], bh0, acc[f][0], 0, 0, 0);
      acc[f][0] = __builtin_amdgcn_mfma_f32_16x16x32_bf16(ah[f], bl0, acc[f][0], 0, 0, 0);
      acc[f][1] = __builtin_amdgcn_mfma_f32_16x16x32_bf16(ah[f], bh1, acc[f][1], 0, 0, 0);
      acc[f][1] = __builtin_amdgcn_mfma_f32_16x16x32_bf16(ah[f], bl1, acc[f][1], 0, 0, 0);
    }
  }

  // epilogue: bias + relu + 2x2 pool, write separate hi/lo planes (FULL split)
  float bb0 = bias[nbase + l15], bb1 = bias[nbase + 16 + l15];
#pragma unroll
  for (int pi = 0; pi < 2; ++pi) {
    const int fa = pi, fb = pi + 2;
    const int m0a = wm * 32 + fa * 16;
    const int prow = (y0 + m0a / W) >> 1;      // == pr0
    const int pxb = (m0a % W) >> 1;
#pragma unroll
    for (int n = 0; n < 2; ++n) {
      const float bb = n ? bb1 : bb0;
#pragma unroll
      for (int xp = 0; xp < 2; ++xp) {
        float v = fmaxf(fmaxf(acc[fa][n][2 * xp], acc[fa][n][2 * xp + 1]),
                        fmaxf(acc[fb][n][2 * xp], acc[fb][n][2 * xp + 1]));
        float vv = fmaxf(v + bb, 0.f);
        size_t idx = out_img + ((size_t)(prow + 1) * 34 + pxb + 2 * l4 + xp + 1) * OC +
                     nbase + n * 16 + l15;
        unsigned short h = f2bf(vv);
        outH[idx] = h;
        outL[idx] = f2bf(vv - bf2f(h));
      }
    }
  }

  // zero pad borders (both planes)
  const uint4 z4 = {0u, 0u, 0u, 0u};
  if (t < 32) {
    int side = (t >> 4) & 1, pl = (t >> 3) & 1, q = t & 7;
    unsigned short* dst = pl ? outL : outH;
    *(uint4*)(dst + out_img + ((size_t)(pr0 + 1) * 34 + side * 33) * OC + q * 8) = z4;
  }
  if (pr0 == 0)
    for (int e = t; e < 544; e += 256) {
      int pl = e >= 272, i = e - pl * 272;
      unsigned short* dst = pl ? outL : outH;
      *(uint4*)(dst + out_img + (size_t)i * 8) = z4;
    }
  if (pr0 + 1 == OH)
    for (int e = t; e < 544; e += 256) {
      int pl = e >= 272, i = e - pl * 272;
      unsigned short* dst = pl ? outL : outH;
      *(uint4*)(dst + out_img + (size_t)33 * 34 * OC + (size_t)i * 8) = z4;
    }
}

// ------- implicit-GEMM split-bf16 MFMA conv+relu+pool, plane hi/lo I/O ------
// One block covers ALL OC=128: wave wn -> 64 oc = 4 n-frags. DMA staging.
template <int C, int OC, int W, int R>
__global__ __launch_bounds__(256) void conv_mfma_k(
    const unsigned short* __restrict__ inH, const unsigned short* __restrict__ inL,
    const unsigned short* __restrict__ bprep, const float* __restrict__ bias,
    unsigned short* __restrict__ outH, unsigned short* __restrict__ outL) {
  constexpr int SL = C / 8;
  constexpr int PW = W + 2;
  constexpr int OW = W / 2, OH = W / 2;
  constexpr int PR = R / 2;
  constexpr int CS = C / 32;
  constexpr int NSTEP = 9 * CS;
  constexpr int M = R * W;
  constexpr int MF = M / 32;
  constexpr int E = (R + 2) * PW * SL;
  constexpr int EP = (E + 63) & ~63;
  __shared__ __align__(16) unsigned short patchH[(R + 2) * PW * C + 256];
  __shared__ __align__(16) unsigned short patchL[(R + 2) * PW * C + 256];
  const int t = threadIdx.x;
  const int img = blockIdx.z;
  const int y0 = blockIdx.x * R;
  const int pr0 = blockIdx.x * PR;
  const size_t in_img = (size_t)img * (W + 2) * (W + 2) * C;
  const size_t out_img = (size_t)img * (OW + 2) * (OW + 2) * OC;

  {
    const unsigned short* gH = inH + in_img + (size_t)y0 * PW * C;
    const unsigned short* gL = inL + in_img + (size_t)y0 * PW * C;
    for (int e0 = t; e0 < EP; e0 += 256) {
      int e = e0 < E ? e0 : E - 1;
      int row = e / (PW * SL);
      int rem = e - row * (PW * SL);
      int px = rem / SL, sl = rem & (SL - 1);
      int goff = row * PW * C + px * C + swz<C>(sl, px) * 8;
      int lbase = __builtin_amdgcn_readfirstlane(e0 & ~63) * 8;
      __builtin_amdgcn_global_load_lds((GasV*)(gH + goff), (LasV*)(patchH + lbase), 16, 0, 0);
      __builtin_amdgcn_global_load_lds((GasV*)(gL + goff), (LasV*)(patchL + lbase), 16, 0, 0);
    }
  }
  __syncthreads();

  const int lane = t & 63, wid = t >> 6;
  const int wm = wid >> 1, wn = wid & 1;
  const int l15 = lane & 15, l4 = lane >> 4;
  const int nbase = wn * 64;

  f32x4 acc[MF][4] = {};
  const unsigned short* bpw0 =
      bprep + (((size_t)(wn * 2 + 0) * NSTEP) * 64 + lane) * 32;
  const unsigned short* bpw1 =
      bprep + (((size_t)(wn * 2 + 1) * NSTEP) * 64 + lane) * 32;

  for (int s = 0; s < NSTEP; ++s) {
    const frag8* bp0 = (const frag8*)(bpw0 + (size_t)s * 2048);
    const frag8* bp1 = (const frag8*)(bpw1 + (size_t)s * 2048);
    frag8 bh0 = bp0[0], bh1 = bp0[1], bh2 = bp1[0], bh3 = bp1[1];
    frag8 bl0 = bp0[2], bl1 = bp0[3], bl2 = bp1[2], bl3 = bp1[3];
    const int off = s / CS, c0 = (s % CS) * 32;
    const int ky = off / 3, kx = off - ky * 3;
    const int slin = (c0 >> 3) + l4;
    frag8 ah[MF], al[MF];
#pragma unroll
    for (int f = 0; f < MF; ++f) {
      int m0 = wm * (M / 2) + f * 16;
      int ry = m0 / W + ky;
      int px = (m0 % W) + l15 + kx;
      size_t o = ((size_t)ry * PW + px) * C + swz<C>(slin, px) * 8;
      ah[f] = *(const frag8*)(patchH + o);
      al[f] = *(const frag8*)(patchL + o);
    }
#pragma unroll
    for (int f = 0; f < MF; ++f) {
      acc[f][0] = __builtin_amdgcn_mfma_f32_16x16x32_bf16(ah[f], bh0, acc[f][0], 0, 0, 0);
      acc[f][0] = __builtin_amdgcn_mfma_f32_16x16x32_bf16(al[f], bh0, acc[f][0], 0, 0, 0);
      acc[f][0] = __builtin_amdgcn_mfma_f32_16x16x32_bf16(ah[f], bl0, acc[f][0], 0, 0, 0);
      acc[f][1] = __builtin_amdgcn_mfma_f32_16x16x32_bf16(ah[f], bh1, acc[f][1], 0, 0, 0);
      acc[f][1] = __builtin_amdgcn_mfma_f32_16x16x32_bf16(al[f], bh1, acc[f][1], 0, 0, 0);
      acc[f][1] = __builtin_amdgcn_mfma_f32_16x16x32_bf16(ah[f], bl1, acc[f][1], 0, 0, 0);
      acc[f][2] = __builtin_amdgcn_mfma_f32_16x16x32_bf16(ah[f], bh2, acc[f][2], 0, 0, 0);
      acc[f][2] = __builtin_amdgcn_mfma_f32_16x16x32_bf16(al[f], bh2, acc[f][2], 0, 0, 0);
      acc[f][2] = __builtin_amdgcn_mfma_f32_16x16x32_bf16(ah[f], bl2, acc[f][2], 0, 0, 0);
      acc[f][3] = __builtin_amdgcn_mfma_f32_16x16x32_bf16(ah[f], bh3, acc[f][3], 0, 0, 0);
      acc[f][3] = __builtin_amdgcn_mfma_f32_16x16x32_bf16(al[f], bh3, acc[f][3], 0, 0, 0);
      acc[f][3] = __builtin_amdgcn_mfma_f32_16x16x32_bf16(ah[f], bl3, acc[f][3], 0, 0, 0);
    }
  }

  float bb[4];
#pragma unroll
  for (int n = 0; n < 4; ++n) bb[n] = bias[nbase + n * 16 + l15];
#pragma unroll
  for (int pi = 0; pi < MF / 2; ++pi) {
    const int fa = (W == 16) ? (pi * 2) : pi;
    const int fb = (W == 16) ? (pi * 2 + 1) : (pi + 2);
    const int m0a = wm * (M / 2) + fa * 16;
    const int prow = (y0 + m0a / W) >> 1;
    const int pxb = (m0a % W) >> 1;
#pragma unroll
    for (int n = 0; n < 4; ++n) {
#pragma unroll
      for (int xp = 0; xp < 2; ++xp) {
        float v = fmaxf(fmaxf(acc[fa][n][2 * xp], acc[fa][n][2 * xp + 1]),
                        fmaxf(acc[fb][n][2 * xp], acc[fb][n][2 * xp + 1]));
        float vv = fmaxf(v + bb[n], 0.f);
        size_t idx = out_img + ((size_t)(prow + 1) * (OW + 2) + pxb + 2 * l4 + xp + 1) * OC +
                     nbase + n * 16 + l15;
        unsigned short h = f2bf(vv);
        outH[idx] = h;
        outL[idx] = f2bf(vv - bf2f(h));
      }
    }
  }

  const uint4 z4 = {0u, 0u, 0u, 0u};
  if (t < PR * 64) {
    int r = t >> 6, rem = t & 63;
    int side = rem >> 5, pl = (rem >> 4) & 1, q = rem & 15;
    unsigned short* dst = pl ? outL : outH;
    *(uint4*)(dst + out_img + ((size_t)(pr0 + r + 1) * (OW + 2) + side * (OW + 1)) * OC +
              q * 8) = z4;
  }
  if (pr0 == 0)
    for (int e = t; e < (OW + 2) * 32; e += 256) {
      int pl = e >= (OW + 2) * 16, i = e - pl * (OW + 2) * 16;
      unsigned short* dst = pl ? outL : outH;
      *(uint4*)(dst + out_img + (size_t)(i >> 4) * OC + (i & 15) * 8) = z4;
    }
  if (pr0 + PR == OH)
    for (int e = t; e < (OW + 2) * 32; e += 256) {
      int pl = e >= (OW + 2) * 16, i = e - pl * (OW + 2) * 16;
      unsigned short* dst = pl ? outL : outH;
      *(uint4*)(dst + out_img + ((size_t)(OH + 1) * (OW + 2) + (i >> 4)) * OC +
                (i & 15) * 8) = z4;
    }
}

// ---------------- spatial mean (8x8 interior, hi/lo planes) + fc ------------
__global__ __launch_bounds__(128) void meanfc_k(
    const unsigned short* __restrict__ c4H, const unsigned short* __restrict__ c4L,
    const float* __restrict__ fcw, const float* __restrict__ fcb,
    float* __restrict__ feats, int img0) {
  int img = blockIdx.x, t = threadIdx.x;
  __shared__ float sM[128];
  const unsigned short* pH = c4H + (size_t)img * 12800;
  const unsigned short* pL = c4L + (size_t)img * 12800;
  float s0 = 0.f, s1 = 0.f;
  for (int pix = 0; pix < 64; pix += 2) {
    int py0 = pix >> 3, px0 = pix & 7;
    int py1 = (pix + 1) >> 3, px1 = (pix + 1) & 7;
    size_t i0 = ((size_t)(py0 + 1) * 10 + px0 + 1) * 128 + t;
    size_t i1 = ((size_t)(py1 + 1) * 10 + px1 + 1) * 128 + t;
    s0 += bf2f(pH[i0]) + bf2f(pL[i0]);
    s1 += bf2f(pH[i1]) + bf2f(pL[i1]);
  }
  sM[t] = (s0 + s1) * (1.f / 64.f);
  __syncthreads();
  float a0 = 0.f, a1 = 0.f, a2 = 0.f, a3 = 0.f;
  for (int c = 0; c < 128; c += 4) {
    a0 = fmaf(sM[c], fcw[c * 128 + t], a0);
    a1 = fmaf(sM[c + 1], fcw[(c + 1) * 128 + t], a1);
    a2 = fmaf(sM[c + 2], fcw[(c + 2) * 128 + t], a2);
    a3 = fmaf(sM[c + 3], fcw[(c + 3) * 128 + t], a3);
  }
  feats[(size_t)(img0 + img) * 128 + t] = fcb[t] + ((a0 + a1) + (a2 + a3));
}

// ---------------- Wh = slices @ att_W, plus f1/f2 projections ---------------
__global__ __launch_bounds__(64) void wh_k(
    const float* __restrict__ feats, const float* __restrict__ attW,
    const float* __restrict__ atta, float* __restrict__ Wh,
    float* __restrict__ f1, float* __restrict__ f2) {
  int bid = blockIdx.x;           // b*152 + k*19 + n
  int n = bid % 19;
  int k = (bid / 19) % 8;
  int b = bid / 152;
  int h = threadIdx.x;
  float acc = 0.f;
  if (n >= 3) {
    const float* s = feats + (size_t)(b * 16 + n - 3) * 128;
    const float* W = attW + (size_t)k * 8192 + h;
    float a0 = 0.f, a1 = 0.f, a2 = 0.f, a3 = 0.f;
    for (int f = 0; f < 128; f += 4) {
      a0 = fmaf(s[f], W[f * 64], a0);
      a1 = fmaf(s[f + 1], W[(f + 1) * 64], a1);
      a2 = fmaf(s[f + 2], W[(f + 2) * 64], a2);
      a3 = fmaf(s[f + 3], W[(f + 3) * 64], a3);
    }
    acc = (a0 + a1) + (a2 + a3);
  }
  Wh[(size_t)bid * 64 + h] = acc;
  float p1 = acc * atta[k * 128 + h];
  float p2 = acc * atta[k * 128 + 64 + h];
#pragma unroll
  for (int off = 32; off > 0; off >>= 1) {
    p1 += __shfl_down(p1, off);
    p2 += __shfl_down(p2, off);
  }
  if (h == 0) { f1[bid] = p1; f2[bid] = p2; }
}

// ---- fused GAT layer 1 + slices head: softmax + head-mean + h=att@Wh + elu
//      + slices_hidden/slices_out (absorbed sh_k) ---------------------------
__global__ __launch_bounds__(256) void gat1_k(
    const float* __restrict__ f1, const float* __restrict__ f2,
    const float* __restrict__ adj, const float* __restrict__ Wh,
    const float* __restrict__ feats, const float* __restrict__ sfcw,
    const float* __restrict__ sfcb, float* __restrict__ out,
    float* __restrict__ xb) {
  int b = blockIdx.x, t = threadIdx.x;
  __shared__ float satt[8][19][19];
  __shared__ float sadj[361], sf1[152], sf2[152];
  __shared__ float shh[128];
  for (int e = t; e < 361; e += 256) sadj[e] = adj[e];
  if (t < 152) { sf1[t] = f1[b * 152 + t]; sf2[t] = f2[b * 152 + t]; }
  __syncthreads();
  if (t < 152) {
    int k = t / 19, i = t % 19;
    float fi = sf1[t];
    float v[19];
    float mx = -1e30f;
#pragma unroll
    for (int j = 0; j < 19; ++j) {
      float e = fi + sf2[k * 19 + j];
      e = e >= 0.f ? e : 0.2f * e;
      e = sadj[i * 19 + j] > 0.f ? e : NEG_INF_F;
      v[j] = e;
      mx = fmaxf(mx, e);
    }
    float sum = 0.f;
#pragma unroll
    for (int j = 0; j < 19; ++j) { v[j] = expf(v[j] - mx); sum += v[j]; }
    float inv = 1.f / sum;
#pragma unroll
    for (int j = 0; j < 19; ++j) satt[k][i][j] = v[j] * inv;
  }
  __syncthreads();
  for (int e = t; e < 361; e += 256) {
    int i = e / 19, j = e - i * 19;
    float s = 0.f;
#pragma unroll
    for (int k = 0; k < 8; ++k) s += satt[k][i][j];
    out[3104 + b * 361 + e] = s * 0.125f;
  }
  int h = t & 63, g = t >> 6;
  for (int row = g; row < 152; row += 4) {
    int k = row / 19, i = row - k * 19;
    const float* whp = Wh + ((size_t)(b * 152 + k * 19)) * 64 + h;
    float s = 0.f;
#pragma unroll
    for (int j = 0; j < 19; ++j) s = fmaf(satt[k][i][j], whp[j * 64], s);
    xb[((size_t)b * 19 + i) * 512 + k * 64 + h] = s > 0.f ? s : expm1f(s);
  }
  // absorbed sh_k: slices_hidden + slices_out
  if (t < 128) {
    float s = 0.f;
    for (int c = 0; c < 16; ++c) s += feats[(size_t)(b * 16 + c) * 128 + t];
    s *= (1.f / 16.f);
    out[b * 128 + t] = s;
    shh[t] = s;
  }
  __syncthreads();
  if (t < 2) {
    float a0 = 0.f, a1 = 0.f, a2 = 0.f, a3 = 0.f;
    for (int e = 0; e < 128; e += 4) {
      a0 = fmaf(shh[e], sfcw[e * 2 + t], a0);
      a1 = fmaf(shh[e + 1], sfcw[(e + 1) * 2 + t], a1);
      a2 = fmaf(shh[e + 2], sfcw[(e + 2) * 2 + t], a2);
      a3 = fmaf(shh[e + 3], sfcw[(e + 3) * 2 + t], a3);
    }
    out[3088 + b * 2 + t] = sfcb[t] + ((a0 + a1) + (a2 + a3));
  }
}

// ---------------- Wh2 = x @ out_W, plus o1/o2 projections -------------------
__global__ __launch_bounds__(128) void wh2_k(
    const float* __restrict__ xb, const float* __restrict__ outW,
    const float* __restrict__ oa, float* __restrict__ Wh2,
    float* __restrict__ o1, float* __restrict__ o2) {
  int bn = blockIdx.x, t = threadIdx.x;  // bn = b*19+n
  __shared__ float sx[512];
  __shared__ float r1[128], r2[128];
  for (int m = t; m < 512; m += 128) sx[m] = xb[(size_t)bn * 512 + m];
  __syncthreads();
  float a0 = 0.f, a1 = 0.f, a2 = 0.f, a3 = 0.f;
  for (int m = 0; m < 512; m += 4) {
    a0 = fmaf(sx[m], outW[m * 128 + t], a0);
    a1 = fmaf(sx[m + 1], outW[(m + 1) * 128 + t], a1);
    a2 = fmaf(sx[m + 2], outW[(m + 2) * 128 + t], a2);
    a3 = fmaf(sx[m + 3], outW[(m + 3) * 128 + t], a3);
  }
  float a = (a0 + a1) + (a2 + a3);
  Wh2[(size_t)bn * 128 + t] = a;
  r1[t] = a * oa[t];
  r2[t] = a * oa[128 + t];
  __syncthreads();
  for (int s = 64; s > 0; s >>= 1) {
    if (t < s) { r1[t] += r1[t + s]; r2[t] += r2[t + s]; }
    __syncthreads();
  }
  if (t == 0) { o1[bn] = r1[0]; o2[bn] = r2[0]; }
}

// ---------------- layer-2 attention row 0 + heads ---------------------------
__global__ __launch_bounds__(256) void final_k(
    const float* __restrict__ adj, const float* __restrict__ o1,
    const float* __restrict__ o2, const float* __restrict__ Wh2,
    const float* __restrict__ llw, const float* __restrict__ llb,
    const float* __restrict__ fcw, const float* __restrict__ fcb,
    float* __restrict__ out) {
  int b = blockIdx.x, t = threadIdx.x;
  __shared__ float sA[19], sF[128], sG[256];
  if (t < 19) {
    float e = o1[b * 19] + o2[b * 19 + t];
    e = e >= 0.f ? e : 0.2f * e;
    sA[t] = adj[t] > 0.f ? e : NEG_INF_F;  // adj row 0
  }
  __syncthreads();
  if (t == 0) {
    float mx = -1e30f;
    for (int j = 0; j < 19; ++j) mx = fmaxf(mx, sA[j]);
    float sum = 0.f;
    for (int j = 0; j < 19; ++j) { sA[j] = expf(sA[j] - mx); sum += sA[j]; }
    float inv = 1.f / sum;
    for (int j = 0; j < 19; ++j) sA[j] *= inv;
  }
  __syncthreads();
  if (t < 128) {
    float s = 0.f;
    for (int j = 0; j < 19; ++j) s = fmaf(sA[j], Wh2[(size_t)(b * 19 + j) * 128 + t], s);
    sF[t] = s > 0.f ? s : expm1f(s);
  }
  __syncthreads();
  {
    float a0 = 0.f, a1 = 0.f, a2 = 0.f, a3 = 0.f;
    for (int e = 0; e < 128; e += 4) {
      a0 = fmaf(sF[e], llw[e * 256 + t], a0);
      a1 = fmaf(sF[e + 1], llw[(e + 1) * 256 + t], a1);
      a2 = fmaf(sF[e + 2], llw[(e + 2) * 256 + t], a2);
      a3 = fmaf(sF[e + 3], llw[(e + 3) * 256 + t], a3);
    }
    float a = fmaxf(llb[t] + ((a0 + a1) + (a2 + a3)), 0.f);
    sG[t] = a;
    out[1024 + b * 256 + t] = a;
  }
  __syncthreads();
  if (t < 2) {
    float a0 = 0.f, a1 = 0.f, a2 = 0.f, a3 = 0.f;
    for (int o = 0; o < 256; o += 4) {
      a0 = fmaf(sG[o], fcw[o * 2 + t], a0);
      a1 = fmaf(sG[o + 1], fcw[(o + 1) * 2 + t], a1);
      a2 = fmaf(sG[o + 2], fcw[(o + 2) * 2 + t], a2);
      a3 = fmaf(sG[o + 3], fcw[(o + 3) * 2 + t], a3);
    }
    out[3072 + b * 2 + t] = fcb[t] + ((a0 + a1) + (a2 + a3));
  }
}

// ---------------------------------------------------------------------------
extern "C" void kernel_launch(void* const* d_in, const int* in_sizes, int n_in,
                              void* d_out, int out_size, void* d_ws, size_t ws_size,
                              hipStream_t stream) {
  const float* in_img   = (const float*)d_in[0];
  const float* w1       = (const float*)d_in[1];
  const float* b1       = (const float*)d_in[2];
  const float* w2       = (const float*)d_in[3];
  const float* b2       = (const float*)d_in[4];
  const float* w3       = (const float*)d_in[5];
  const float* b3       = (const float*)d_in[6];
  const float* w4       = (const float*)d_in[7];
  const float* b4       = (const float*)d_in[8];
  const float* fc_cnn_w = (const float*)d_in[9];
  const float* fc_cnn_b = (const float*)d_in[10];
  const float* att_W    = (const float*)d_in[11];
  const float* att_a    = (const float*)d_in[12];
  const float* out_W    = (const float*)d_in[13];
  const float* out_a    = (const float*)d_in[14];
  const float* ll_w     = (const float*)d_in[15];
  const float* ll_b     = (const float*)d_in[16];
  const float* fc_w     = (const float*)d_in[17];
  const float* fc_b     = (const float*)d_in[18];
  const float* sfc_w    = (const float*)d_in[19];
  const float* sfc_b    = (const float*)d_in[20];
  float* out = (float*)d_out;

  // ---- workspace layout ----------------------------------------------------
  float* p = (float*)d_ws;
  float* adj   = p; p += 361;
  float* feats = p; p += 16384;
  float* Wh    = p; p += 77824;
  float* f1    = p; p += 1216;
  float* f2    = p; p += 1216;
  float* xb    = p; p += 77824;
  float* Wh2   = p; p += 19456;
  float* o1    = p; p += 152;
  float* o2    = p; p += 152;
  char* base = (char*)p;
  auto align16 = [&]() { base = (char*)(((uintptr_t)base + 15) & ~(uintptr_t)15); };
  align16();
  auto aus = [&](size_t n) { unsigned short* q = (unsigned short*)base; base += n * 2; return q; };
  unsigned short* bp2 = aus((size_t)2 * 9 * 64 * 4 * 8);
  unsigned short* bp3 = aus((size_t)4 * 18 * 64 * 4 * 8);
  unsigned short* bp4 = aus((size_t)4 * 36 * 64 * 4 * 8);
  align16();
  size_t fixed_bytes = (size_t)(base - (char*)d_ws);
  // per-image (ushort elems, x2 planes): c2o 73984, c3o 41472, c4o 12800
  constexpr size_t PER_IMG_SH = 2 * (73984 + 41472 + 12800);
  int chunk = 128;
  while (chunk > 1 && fixed_bytes + (size_t)chunk * PER_IMG_SH * 2 > ws_size)
    chunk >>= 1;
  unsigned short* buf2H = (unsigned short*)base;
  unsigned short* buf2L = buf2H + (size_t)chunk * 73984;
  unsigned short* buf3H = buf2L + (size_t)chunk * 73984;
  unsigned short* buf3L = buf3H + (size_t)chunk * 41472;
  unsigned short* buf4H = buf3L + (size_t)chunk * 41472;
  unsigned short* buf4L = buf4H + (size_t)chunk * 12800;

  prep_k<<<235, 256, 0, stream>>>(w2, w3, w4, bp2, bp3, bp4, adj);

  for (int c0 = 0; c0 < 128; c0 += chunk) {
    conv12_k<<<dim3(32, 1, chunk), 256, 0, stream>>>(
        in_img + (size_t)c0 * 16384, w1, b1, bp2, b2, buf2H, buf2L);
    conv_mfma_k<64, 128, 32, 4><<<dim3(8, 1, chunk), 256, 0, stream>>>(
        buf2H, buf2L, bp3, b3, buf3H, buf3L);
    conv_mfma_k<128, 128, 16, 4><<<dim3(4, 1, chunk), 256, 0, stream>>>(
        buf3H, buf3L, bp4, b4, buf4H, buf4L);
    meanfc_k<<<chunk, 128, 0, stream>>>(buf4H, buf4L, fc_cnn_w, fc_cnn_b, feats, c0);
  }

  wh_k<<<1216, 64, 0, stream>>>(feats, att_W, att_a, Wh, f1, f2);
  gat1_k<<<8, 256, 0, stream>>>(f1, f2, adj, Wh, feats, sfc_w, sfc_b, out, xb);
  wh2_k<<<152, 128, 0, stream>>>(xb, out_W, out_a, Wh2, o1, o2);
  final_k<<<8, 256, 0, stream>>>(adj, o1, o2, Wh2, ll_w, ll_b, fc_w, fc_b, out);
}

// Round 19
// 202.079 us; speedup vs baseline: 4.7239x; 1.0708x over previous
//
#include <hip/hip_runtime.h>
#include <hip/hip_bf16.h>
#include <math.h>

// ---------------------------------------------------------------------------
// GATEmbedding. CNN: conv1 fused into conv2 (conv12_k, R=2, SGPR conv1
// weights). ROUND-19: ALL inter-layer activations are HI-ONLY bf16 (single
// plane; weights remain hi/lo split -> 2 MFMAs per fragment: ah*bh + ah*bl).
// Halves activation traffic, staging DMA, and conv LDS; cuts MFMA 3->2.
// conv3/conv4: implicit-GEMM split-weight MFMA (NFR=4, DMA staging).
// prep fused (adj+3x bprep); sh_k absorbed into gat1_k. 9 launches.
// Outputs (flat): slices_hidden(8,128)@0, image_feature_second(8,256)@1024,
//   prediction(8,2)@3072, slices_out(8,2)@3088, batch_attention(8,19,19)@3104
// ---------------------------------------------------------------------------

#define NEG_INF_F (-9.0e15f)

typedef __attribute__((ext_vector_type(8))) short frag8;
typedef __attribute__((ext_vector_type(4))) float f32x4;
typedef const __attribute__((address_space(1))) void GasV;
typedef __attribute__((address_space(3))) void LasV;

__device__ __forceinline__ unsigned short f2bf(float f) {
  union { float f; unsigned u; } v; v.f = f;
  unsigned r = v.u + 0x7fffu + ((v.u >> 16) & 1u);   // RNE
  return (unsigned short)(r >> 16);
}
__device__ __forceinline__ float bf2f(unsigned short u) {
  union { unsigned u; float f; } v; v.u = ((unsigned)u) << 16;
  return v.f;
}

// LDS 16B-slot swizzle so a ds_read_b128 16-lane phase is <=2-way per bank.
template <int C>
__device__ __forceinline__ int swz(int slot, int px) {
  if constexpr (C == 32) return slot ^ ((px >> 1) & 3);
  else return slot ^ (px & 7);   // C=64: full; C=128: low 3 slot bits
}

// ---- B-prep device body: pack w[oc][c][3][3] f32 into per-lane fragments ---
template <int C, int OC>
__device__ __forceinline__ void bprep_dev(const float* __restrict__ w,
                                          unsigned short* __restrict__ bp, int idx) {
  constexpr int CS = C / 32, NSTEP = 9 * CS, NG = (OC / 64) * 2;
  if (idx >= NG * NSTEP * 64 * 4) return;
  int q = idx & 3;
  int lane = (idx >> 2) & 63;
  int gs = idx >> 8;
  int s = gs % NSTEP;
  int g = gs / NSTEP;
  int off = s / CS, c0 = (s % CS) * 32;
  int l15 = lane & 15, l4 = lane >> 4;
  int oc = (g >> 1) * 64 + (g & 1) * 32 + (q & 1) * 16 + l15;
  int kc = c0 + l4 * 8;
  unsigned short o8[8];
#pragma unroll
  for (int j = 0; j < 8; ++j) {
    float v = w[((size_t)oc * C + kc + j) * 9 + off];
    unsigned short h = f2bf(v);
    o8[j] = (q < 2) ? h : f2bf(v - bf2f(h));
  }
  *(uint4*)(bp + (size_t)idx * 8) = *(uint4*)o8;
}

// ---- prep: adjacency (block 0) + bprep2 (1..18) + bprep3 (19..90) +
//      bprep4 (91..234) in one launch --------------------------------------
__global__ __launch_bounds__(256) void prep_k(
    const float* __restrict__ w2, const float* __restrict__ w3,
    const float* __restrict__ w4, unsigned short* __restrict__ bp2,
    unsigned short* __restrict__ bp3, unsigned short* __restrict__ bp4,
    float* __restrict__ adj) {
  const int bx = blockIdx.x, t = threadIdx.x;
  if (bx == 0) {
    __shared__ float A[19][19];
    for (int e = t; e < 361; e += 256) {
      int i = e / 19, j = e % 19;
      float v = 0.f;
      const int MIDN = 3, N = 19, MID = 10, WIDTH = 2;
      if (i < MIDN) {
        if (i == MIDN - 1) { if (j > MIDN - 1) v = 1.f; }
        else if (j == i + 1 || (j > MID - (i + 1) * WIDTH && j < MID + (i + 1) * WIDTH)) v = 1.f;
      } else {
        if (i == MIDN) { if (j == MIDN + 1) v = 1.f; }
        else if (i == N - 1) { if (j == N - 2) v = 1.f; }
        else if (j == i - 1 || j == i + 1) v = 1.f;
      }
      if (i == j) v += 1.f;
      A[i][j] = v;
    }
    __syncthreads();
    for (int e = t; e < 361; e += 256) {
      int i = e / 19;
      float rs = 0.f;
      for (int j = 0; j < 19; ++j) rs += A[i][j];
      float rinv = rs > 0.f ? 1.f / rs : 0.f;
      adj[e] = A[i][e % 19] * rinv;
    }
  } else if (bx <= 18) {
    bprep_dev<32, 64>(w2, bp2, (bx - 1) * 256 + t);
  } else if (bx <= 90) {
    bprep_dev<64, 128>(w3, bp3, (bx - 19) * 256 + t);
  } else {
    bprep_dev<128, 128>(w4, bp4, (bx - 91) * 256 + t);
  }
}

// ---- conv12: conv1 (1->32, SGPR weights, HI-ONLY) in-LDS,
//      conv2 MFMA (32->64, 2 MFMAs/frag), R=2, HI-ONLY output ---------------
// grid (32, 1, imgs). conv1 thread = (px = t&63, ocg = t>>6 wave-uniform).
__global__ __launch_bounds__(256) void conv12_k(
    const float* __restrict__ in, const float* __restrict__ w1,
    const float* __restrict__ b1, const unsigned short* __restrict__ bprep,
    const float* __restrict__ bias, unsigned short* __restrict__ outH) {
  constexpr int C = 32, OC = 64, W = 64;
  constexpr int PW = W + 2, OH = W / 2;
  constexpr int NSTEP = 9;
  __shared__ float sr[10][132];
  __shared__ __align__(16) unsigned short patchH[4 * PW * C];
  const int t = threadIdx.x;
  const int img = blockIdx.z;
  const int y0 = blockIdx.x * 2;        // base padded pooled row / conv-row base
  const int pr0 = blockIdx.x;           // base unpadded pooled-out row
  const size_t out_img = (size_t)img * 34 * 34 * OC;

  // stage raw image rows 2*y0-3 .. 2*y0+6 (col c = x+1, zero OOB)
  const float* ip = in + (size_t)img * 16384;
  for (int e = t; e < 10 * 130; e += 256) {
    int s = e / 130, c = e - s * 130;
    int y = 2 * y0 - 3 + s, x = c - 1;
    sr[s][c] = (y >= 0 && y < 128 && x >= 0 && x < 128) ? ip[y * 128 + x] : 0.f;
  }
  __syncthreads();

  // conv1+relu+pool into swizzled HI patch; weights/bias via SGPR
  {
    const int px = t & 63, ocg = t >> 6;
    const int gx = px + 1;
    const int ssl = swz<C>(ocg, gx);
    const int ocg_s = __builtin_amdgcn_readfirstlane(ocg);
    const float* wg = w1 + ocg_s * 72;   // 8 oc x 9 taps
    const float* bg = b1 + ocg_s * 8;
#pragma unroll
    for (int r = 0; r < 4; ++r) {
      int rp = y0 + r;                   // padded pooled row
      unsigned short h8[8];
      if (rp == 0 || rp == 65) {
#pragma unroll
        for (int i = 0; i < 8; ++i) h8[i] = 0;
      } else {
        float v[4][4];
#pragma unroll
        for (int dy = 0; dy < 4; ++dy)
#pragma unroll
          for (int dx = 0; dx < 4; ++dx) v[dy][dx] = sr[2 * r + dy][2 * px + dx];
#pragma unroll
        for (int i = 0; i < 8; ++i) {
          float m = -1e30f;
#pragma unroll
          for (int dy = 0; dy < 2; ++dy)
#pragma unroll
            for (int dx = 0; dx < 2; ++dx) {
              float a = 0.f;
#pragma unroll
              for (int ky = 0; ky < 3; ++ky)
#pragma unroll
                for (int kx = 0; kx < 3; ++kx)
                  a = fmaf(v[dy + ky][dx + kx], wg[i * 9 + ky * 3 + kx], a);
              m = fmaxf(m, a);
            }
          h8[i] = f2bf(fmaxf(m + bg[i], 0.f));
        }
      }
      *(uint4*)(patchH + (r * PW + gx) * C + ssl * 8) = *(uint4*)h8;
    }
    if (t < 32) {   // left/right pad pixels: 4 rows x 2 sides x 4 slots (H only)
      int r = t >> 3, rem = t & 7;
      int side = rem >> 2, q = rem & 3;
      const uint4 z4 = {0u, 0u, 0u, 0u};
      *(uint4*)(patchH + (r * PW + side * (PW - 1)) * C + q * 8) = z4;
    }
  }
  __syncthreads();

  // MFMA main loop: 2 MFMAs per frag pair (ah*bh + ah*bl)
  const int lane = t & 63, wid = t >> 6;
  const int wm = wid >> 1, wn = wid & 1;
  const int l15 = lane & 15, l4 = lane >> 4;
  const int nbase = wn * 32;

  f32x4 acc[4][2] = {};
  const unsigned short* bpw = bprep + ((size_t)wn * NSTEP * 64 + lane) * 32;

  for (int s = 0; s < NSTEP; ++s) {
    const frag8* bp = (const frag8*)(bpw + (size_t)s * 2048);
    frag8 bh0 = bp[0], bh1 = bp[1], bl0 = bp[2], bl1 = bp[3];
    const int ky = s / 3, kx = s - ky * 3;
    frag8 ah[4];
#pragma unroll
    for (int f = 0; f < 4; ++f) {
      int m0 = wm * 32 + (f & 1) * 16 + (f >> 1) * 64;
      int ry = m0 / W + ky;
      int px = (m0 % W) + l15 + kx;
      ah[f] = *(const frag8*)(patchH + ((size_t)ry * PW + px) * C + swz<C>(l4, px) * 8);
    }
#pragma unroll
    for (int f = 0; f < 4; ++f) {
      acc[f][0] = __builtin_amdgcn_mfma_f32_16x16x32_bf16(ah[f], bh0, acc[f][0], 0, 0, 0);
      acc[f][0] = __builtin_amdgcn_mfma_f32_16x16x32_bf16(ah[f], bl0, acc[f][0], 0, 0, 0);
      acc[f][1] = __builtin_amdgcn_mfma_f32_16x16x32_bf16(ah[f], bh1, acc[f][1], 0, 0, 0);
      acc[f][1] = __builtin_amdgcn_mfma_f32_16x16x32_bf16(ah[f], bl1, acc[f][1], 0, 0, 0);
    }
  }

  // epilogue: bias + relu + 2x2 pool, HI-only write
  float bb0 = bias[nbase + l15], bb1 = bias[nbase + 16 + l15];
#pragma unroll
  for (int pi = 0; pi < 2; ++pi) {
    const int fa = pi, fb = pi + 2;
    const int m0a = wm * 32 + fa * 16;
    const int prow = (y0 + m0a / W) >> 1;      // == pr0
    const int pxb = (m0a % W) >> 1;
#pragma unroll
    for (int n = 0; n < 2; ++n) {
      const float bb = n ? bb1 : bb0;
#pragma unroll
      for (int xp = 0; xp < 2; ++xp) {
        float v = fmaxf(fmaxf(acc[fa][n][2 * xp], acc[fa][n][2 * xp + 1]),
                        fmaxf(acc[fb][n][2 * xp], acc[fb][n][2 * xp + 1]));
        outH[out_img + ((size_t)(prow + 1) * 34 + pxb + 2 * l4 + xp + 1) * OC +
             nbase + n * 16 + l15] = f2bf(fmaxf(v + bb, 0.f));
      }
    }
  }

  // zero pad borders (H plane)
  const uint4 z4 = {0u, 0u, 0u, 0u};
  if (t < 16) {
    int side = (t >> 3) & 1, q = t & 7;
    *(uint4*)(outH + out_img + ((size_t)(pr0 + 1) * 34 + side * 33) * OC + q * 8) = z4;
  }
  if (pr0 == 0)
    for (int e = t; e < 272; e += 256)
      *(uint4*)(outH + out_img + (size_t)e * 8) = z4;
  if (pr0 + 1 == OH)
    for (int e = t; e < 272; e += 256)
      *(uint4*)(outH + out_img + (size_t)33 * 34 * OC + (size_t)e * 8) = z4;
}

// ------- implicit-GEMM split-weight MFMA conv+relu+pool, HI-only act --------
// One block covers ALL OC=128: wave wn -> 64 oc = 4 n-frags. DMA staging.
template <int C, int OC, int W, int R>
__global__ __launch_bounds__(256) void conv_mfma_k(
    const unsigned short* __restrict__ inH,
    const unsigned short* __restrict__ bprep, const float* __restrict__ bias,
    unsigned short* __restrict__ outH) {
  constexpr int SL = C / 8;
  constexpr int PW = W + 2;
  constexpr int OW = W / 2, OH = W / 2;
  constexpr int PR = R / 2;
  constexpr int CS = C / 32;
  constexpr int NSTEP = 9 * CS;
  constexpr int M = R * W;
  constexpr int MF = M / 32;
  constexpr int E = (R + 2) * PW * SL;
  constexpr int EP = (E + 63) & ~63;
  __shared__ __align__(16) unsigned short patchH[(R + 2) * PW * C + 256];
  const int t = threadIdx.x;
  const int img = blockIdx.z;
  const int y0 = blockIdx.x * R;
  const int pr0 = blockIdx.x * PR;
  const size_t in_img = (size_t)img * (W + 2) * (W + 2) * C;
  const size_t out_img = (size_t)img * (OW + 2) * (OW + 2) * OC;

  {
    const unsigned short* gH = inH + in_img + (size_t)y0 * PW * C;
    for (int e0 = t; e0 < EP; e0 += 256) {
      int e = e0 < E ? e0 : E - 1;
      int row = e / (PW * SL);
      int rem = e - row * (PW * SL);
      int px = rem / SL, sl = rem & (SL - 1);
      int goff = row * PW * C + px * C + swz<C>(sl, px) * 8;
      int lbase = __builtin_amdgcn_readfirstlane(e0 & ~63) * 8;
      __builtin_amdgcn_global_load_lds((GasV*)(gH + goff), (LasV*)(patchH + lbase), 16, 0, 0);
    }
  }
  __syncthreads();

  const int lane = t & 63, wid = t >> 6;
  const int wm = wid >> 1, wn = wid & 1;
  const int l15 = lane & 15, l4 = lane >> 4;
  const int nbase = wn * 64;

  f32x4 acc[MF][4] = {};
  const unsigned short* bpw0 =
      bprep + (((size_t)(wn * 2 + 0) * NSTEP) * 64 + lane) * 32;
  const unsigned short* bpw1 =
      bprep + (((size_t)(wn * 2 + 1) * NSTEP) * 64 + lane) * 32;

  for (int s = 0; s < NSTEP; ++s) {
    const frag8* bp0 = (const frag8*)(bpw0 + (size_t)s * 2048);
    const frag8* bp1 = (const frag8*)(bpw1 + (size_t)s * 2048);
    frag8 bh0 = bp0[0], bh1 = bp0[1], bh2 = bp1[0], bh3 = bp1[1];
    frag8 bl0 = bp0[2], bl1 = bp0[3], bl2 = bp1[2], bl3 = bp1[3];
    const int off = s / CS, c0 = (s % CS) * 32;
    const int ky = off / 3, kx = off - ky * 3;
    const int slin = (c0 >> 3) + l4;
    frag8 ah[MF];
#pragma unroll
    for (int f = 0; f < MF; ++f) {
      int m0 = wm * (M / 2) + f * 16;
      int ry = m0 / W + ky;
      int px = (m0 % W) + l15 + kx;
      ah[f] = *(const frag8*)(patchH + ((size_t)ry * PW + px) * C + swz<C>(slin, px) * 8);
    }
#pragma unroll
    for (int f = 0; f < MF; ++f) {
      acc[f][0] = __builtin_amdgcn_mfma_f32_16x16x32_bf16(ah[f], bh0, acc[f][0], 0, 0, 0);
      acc[f][0] = __builtin_amdgcn_mfma_f32_16x16x32_bf16(ah[f], bl0, acc[f][0], 0, 0, 0);
      acc[f][1] = __builtin_amdgcn_mfma_f32_16x16x32_bf16(ah[f], bh1, acc[f][1], 0, 0, 0);
      acc[f][1] = __builtin_amdgcn_mfma_f32_16x16x32_bf16(ah[f], bl1, acc[f][1], 0, 0, 0);
      acc[f][2] = __builtin_amdgcn_mfma_f32_16x16x32_bf16(ah[f], bh2, acc[f][2], 0, 0, 0);
      acc[f][2] = __builtin_amdgcn_mfma_f32_16x16x32_bf16(ah[f], bl2, acc[f][2], 0, 0, 0);
      acc[f][3] = __builtin_amdgcn_mfma_f32_16x16x32_bf16(ah[f], bh3, acc[f][3], 0, 0, 0);
      acc[f][3] = __builtin_amdgcn_mfma_f32_16x16x32_bf16(ah[f], bl3, acc[f][3], 0, 0, 0);
    }
  }

  float bb[4];
#pragma unroll
  for (int n = 0; n < 4; ++n) bb[n] = bias[nbase + n * 16 + l15];
#pragma unroll
  for (int pi = 0; pi < MF / 2; ++pi) {
    const int fa = (W == 16) ? (pi * 2) : pi;
    const int fb = (W == 16) ? (pi * 2 + 1) : (pi + 2);
    const int m0a = wm * (M / 2) + fa * 16;
    const int prow = (y0 + m0a / W) >> 1;
    const int pxb = (m0a % W) >> 1;
#pragma unroll
    for (int n = 0; n < 4; ++n) {
#pragma unroll
      for (int xp = 0; xp < 2; ++xp) {
        float v = fmaxf(fmaxf(acc[fa][n][2 * xp], acc[fa][n][2 * xp + 1]),
                        fmaxf(acc[fb][n][2 * xp], acc[fb][n][2 * xp + 1]));
        outH[out_img + ((size_t)(prow + 1) * (OW + 2) + pxb + 2 * l4 + xp + 1) * OC +
             nbase + n * 16 + l15] = f2bf(fmaxf(v + bb[n], 0.f));
      }
    }
  }

  // zero pad borders (H plane), all OC columns
  const uint4 z4 = {0u, 0u, 0u, 0u};
  if (t < PR * 32) {
    int r = t >> 5, rem = t & 31;
    int side = rem >> 4, q = rem & 15;
    *(uint4*)(outH + out_img + ((size_t)(pr0 + r + 1) * (OW + 2) + side * (OW + 1)) * OC +
              q * 8) = z4;
  }
  if (pr0 == 0)
    for (int e = t; e < (OW + 2) * 16; e += 256)
      *(uint4*)(outH + out_img + (size_t)(e >> 4) * OC + (e & 15) * 8) = z4;
  if (pr0 + PR == OH)
    for (int e = t; e < (OW + 2) * 16; e += 256)
      *(uint4*)(outH + out_img + ((size_t)(OH + 1) * (OW + 2) + (e >> 4)) * OC +
                (e & 15) * 8) = z4;
}

// ---------------- spatial mean (8x8 interior, HI plane) + fc ----------------
__global__ __launch_bounds__(128) void meanfc_k(
    const unsigned short* __restrict__ c4H, const float* __restrict__ fcw,
    const float* __restrict__ fcb, float* __restrict__ feats, int img0) {
  int img = blockIdx.x, t = threadIdx.x;
  __shared__ float sM[128];
  const unsigned short* pH = c4H + (size_t)img * 12800;
  float s0 = 0.f, s1 = 0.f;
  for (int pix = 0; pix < 64; pix += 2) {
    int py0 = pix >> 3, px0 = pix & 7;
    int py1 = (pix + 1) >> 3, px1 = (pix + 1) & 7;
    s0 += bf2f(pH[((size_t)(py0 + 1) * 10 + px0 + 1) * 128 + t]);
    s1 += bf2f(pH[((size_t)(py1 + 1) * 10 + px1 + 1) * 128 + t]);
  }
  sM[t] = (s0 + s1) * (1.f / 64.f);
  __syncthreads();
  float a0 = 0.f, a1 = 0.f, a2 = 0.f, a3 = 0.f;
  for (int c = 0; c < 128; c += 4) {
    a0 = fmaf(sM[c], fcw[c * 128 + t], a0);
    a1 = fmaf(sM[c + 1], fcw[(c + 1) * 128 + t], a1);
    a2 = fmaf(sM[c + 2], fcw[(c + 2) * 128 + t], a2);
    a3 = fmaf(sM[c + 3], fcw[(c + 3) * 128 + t], a3);
  }
  feats[(size_t)(img0 + img) * 128 + t] = fcb[t] + ((a0 + a1) + (a2 + a3));
}

// ---------------- Wh = slices @ att_W, plus f1/f2 projections ---------------
__global__ __launch_bounds__(64) void wh_k(
    const float* __restrict__ feats, const float* __restrict__ attW,
    const float* __restrict__ atta, float* __restrict__ Wh,
    float* __restrict__ f1, float* __restrict__ f2) {
  int bid = blockIdx.x;           // b*152 + k*19 + n
  int n = bid % 19;
  int k = (bid / 19) % 8;
  int b = bid / 152;
  int h = threadIdx.x;
  float acc = 0.f;
  if (n >= 3) {
    const float* s = feats + (size_t)(b * 16 + n - 3) * 128;
    const float* W = attW + (size_t)k * 8192 + h;
    float a0 = 0.f, a1 = 0.f, a2 = 0.f, a3 = 0.f;
    for (int f = 0; f < 128; f += 4) {
      a0 = fmaf(s[f], W[f * 64], a0);
      a1 = fmaf(s[f + 1], W[(f + 1) * 64], a1);
      a2 = fmaf(s[f + 2], W[(f + 2) * 64], a2);
      a3 = fmaf(s[f + 3], W[(f + 3) * 64], a3);
    }
    acc = (a0 + a1) + (a2 + a3);
  }
  Wh[(size_t)bid * 64 + h] = acc;
  float p1 = acc * atta[k * 128 + h];
  float p2 = acc * atta[k * 128 + 64 + h];
#pragma unroll
  for (int off = 32; off > 0; off >>= 1) {
    p1 += __shfl_down(p1, off);
    p2 += __shfl_down(p2, off);
  }
  if (h == 0) { f1[bid] = p1; f2[bid] = p2; }
}

// ---- fused GAT layer 1 + slices head: softmax + head-mean + h=att@Wh + elu
//      + slices_hidden/slices_out (absorbed sh_k) ---------------------------
__global__ __launch_bounds__(256) void gat1_k(
    const float* __restrict__ f1, const float* __restrict__ f2,
    const float* __restrict__ adj, const float* __restrict__ Wh,
    const float* __restrict__ feats, const float* __restrict__ sfcw,
    const float* __restrict__ sfcb, float* __restrict__ out,
    float* __restrict__ xb) {
  int b = blockIdx.x, t = threadIdx.x;
  __shared__ float satt[8][19][19];
  __shared__ float sadj[361], sf1[152], sf2[152];
  __shared__ float shh[128];
  for (int e = t; e < 361; e += 256) sadj[e] = adj[e];
  if (t < 152) { sf1[t] = f1[b * 152 + t]; sf2[t] = f2[b * 152 + t]; }
  __syncthreads();
  if (t < 152) {
    int k = t / 19, i = t % 19;
    float fi = sf1[t];
    float v[19];
    float mx = -1e30f;
#pragma unroll
    for (int j = 0; j < 19; ++j) {
      float e = fi + sf2[k * 19 + j];
      e = e >= 0.f ? e : 0.2f * e;
      e = sadj[i * 19 + j] > 0.f ? e : NEG_INF_F;
      v[j] = e;
      mx = fmaxf(mx, e);
    }
    float sum = 0.f;
#pragma unroll
    for (int j = 0; j < 19; ++j) { v[j] = expf(v[j] - mx); sum += v[j]; }
    float inv = 1.f / sum;
#pragma unroll
    for (int j = 0; j < 19; ++j) satt[k][i][j] = v[j] * inv;
  }
  __syncthreads();
  for (int e = t; e < 361; e += 256) {
    int i = e / 19, j = e - i * 19;
    float s = 0.f;
#pragma unroll
    for (int k = 0; k < 8; ++k) s += satt[k][i][j];
    out[3104 + b * 361 + e] = s * 0.125f;
  }
  int h = t & 63, g = t >> 6;
  for (int row = g; row < 152; row += 4) {
    int k = row / 19, i = row - k * 19;
    const float* whp = Wh + ((size_t)(b * 152 + k * 19)) * 64 + h;
    float s = 0.f;
#pragma unroll
    for (int j = 0; j < 19; ++j) s = fmaf(satt[k][i][j], whp[j * 64], s);
    xb[((size_t)b * 19 + i) * 512 + k * 64 + h] = s > 0.f ? s : expm1f(s);
  }
  // absorbed sh_k: slices_hidden + slices_out
  if (t < 128) {
    float s = 0.f;
    for (int c = 0; c < 16; ++c) s += feats[(size_t)(b * 16 + c) * 128 + t];
    s *= (1.f / 16.f);
    out[b * 128 + t] = s;
    shh[t] = s;
  }
  __syncthreads();
  if (t < 2) {
    float a0 = 0.f, a1 = 0.f, a2 = 0.f, a3 = 0.f;
    for (int e = 0; e < 128; e += 4) {
      a0 = fmaf(shh[e], sfcw[e * 2 + t], a0);
      a1 = fmaf(shh[e + 1], sfcw[(e + 1) * 2 + t], a1);
      a2 = fmaf(shh[e + 2], sfcw[(e + 2) * 2 + t], a2);
      a3 = fmaf(shh[e + 3], sfcw[(e + 3) * 2 + t], a3);
    }
    out[3088 + b * 2 + t] = sfcb[t] + ((a0 + a1) + (a2 + a3));
  }
}

// ---------------- Wh2 = x @ out_W, plus o1/o2 projections -------------------
__global__ __launch_bounds__(128) void wh2_k(
    const float* __restrict__ xb, const float* __restrict__ outW,
    const float* __restrict__ oa, float* __restrict__ Wh2,
    float* __restrict__ o1, float* __restrict__ o2) {
  int bn = blockIdx.x, t = threadIdx.x;  // bn = b*19+n
  __shared__ float sx[512];
  __shared__ float r1[128], r2[128];
  for (int m = t; m < 512; m += 128) sx[m] = xb[(size_t)bn * 512 + m];
  __syncthreads();
  float a0 = 0.f, a1 = 0.f, a2 = 0.f, a3 = 0.f;
  for (int m = 0; m < 512; m += 4) {
    a0 = fmaf(sx[m], outW[m * 128 + t], a0);
    a1 = fmaf(sx[m + 1], outW[(m + 1) * 128 + t], a1);
    a2 = fmaf(sx[m + 2], outW[(m + 2) * 128 + t], a2);
    a3 = fmaf(sx[m + 3], outW[(m + 3) * 128 + t], a3);
  }
  float a = (a0 + a1) + (a2 + a3);
  Wh2[(size_t)bn * 128 + t] = a;
  r1[t] = a * oa[t];
  r2[t] = a * oa[128 + t];
  __syncthreads();
  for (int s = 64; s > 0; s >>= 1) {
    if (t < s) { r1[t] += r1[t + s]; r2[t] += r2[t + s]; }
    __syncthreads();
  }
  if (t == 0) { o1[bn] = r1[0]; o2[bn] = r2[0]; }
}

// ---------------- layer-2 attention row 0 + heads ---------------------------
__global__ __launch_bounds__(256) void final_k(
    const float* __restrict__ adj, const float* __restrict__ o1,
    const float* __restrict__ o2, const float* __restrict__ Wh2,
    const float* __restrict__ llw, const float* __restrict__ llb,
    const float* __restrict__ fcw, const float* __restrict__ fcb,
    float* __restrict__ out) {
  int b = blockIdx.x, t = threadIdx.x;
  __shared__ float sA[19], sF[128], sG[256];
  if (t < 19) {
    float e = o1[b * 19] + o2[b * 19 + t];
    e = e >= 0.f ? e : 0.2f * e;
    sA[t] = adj[t] > 0.f ? e : NEG_INF_F;  // adj row 0
  }
  __syncthreads();
  if (t == 0) {
    float mx = -1e30f;
    for (int j = 0; j < 19; ++j) mx = fmaxf(mx, sA[j]);
    float sum = 0.f;
    for (int j = 0; j < 19; ++j) { sA[j] = expf(sA[j] - mx); sum += sA[j]; }
    float inv = 1.f / sum;
    for (int j = 0; j < 19; ++j) sA[j] *= inv;
  }
  __syncthreads();
  if (t < 128) {
    float s = 0.f;
    for (int j = 0; j < 19; ++j) s = fmaf(sA[j], Wh2[(size_t)(b * 19 + j) * 128 + t], s);
    sF[t] = s > 0.f ? s : expm1f(s);
  }
  __syncthreads();
  {
    float a0 = 0.f, a1 = 0.f, a2 = 0.f, a3 = 0.f;
    for (int e = 0; e < 128; e += 4) {
      a0 = fmaf(sF[e], llw[e * 256 + t], a0);
      a1 = fmaf(sF[e + 1], llw[(e + 1) * 256 + t], a1);
      a2 = fmaf(sF[e + 2], llw[(e + 2) * 256 + t], a2);
      a3 = fmaf(sF[e + 3], llw[(e + 3) * 256 + t], a3);
    }
    float a = fmaxf(llb[t] + ((a0 + a1) + (a2 + a3)), 0.f);
    sG[t] = a;
    out[1024 + b * 256 + t] = a;
  }
  __syncthreads();
  if (t < 2) {
    float a0 = 0.f, a1 = 0.f, a2 = 0.f, a3 = 0.f;
    for (int o = 0; o < 256; o += 4) {
      a0 = fmaf(sG[o], fcw[o * 2 + t], a0);
      a1 = fmaf(sG[o + 1], fcw[(o + 1) * 2 + t], a1);
      a2 = fmaf(sG[o + 2], fcw[(o + 2) * 2 + t], a2);
      a3 = fmaf(sG[o + 3], fcw[(o + 3) * 2 + t], a3);
    }
    out[3072 + b * 2 + t] = fcb[t] + ((a0 + a1) + (a2 + a3));
  }
}

// ---------------------------------------------------------------------------
extern "C" void kernel_launch(void* const* d_in, const int* in_sizes, int n_in,
                              void* d_out, int out_size, void* d_ws, size_t ws_size,
                              hipStream_t stream) {
  const float* in_img   = (const float*)d_in[0];
  const float* w1       = (const float*)d_in[1];
  const float* b1       = (const float*)d_in[2];
  const float* w2       = (const float*)d_in[3];
  const float* b2       = (const float*)d_in[4];
  const float* w3       = (const float*)d_in[5];
  const float* b3       = (const float*)d_in[6];
  const float* w4       = (const float*)d_in[7];
  const float* b4       = (const float*)d_in[8];
  const float* fc_cnn_w = (const float*)d_in[9];
  const float* fc_cnn_b = (const float*)d_in[10];
  const float* att_W    = (const float*)d_in[11];
  const float* att_a    = (const float*)d_in[12];
  const float* out_W    = (const float*)d_in[13];
  const float* out_a    = (const float*)d_in[14];
  const float* ll_w     = (const float*)d_in[15];
  const float* ll_b     = (const float*)d_in[16];
  const float* fc_w     = (const float*)d_in[17];
  const float* fc_b     = (const float*)d_in[18];
  const float* sfc_w    = (const float*)d_in[19];
  const float* sfc_b    = (const float*)d_in[20];
  float* out = (float*)d_out;

  // ---- workspace layout ----------------------------------------------------
  float* p = (float*)d_ws;
  float* adj   = p; p += 361;
  float* feats = p; p += 16384;
  float* Wh    = p; p += 77824;
  float* f1    = p; p += 1216;
  float* f2    = p; p += 1216;
  float* xb    = p; p += 77824;
  float* Wh2   = p; p += 19456;
  float* o1    = p; p += 152;
  float* o2    = p; p += 152;
  char* base = (char*)p;
  auto align16 = [&]() { base = (char*)(((uintptr_t)base + 15) & ~(uintptr_t)15); };
  align16();
  auto aus = [&](size_t n) { unsigned short* q = (unsigned short*)base; base += n * 2; return q; };
  unsigned short* bp2 = aus((size_t)2 * 9 * 64 * 4 * 8);
  unsigned short* bp3 = aus((size_t)4 * 18 * 64 * 4 * 8);
  unsigned short* bp4 = aus((size_t)4 * 36 * 64 * 4 * 8);
  align16();
  size_t fixed_bytes = (size_t)(base - (char*)d_ws);
  // per-image (ushort elems, single plane): c2o 73984, c3o 41472, c4o 12800
  constexpr size_t PER_IMG_SH = 73984 + 41472 + 12800;
  int chunk = 128;
  while (chunk > 1 && fixed_bytes + (size_t)chunk * PER_IMG_SH * 2 > ws_size)
    chunk >>= 1;
  unsigned short* buf2H = (unsigned short*)base;
  unsigned short* buf3H = buf2H + (size_t)chunk * 73984;
  unsigned short* buf4H = buf3H + (size_t)chunk * 41472;

  prep_k<<<235, 256, 0, stream>>>(w2, w3, w4, bp2, bp3, bp4, adj);

  for (int c0 = 0; c0 < 128; c0 += chunk) {
    conv12_k<<<dim3(32, 1, chunk), 256, 0, stream>>>(
        in_img + (size_t)c0 * 16384, w1, b1, bp2, b2, buf2H);
    conv_mfma_k<64, 128, 32, 4><<<dim3(8, 1, chunk), 256, 0, stream>>>(
        buf2H, bp3, b3, buf3H);
    conv_mfma_k<128, 128, 16, 4><<<dim3(4, 1, chunk), 256, 0, stream>>>(
        buf3H, bp4, b4, buf4H);
    meanfc_k<<<chunk, 128, 0, stream>>>(buf4H, fc_cnn_w, fc_cnn_b, feats, c0);
  }

  wh_k<<<1216, 64, 0, stream>>>(feats, att_W, att_a, Wh, f1, f2);
  gat1_k<<<8, 256, 0, stream>>>(f1, f2, adj, Wh, feats, sfc_w, sfc_b, out, xb);
  wh2_k<<<152, 128, 0, stream>>>(xb, out_W, out_a, Wh2, o1, o2);
  final_k<<<8, 256, 0, stream>>>(adj, o1, o2, Wh2, ll_w, ll_b, fc_w, fc_b, out);
}

// Round 20
// 150.704 us; speedup vs baseline: 6.3343x; 1.3409x over previous
//
#include <hip/hip_runtime.h>
#include <hip/hip_bf16.h>
#include <math.h>

// ---------------------------------------------------------------------------
// GATEmbedding. ROUND-20: plain-bf16 convs (weights AND activations hi-only
// bf16, fp32 MFMA accumulate -> 1 MFMA per fragment pair). conv1 fused into
// conv2 (conv12_k, R=2, SGPR conv1 weights). conv3/conv4 implicit-GEMM MFMA
// (NFR=4, global_load_lds DMA staging, pre-swizzled source); conv4 skips
// border pads (PAD=false, interior-only consumer). prep fused; sh_k absorbed
// into gat1_k. 9 launches.
// Outputs (flat): slices_hidden(8,128)@0, image_feature_second(8,256)@1024,
//   prediction(8,2)@3072, slices_out(8,2)@3088, batch_attention(8,19,19)@3104
// ---------------------------------------------------------------------------

#define NEG_INF_F (-9.0e15f)

typedef __attribute__((ext_vector_type(8))) short frag8;
typedef __attribute__((ext_vector_type(4))) float f32x4;
typedef const __attribute__((address_space(1))) void GasV;
typedef __attribute__((address_space(3))) void LasV;

__device__ __forceinline__ unsigned short f2bf(float f) {
  union { float f; unsigned u; } v; v.f = f;
  unsigned r = v.u + 0x7fffu + ((v.u >> 16) & 1u);   // RNE
  return (unsigned short)(r >> 16);
}
__device__ __forceinline__ float bf2f(unsigned short u) {
  union { unsigned u; float f; } v; v.u = ((unsigned)u) << 16;
  return v.f;
}

// LDS 16B-slot swizzle so a ds_read_b128 16-lane phase is <=2-way per bank.
template <int C>
__device__ __forceinline__ int swz(int slot, int px) {
  if constexpr (C == 32) return slot ^ ((px >> 1) & 3);
  else return slot ^ (px & 7);   // C=64: full; C=128: low 3 slot bits
}

// ---- B-prep device body: pack w[oc][c][3][3] f32 -> bf16 per-lane frags ----
// Layout: frag8 index = ((g*NSTEP + s)*64 + lane)*2 + q, q in {oc, oc+16}.
template <int C, int OC>
__device__ __forceinline__ void bprep_dev(const float* __restrict__ w,
                                          unsigned short* __restrict__ bp, int idx) {
  constexpr int CS = C / 32, NSTEP = 9 * CS, NG = (OC / 64) * 2;
  if (idx >= NG * NSTEP * 64 * 2) return;
  int q = idx & 1;
  int lane = (idx >> 1) & 63;
  int gs = idx >> 7;
  int s = gs % NSTEP;
  int g = gs / NSTEP;
  int off = s / CS, c0 = (s % CS) * 32;
  int l15 = lane & 15, l4 = lane >> 4;
  int oc = (g >> 1) * 64 + (g & 1) * 32 + q * 16 + l15;
  int kc = c0 + l4 * 8;
  unsigned short o8[8];
#pragma unroll
  for (int j = 0; j < 8; ++j)
    o8[j] = f2bf(w[((size_t)oc * C + kc + j) * 9 + off]);
  *(uint4*)(bp + (size_t)idx * 8) = *(uint4*)o8;
}

// ---- prep: adjacency (block 0) + bprep2 (1..9) + bprep3 (10..45) +
//      bprep4 (46..117) in one launch ---------------------------------------
__global__ __launch_bounds__(256) void prep_k(
    const float* __restrict__ w2, const float* __restrict__ w3,
    const float* __restrict__ w4, unsigned short* __restrict__ bp2,
    unsigned short* __restrict__ bp3, unsigned short* __restrict__ bp4,
    float* __restrict__ adj) {
  const int bx = blockIdx.x, t = threadIdx.x;
  if (bx == 0) {
    __shared__ float A[19][19];
    for (int e = t; e < 361; e += 256) {
      int i = e / 19, j = e % 19;
      float v = 0.f;
      const int MIDN = 3, N = 19, MID = 10, WIDTH = 2;
      if (i < MIDN) {
        if (i == MIDN - 1) { if (j > MIDN - 1) v = 1.f; }
        else if (j == i + 1 || (j > MID - (i + 1) * WIDTH && j < MID + (i + 1) * WIDTH)) v = 1.f;
      } else {
        if (i == MIDN) { if (j == MIDN + 1) v = 1.f; }
        else if (i == N - 1) { if (j == N - 2) v = 1.f; }
        else if (j == i - 1 || j == i + 1) v = 1.f;
      }
      if (i == j) v += 1.f;
      A[i][j] = v;
    }
    __syncthreads();
    for (int e = t; e < 361; e += 256) {
      int i = e / 19;
      float rs = 0.f;
      for (int j = 0; j < 19; ++j) rs += A[i][j];
      float rinv = rs > 0.f ? 1.f / rs : 0.f;
      adj[e] = A[i][e % 19] * rinv;
    }
  } else if (bx <= 9) {
    bprep_dev<32, 64>(w2, bp2, (bx - 1) * 256 + t);
  } else if (bx <= 45) {
    bprep_dev<64, 128>(w3, bp3, (bx - 10) * 256 + t);
  } else {
    bprep_dev<128, 128>(w4, bp4, (bx - 46) * 256 + t);
  }
}

// ---- conv12: conv1 (1->32, SGPR weights) in-LDS, conv2 MFMA (32->64), R=2 --
// 1 MFMA per fragment pair (plain bf16). HI-only activations throughout.
__global__ __launch_bounds__(256) void conv12_k(
    const float* __restrict__ in, const float* __restrict__ w1,
    const float* __restrict__ b1, const unsigned short* __restrict__ bprep,
    const float* __restrict__ bias, unsigned short* __restrict__ outH) {
  constexpr int C = 32, OC = 64, W = 64;
  constexpr int PW = W + 2, OH = W / 2;
  constexpr int NSTEP = 9;
  __shared__ float sr[10][132];
  __shared__ __align__(16) unsigned short patchH[4 * PW * C];
  const int t = threadIdx.x;
  const int img = blockIdx.z;
  const int y0 = blockIdx.x * 2;        // base padded pooled row / conv-row base
  const int pr0 = blockIdx.x;           // base unpadded pooled-out row
  const size_t out_img = (size_t)img * 34 * 34 * OC;

  // stage raw image rows 2*y0-3 .. 2*y0+6 (col c = x+1, zero OOB)
  const float* ip = in + (size_t)img * 16384;
  for (int e = t; e < 10 * 130; e += 256) {
    int s = e / 130, c = e - s * 130;
    int y = 2 * y0 - 3 + s, x = c - 1;
    sr[s][c] = (y >= 0 && y < 128 && x >= 0 && x < 128) ? ip[y * 128 + x] : 0.f;
  }
  __syncthreads();

  // conv1+relu+pool into swizzled HI patch; weights/bias via SGPR
  {
    const int px = t & 63, ocg = t >> 6;
    const int gx = px + 1;
    const int ssl = swz<C>(ocg, gx);
    const int ocg_s = __builtin_amdgcn_readfirstlane(ocg);
    const float* wg = w1 + ocg_s * 72;   // 8 oc x 9 taps
    const float* bg = b1 + ocg_s * 8;
#pragma unroll
    for (int r = 0; r < 4; ++r) {
      int rp = y0 + r;                   // padded pooled row
      unsigned short h8[8];
      if (rp == 0 || rp == 65) {
#pragma unroll
        for (int i = 0; i < 8; ++i) h8[i] = 0;
      } else {
        float v[4][4];
#pragma unroll
        for (int dy = 0; dy < 4; ++dy)
#pragma unroll
          for (int dx = 0; dx < 4; ++dx) v[dy][dx] = sr[2 * r + dy][2 * px + dx];
#pragma unroll
        for (int i = 0; i < 8; ++i) {
          float m = -1e30f;
#pragma unroll
          for (int dy = 0; dy < 2; ++dy)
#pragma unroll
            for (int dx = 0; dx < 2; ++dx) {
              float a = 0.f;
#pragma unroll
              for (int ky = 0; ky < 3; ++ky)
#pragma unroll
                for (int kx = 0; kx < 3; ++kx)
                  a = fmaf(v[dy + ky][dx + kx], wg[i * 9 + ky * 3 + kx], a);
              m = fmaxf(m, a);
            }
          h8[i] = f2bf(fmaxf(m + bg[i], 0.f));
        }
      }
      *(uint4*)(patchH + (r * PW + gx) * C + ssl * 8) = *(uint4*)h8;
    }
    if (t < 32) {   // left/right pad pixels: 4 rows x 2 sides x 4 slots (H only)
      int r = t >> 3, rem = t & 7;
      int side = rem >> 2, q = rem & 3;
      const uint4 z4 = {0u, 0u, 0u, 0u};
      *(uint4*)(patchH + (r * PW + side * (PW - 1)) * C + q * 8) = z4;
    }
  }
  __syncthreads();

  // MFMA main loop: 1 MFMA per frag pair
  const int lane = t & 63, wid = t >> 6;
  const int wm = wid >> 1, wn = wid & 1;
  const int l15 = lane & 15, l4 = lane >> 4;
  const int nbase = wn * 32;

  f32x4 acc[4][2] = {};
  const unsigned short* bpw = bprep + ((size_t)wn * NSTEP * 64 + lane) * 16;

  for (int s = 0; s < NSTEP; ++s) {
    const frag8* bp = (const frag8*)(bpw + (size_t)s * 1024);
    frag8 bh0 = bp[0], bh1 = bp[1];
    const int ky = s / 3, kx = s - ky * 3;
    frag8 ah[4];
#pragma unroll
    for (int f = 0; f < 4; ++f) {
      int m0 = wm * 32 + (f & 1) * 16 + (f >> 1) * 64;
      int ry = m0 / W + ky;
      int px = (m0 % W) + l15 + kx;
      ah[f] = *(const frag8*)(patchH + ((size_t)ry * PW + px) * C + swz<C>(l4, px) * 8);
    }
#pragma unroll
    for (int f = 0; f < 4; ++f) {
      acc[f][0] = __builtin_amdgcn_mfma_f32_16x16x32_bf16(ah[f], bh0, acc[f][0], 0, 0, 0);
      acc[f][1] = __builtin_amdgcn_mfma_f32_16x16x32_bf16(ah[f], bh1, acc[f][1], 0, 0, 0);
    }
  }

  // epilogue: bias + relu + 2x2 pool, HI-only write
  float bb0 = bias[nbase + l15], bb1 = bias[nbase + 16 + l15];
#pragma unroll
  for (int pi = 0; pi < 2; ++pi) {
    const int fa = pi, fb = pi + 2;
    const int m0a = wm * 32 + fa * 16;
    const int prow = (y0 + m0a / W) >> 1;      // == pr0
    const int pxb = (m0a % W) >> 1;
#pragma unroll
    for (int n = 0; n < 2; ++n) {
      const float bb = n ? bb1 : bb0;
#pragma unroll
      for (int xp = 0; xp < 2; ++xp) {
        float v = fmaxf(fmaxf(acc[fa][n][2 * xp], acc[fa][n][2 * xp + 1]),
                        fmaxf(acc[fb][n][2 * xp], acc[fb][n][2 * xp + 1]));
        outH[out_img + ((size_t)(prow + 1) * 34 + pxb + 2 * l4 + xp + 1) * OC +
             nbase + n * 16 + l15] = f2bf(fmaxf(v + bb, 0.f));
      }
    }
  }

  // zero pad borders (H plane)
  const uint4 z4 = {0u, 0u, 0u, 0u};
  if (t < 16) {
    int side = (t >> 3) & 1, q = t & 7;
    *(uint4*)(outH + out_img + ((size_t)(pr0 + 1) * 34 + side * 33) * OC + q * 8) = z4;
  }
  if (pr0 == 0)
    for (int e = t; e < 272; e += 256)
      *(uint4*)(outH + out_img + (size_t)e * 8) = z4;
  if (pr0 + 1 == OH)
    for (int e = t; e < 272; e += 256)
      *(uint4*)(outH + out_img + (size_t)33 * 34 * OC + (size_t)e * 8) = z4;
}

// ------- implicit-GEMM bf16 MFMA conv+relu+pool, HI-only act ----------------
// One block covers ALL OC=128: wave wn -> 64 oc = 4 n-frags. DMA staging.
// PAD=false skips border-pad writes (interior-only consumers, e.g. conv4).
template <int C, int OC, int W, int R, bool PAD = true>
__global__ __launch_bounds__(256) void conv_mfma_k(
    const unsigned short* __restrict__ inH,
    const unsigned short* __restrict__ bprep, const float* __restrict__ bias,
    unsigned short* __restrict__ outH) {
  constexpr int SL = C / 8;
  constexpr int PW = W + 2;
  constexpr int OW = W / 2, OH = W / 2;
  constexpr int PR = R / 2;
  constexpr int CS = C / 32;
  constexpr int NSTEP = 9 * CS;
  constexpr int M = R * W;
  constexpr int MF = M / 32;
  constexpr int E = (R + 2) * PW * SL;
  constexpr int EP = (E + 63) & ~63;
  __shared__ __align__(16) unsigned short patchH[(R + 2) * PW * C + 256];
  const int t = threadIdx.x;
  const int img = blockIdx.z;
  const int y0 = blockIdx.x * R;
  const int pr0 = blockIdx.x * PR;
  const size_t in_img = (size_t)img * (W + 2) * (W + 2) * C;
  const size_t out_img = (size_t)img * (OW + 2) * (OW + 2) * OC;

  {
    const unsigned short* gH = inH + in_img + (size_t)y0 * PW * C;
    for (int e0 = t; e0 < EP; e0 += 256) {
      int e = e0 < E ? e0 : E - 1;
      int row = e / (PW * SL);
      int rem = e - row * (PW * SL);
      int px = rem / SL, sl = rem & (SL - 1);
      int goff = row * PW * C + px * C + swz<C>(sl, px) * 8;
      int lbase = __builtin_amdgcn_readfirstlane(e0 & ~63) * 8;
      __builtin_amdgcn_global_load_lds((GasV*)(gH + goff), (LasV*)(patchH + lbase), 16, 0, 0);
    }
  }
  __syncthreads();

  const int lane = t & 63, wid = t >> 6;
  const int wm = wid >> 1, wn = wid & 1;
  const int l15 = lane & 15, l4 = lane >> 4;
  const int nbase = wn * 64;

  f32x4 acc[MF][4] = {};
  const unsigned short* bpw0 =
      bprep + (((size_t)(wn * 2 + 0) * NSTEP) * 64 + lane) * 16;
  const unsigned short* bpw1 =
      bprep + (((size_t)(wn * 2 + 1) * NSTEP) * 64 + lane) * 16;

  for (int s = 0; s < NSTEP; ++s) {
    const frag8* bp0 = (const frag8*)(bpw0 + (size_t)s * 1024);
    const frag8* bp1 = (const frag8*)(bpw1 + (size_t)s * 1024);
    frag8 bh0 = bp0[0], bh1 = bp0[1], bh2 = bp1[0], bh3 = bp1[1];
    const int off = s / CS, c0 = (s % CS) * 32;
    const int ky = off / 3, kx = off - ky * 3;
    const int slin = (c0 >> 3) + l4;
    frag8 ah[MF];
#pragma unroll
    for (int f = 0; f < MF; ++f) {
      int m0 = wm * (M / 2) + f * 16;
      int ry = m0 / W + ky;
      int px = (m0 % W) + l15 + kx;
      ah[f] = *(const frag8*)(patchH + ((size_t)ry * PW + px) * C + swz<C>(slin, px) * 8);
    }
#pragma unroll
    for (int f = 0; f < MF; ++f) {
      acc[f][0] = __builtin_amdgcn_mfma_f32_16x16x32_bf16(ah[f], bh0, acc[f][0], 0, 0, 0);
      acc[f][1] = __builtin_amdgcn_mfma_f32_16x16x32_bf16(ah[f], bh1, acc[f][1], 0, 0, 0);
      acc[f][2] = __builtin_amdgcn_mfma_f32_16x16x32_bf16(ah[f], bh2, acc[f][2], 0, 0, 0);
      acc[f][3] = __builtin_amdgcn_mfma_f32_16x16x32_bf16(ah[f], bh3, acc[f][3], 0, 0, 0);
    }
  }

  float bb[4];
#pragma unroll
  for (int n = 0; n < 4; ++n) bb[n] = bias[nbase + n * 16 + l15];
#pragma unroll
  for (int pi = 0; pi < MF / 2; ++pi) {
    const int fa = (W == 16) ? (pi * 2) : pi;
    const int fb = (W == 16) ? (pi * 2 + 1) : (pi + 2);
    const int m0a = wm * (M / 2) + fa * 16;
    const int prow = (y0 + m0a / W) >> 1;
    const int pxb = (m0a % W) >> 1;
#pragma unroll
    for (int n = 0; n < 4; ++n) {
#pragma unroll
      for (int xp = 0; xp < 2; ++xp) {
        float v = fmaxf(fmaxf(acc[fa][n][2 * xp], acc[fa][n][2 * xp + 1]),
                        fmaxf(acc[fb][n][2 * xp], acc[fb][n][2 * xp + 1]));
        outH[out_img + ((size_t)(prow + 1) * (OW + 2) + pxb + 2 * l4 + xp + 1) * OC +
             nbase + n * 16 + l15] = f2bf(fmaxf(v + bb[n], 0.f));
      }
    }
  }

  if constexpr (PAD) {
    // zero pad borders (H plane), all OC columns
    const uint4 z4 = {0u, 0u, 0u, 0u};
    if (t < PR * 32) {
      int r = t >> 5, rem = t & 31;
      int side = rem >> 4, q = rem & 15;
      *(uint4*)(outH + out_img + ((size_t)(pr0 + r + 1) * (OW + 2) + side * (OW + 1)) * OC +
                q * 8) = z4;
    }
    if (pr0 == 0)
      for (int e = t; e < (OW + 2) * 16; e += 256)
        *(uint4*)(outH + out_img + (size_t)(e >> 4) * OC + (e & 15) * 8) = z4;
    if (pr0 + PR == OH)
      for (int e = t; e < (OW + 2) * 16; e += 256)
        *(uint4*)(outH + out_img + ((size_t)(OH + 1) * (OW + 2) + (e >> 4)) * OC +
                  (e & 15) * 8) = z4;
  }
}

// ---------------- spatial mean (8x8 interior, HI plane) + fc ----------------
__global__ __launch_bounds__(128) void meanfc_k(
    const unsigned short* __restrict__ c4H, const float* __restrict__ fcw,
    const float* __restrict__ fcb, float* __restrict__ feats, int img0) {
  int img = blockIdx.x, t = threadIdx.x;
  __shared__ float sM[128];
  const unsigned short* pH = c4H + (size_t)img * 12800;
  float s0 = 0.f, s1 = 0.f;
  for (int pix = 0; pix < 64; pix += 2) {
    int py0 = pix >> 3, px0 = pix & 7;
    int py1 = (pix + 1) >> 3, px1 = (pix + 1) & 7;
    s0 += bf2f(pH[((size_t)(py0 + 1) * 10 + px0 + 1) * 128 + t]);
    s1 += bf2f(pH[((size_t)(py1 + 1) * 10 + px1 + 1) * 128 + t]);
  }
  sM[t] = (s0 + s1) * (1.f / 64.f);
  __syncthreads();
  float a0 = 0.f, a1 = 0.f, a2 = 0.f, a3 = 0.f;
  for (int c = 0; c < 128; c += 4) {
    a0 = fmaf(sM[c], fcw[c * 128 + t], a0);
    a1 = fmaf(sM[c + 1], fcw[(c + 1) * 128 + t], a1);
    a2 = fmaf(sM[c + 2], fcw[(c + 2) * 128 + t], a2);
    a3 = fmaf(sM[c + 3], fcw[(c + 3) * 128 + t], a3);
  }
  feats[(size_t)(img0 + img) * 128 + t] = fcb[t] + ((a0 + a1) + (a2 + a3));
}

// ---------------- Wh = slices @ att_W, plus f1/f2 projections ---------------
__global__ __launch_bounds__(64) void wh_k(
    const float* __restrict__ feats, const float* __restrict__ attW,
    const float* __restrict__ atta, float* __restrict__ Wh,
    float* __restrict__ f1, float* __restrict__ f2) {
  int bid = blockIdx.x;           // b*152 + k*19 + n
  int n = bid % 19;
  int k = (bid / 19) % 8;
  int b = bid / 152;
  int h = threadIdx.x;
  float acc = 0.f;
  if (n >= 3) {
    const float* s = feats + (size_t)(b * 16 + n - 3) * 128;
    const float* W = attW + (size_t)k * 8192 + h;
    float a0 = 0.f, a1 = 0.f, a2 = 0.f, a3 = 0.f;
    for (int f = 0; f < 128; f += 4) {
      a0 = fmaf(s[f], W[f * 64], a0);
      a1 = fmaf(s[f + 1], W[(f + 1) * 64], a1);
      a2 = fmaf(s[f + 2], W[(f + 2) * 64], a2);
      a3 = fmaf(s[f + 3], W[(f + 3) * 64], a3);
    }
    acc = (a0 + a1) + (a2 + a3);
  }
  Wh[(size_t)bid * 64 + h] = acc;
  float p1 = acc * atta[k * 128 + h];
  float p2 = acc * atta[k * 128 + 64 + h];
#pragma unroll
  for (int off = 32; off > 0; off >>= 1) {
    p1 += __shfl_down(p1, off);
    p2 += __shfl_down(p2, off);
  }
  if (h == 0) { f1[bid] = p1; f2[bid] = p2; }
}

// ---- fused GAT layer 1 + slices head: softmax + head-mean + h=att@Wh + elu
//      + slices_hidden/slices_out (absorbed sh_k) ---------------------------
__global__ __launch_bounds__(256) void gat1_k(
    const float* __restrict__ f1, const float* __restrict__ f2,
    const float* __restrict__ adj, const float* __restrict__ Wh,
    const float* __restrict__ feats, const float* __restrict__ sfcw,
    const float* __restrict__ sfcb, float* __restrict__ out,
    float* __restrict__ xb) {
  int b = blockIdx.x, t = threadIdx.x;
  __shared__ float satt[8][19][19];
  __shared__ float sadj[361], sf1[152], sf2[152];
  __shared__ float shh[128];
  for (int e = t; e < 361; e += 256) sadj[e] = adj[e];
  if (t < 152) { sf1[t] = f1[b * 152 + t]; sf2[t] = f2[b * 152 + t]; }
  __syncthreads();
  if (t < 152) {
    int k = t / 19, i = t % 19;
    float fi = sf1[t];
    float v[19];
    float mx = -1e30f;
#pragma unroll
    for (int j = 0; j < 19; ++j) {
      float e = fi + sf2[k * 19 + j];
      e = e >= 0.f ? e : 0.2f * e;
      e = sadj[i * 19 + j] > 0.f ? e : NEG_INF_F;
      v[j] = e;
      mx = fmaxf(mx, e);
    }
    float sum = 0.f;
#pragma unroll
    for (int j = 0; j < 19; ++j) { v[j] = expf(v[j] - mx); sum += v[j]; }
    float inv = 1.f / sum;
#pragma unroll
    for (int j = 0; j < 19; ++j) satt[k][i][j] = v[j] * inv;
  }
  __syncthreads();
  for (int e = t; e < 361; e += 256) {
    int i = e / 19, j = e - i * 19;
    float s = 0.f;
#pragma unroll
    for (int k = 0; k < 8; ++k) s += satt[k][i][j];
    out[3104 + b * 361 + e] = s * 0.125f;
  }
  int h = t & 63, g = t >> 6;
  for (int row = g; row < 152; row += 4) {
    int k = row / 19, i = row - k * 19;
    const float* whp = Wh + ((size_t)(b * 152 + k * 19)) * 64 + h;
    float s = 0.f;
#pragma unroll
    for (int j = 0; j < 19; ++j) s = fmaf(satt[k][i][j], whp[j * 64], s);
    xb[((size_t)b * 19 + i) * 512 + k * 64 + h] = s > 0.f ? s : expm1f(s);
  }
  // absorbed sh_k: slices_hidden + slices_out
  if (t < 128) {
    float s = 0.f;
    for (int c = 0; c < 16; ++c) s += feats[(size_t)(b * 16 + c) * 128 + t];
    s *= (1.f / 16.f);
    out[b * 128 + t] = s;
    shh[t] = s;
  }
  __syncthreads();
  if (t < 2) {
    float a0 = 0.f, a1 = 0.f, a2 = 0.f, a3 = 0.f;
    for (int e = 0; e < 128; e += 4) {
      a0 = fmaf(shh[e], sfcw[e * 2 + t], a0);
      a1 = fmaf(shh[e + 1], sfcw[(e + 1) * 2 + t], a1);
      a2 = fmaf(shh[e + 2], sfcw[(e + 2) * 2 + t], a2);
      a3 = fmaf(shh[e + 3], sfcw[(e + 3) * 2 + t], a3);
    }
    out[3088 + b * 2 + t] = sfcb[t] + ((a0 + a1) + (a2 + a3));
  }
}

// ---------------- Wh2 = x @ out_W, plus o1/o2 projections -------------------
__global__ __launch_bounds__(128) void wh2_k(
    const float* __restrict__ xb, const float* __restrict__ outW,
    const float* __restrict__ oa, float* __restrict__ Wh2,
    float* __restrict__ o1, float* __restrict__ o2) {
  int bn = blockIdx.x, t = threadIdx.x;  // bn = b*19+n
  __shared__ float sx[512];
  __shared__ float r1[128], r2[128];
  for (int m = t; m < 512; m += 128) sx[m] = xb[(size_t)bn * 512 + m];
  __syncthreads();
  float a0 = 0.f, a1 = 0.f, a2 = 0.f, a3 = 0.f;
  for (int m = 0; m < 512; m += 4) {
    a0 = fmaf(sx[m], outW[m * 128 + t], a0);
    a1 = fmaf(sx[m + 1], outW[(m + 1) * 128 + t], a1);
    a2 = fmaf(sx[m + 2], outW[(m + 2) * 128 + t], a2);
    a3 = fmaf(sx[m + 3], outW[(m + 3) * 128 + t], a3);
  }
  float a = (a0 + a1) + (a2 + a3);
  Wh2[(size_t)bn * 128 + t] = a;
  r1[t] = a * oa[t];
  r2[t] = a * oa[128 + t];
  __syncthreads();
  for (int s = 64; s > 0; s >>= 1) {
    if (t < s) { r1[t] += r1[t + s]; r2[t] += r2[t + s]; }
    __syncthreads();
  }
  if (t == 0) { o1[bn] = r1[0]; o2[bn] = r2[0]; }
}

// ---------------- layer-2 attention row 0 + heads ---------------------------
__global__ __launch_bounds__(256) void final_k(
    const float* __restrict__ adj, const float* __restrict__ o1,
    const float* __restrict__ o2, const float* __restrict__ Wh2,
    const float* __restrict__ llw, const float* __restrict__ llb,
    const float* __restrict__ fcw, const float* __restrict__ fcb,
    float* __restrict__ out) {
  int b = blockIdx.x, t = threadIdx.x;
  __shared__ float sA[19], sF[128], sG[256];
  if (t < 19) {
    float e = o1[b * 19] + o2[b * 19 + t];
    e = e >= 0.f ? e : 0.2f * e;
    sA[t] = adj[t] > 0.f ? e : NEG_INF_F;  // adj row 0
  }
  __syncthreads();
  if (t == 0) {
    float mx = -1e30f;
    for (int j = 0; j < 19; ++j) mx = fmaxf(mx, sA[j]);
    float sum = 0.f;
    for (int j = 0; j < 19; ++j) { sA[j] = expf(sA[j] - mx); sum += sA[j]; }
    float inv = 1.f / sum;
    for (int j = 0; j < 19; ++j) sA[j] *= inv;
  }
  __syncthreads();
  if (t < 128) {
    float s = 0.f;
    for (int j = 0; j < 19; ++j) s = fmaf(sA[j], Wh2[(size_t)(b * 19 + j) * 128 + t], s);
    sF[t] = s > 0.f ? s : expm1f(s);
  }
  __syncthreads();
  {
    float a0 = 0.f, a1 = 0.f, a2 = 0.f, a3 = 0.f;
    for (int e = 0; e < 128; e += 4) {
      a0 = fmaf(sF[e], llw[e * 256 + t], a0);
      a1 = fmaf(sF[e + 1], llw[(e + 1) * 256 + t], a1);
      a2 = fmaf(sF[e + 2], llw[(e + 2) * 256 + t], a2);
      a3 = fmaf(sF[e + 3], llw[(e + 3) * 256 + t], a3);
    }
    float a = fmaxf(llb[t] + ((a0 + a1) + (a2 + a3)), 0.f);
    sG[t] = a;
    out[1024 + b * 256 + t] = a;
  }
  __syncthreads();
  if (t < 2) {
    float a0 = 0.f, a1 = 0.f, a2 = 0.f, a3 = 0.f;
    for (int o = 0; o < 256; o += 4) {
      a0 = fmaf(sG[o], fcw[o * 2 + t], a0);
      a1 = fmaf(sG[o + 1], fcw[(o + 1) * 2 + t], a1);
      a2 = fmaf(sG[o + 2], fcw[(o + 2) * 2 + t], a2);
      a3 = fmaf(sG[o + 3], fcw[(o + 3) * 2 + t], a3);
    }
    out[3072 + b * 2 + t] = fcb[t] + ((a0 + a1) + (a2 + a3));
  }
}

// ---------------------------------------------------------------------------
extern "C" void kernel_launch(void* const* d_in, const int* in_sizes, int n_in,
                              void* d_out, int out_size, void* d_ws, size_t ws_size,
                              hipStream_t stream) {
  const float* in_img   = (const float*)d_in[0];
  const float* w1       = (const float*)d_in[1];
  const float* b1       = (const float*)d_in[2];
  const float* w2       = (const float*)d_in[3];
  const float* b2       = (const float*)d_in[4];
  const float* w3       = (const float*)d_in[5];
  const float* b3       = (const float*)d_in[6];
  const float* w4       = (const float*)d_in[7];
  const float* b4       = (const float*)d_in[8];
  const float* fc_cnn_w = (const float*)d_in[9];
  const float* fc_cnn_b = (const float*)d_in[10];
  const float* att_W    = (const float*)d_in[11];
  const float* att_a    = (const float*)d_in[12];
  const float* out_W    = (const float*)d_in[13];
  const float* out_a    = (const float*)d_in[14];
  const float* ll_w     = (const float*)d_in[15];
  const float* ll_b     = (const float*)d_in[16];
  const float* fc_w     = (const float*)d_in[17];
  const float* fc_b     = (const float*)d_in[18];
  const float* sfc_w    = (const float*)d_in[19];
  const float* sfc_b    = (const float*)d_in[20];
  float* out = (float*)d_out;

  // ---- workspace layout ----------------------------------------------------
  float* p = (float*)d_ws;
  float* adj   = p; p += 361;
  float* feats = p; p += 16384;
  float* Wh    = p; p += 77824;
  float* f1    = p; p += 1216;
  float* f2    = p; p += 1216;
  float* xb    = p; p += 77824;
  float* Wh2   = p; p += 19456;
  float* o1    = p; p += 152;
  float* o2    = p; p += 152;
  char* base = (char*)p;
  auto align16 = [&]() { base = (char*)(((uintptr_t)base + 15) & ~(uintptr_t)15); };
  align16();
  auto aus = [&](size_t n) { unsigned short* q = (unsigned short*)base; base += n * 2; return q; };
  unsigned short* bp2 = aus((size_t)2 * 9 * 64 * 2 * 8);
  unsigned short* bp3 = aus((size_t)4 * 18 * 64 * 2 * 8);
  unsigned short* bp4 = aus((size_t)4 * 36 * 64 * 2 * 8);
  align16();
  size_t fixed_bytes = (size_t)(base - (char*)d_ws);
  // per-image (ushort elems, single plane): c2o 73984, c3o 41472, c4o 12800
  constexpr size_t PER_IMG_SH = 73984 + 41472 + 12800;
  int chunk = 128;
  while (chunk > 1 && fixed_bytes + (size_t)chunk * PER_IMG_SH * 2 > ws_size)
    chunk >>= 1;
  unsigned short* buf2H = (unsigned short*)base;
  unsigned short* buf3H = buf2H + (size_t)chunk * 73984;
  unsigned short* buf4H = buf3H + (size_t)chunk * 41472;

  prep_k<<<118, 256, 0, stream>>>(w2, w3, w4, bp2, bp3, bp4, adj);

  for (int c0 = 0; c0 < 128; c0 += chunk) {
    conv12_k<<<dim3(32, 1, chunk), 256, 0, stream>>>(
        in_img + (size_t)c0 * 16384, w1, b1, bp2, b2, buf2H);
    conv_mfma_k<64, 128, 32, 4><<<dim3(8, 1, chunk), 256, 0, stream>>>(
        buf2H, bp3, b3, buf3H);
    conv_mfma_k<128, 128, 16, 4, false><<<dim3(4, 1, chunk), 256, 0, stream>>>(
        buf3H, bp4, b4, buf4H);
    meanfc_k<<<chunk, 128, 0, stream>>>(buf4H, fc_cnn_w, fc_cnn_b, feats, c0);
  }

  wh_k<<<1216, 64, 0, stream>>>(feats, att_W, att_a, Wh, f1, f2);
  gat1_k<<<8, 256, 0, stream>>>(f1, f2, adj, Wh, feats, sfc_w, sfc_b, out, xb);
  wh2_k<<<152, 128, 0, stream>>>(xb, out_W, out_a, Wh2, o1, o2);
  final_k<<<8, 256, 0, stream>>>(adj, o1, o2, Wh2, ll_w, ll_b, fc_w, fc_b, out);
}

// Round 21
// 141.159 us; speedup vs baseline: 6.7627x; 1.0676x over previous
//
#include <hip/hip_runtime.h>
#include <hip/hip_bf16.h>
#include <math.h>

// ---------------------------------------------------------------------------
// GATEmbedding. ROUND-21: conv12 R=4 two-tile (round-6 structure, plain-bf16
// numerics): 6-row patch, conv1 redundancy 1.94x -> 1.45x, acc reused across
// two sequential MFMA tiles (no VGPR growth). All convs plain bf16 (hi-only
// weights+activations, fp32 accumulate, 1 MFMA/frag). conv3/conv4 NFR=4 with
// global_load_lds DMA staging; conv4 PAD=false. prep fused; sh_k in gat1_k.
// Outputs (flat): slices_hidden(8,128)@0, image_feature_second(8,256)@1024,
//   prediction(8,2)@3072, slices_out(8,2)@3088, batch_attention(8,19,19)@3104
// ---------------------------------------------------------------------------

#define NEG_INF_F (-9.0e15f)

typedef __attribute__((ext_vector_type(8))) short frag8;
typedef __attribute__((ext_vector_type(4))) float f32x4;
typedef const __attribute__((address_space(1))) void GasV;
typedef __attribute__((address_space(3))) void LasV;

__device__ __forceinline__ unsigned short f2bf(float f) {
  union { float f; unsigned u; } v; v.f = f;
  unsigned r = v.u + 0x7fffu + ((v.u >> 16) & 1u);   // RNE
  return (unsigned short)(r >> 16);
}
__device__ __forceinline__ float bf2f(unsigned short u) {
  union { unsigned u; float f; } v; v.u = ((unsigned)u) << 16;
  return v.f;
}

// LDS 16B-slot swizzle so a ds_read_b128 16-lane phase is <=2-way per bank.
template <int C>
__device__ __forceinline__ int swz(int slot, int px) {
  if constexpr (C == 32) return slot ^ ((px >> 1) & 3);
  else return slot ^ (px & 7);   // C=64: full; C=128: low 3 slot bits
}

// ---- B-prep device body: pack w[oc][c][3][3] f32 -> bf16 per-lane frags ----
template <int C, int OC>
__device__ __forceinline__ void bprep_dev(const float* __restrict__ w,
                                          unsigned short* __restrict__ bp, int idx) {
  constexpr int CS = C / 32, NSTEP = 9 * CS, NG = (OC / 64) * 2;
  if (idx >= NG * NSTEP * 64 * 2) return;
  int q = idx & 1;
  int lane = (idx >> 1) & 63;
  int gs = idx >> 7;
  int s = gs % NSTEP;
  int g = gs / NSTEP;
  int off = s / CS, c0 = (s % CS) * 32;
  int l15 = lane & 15, l4 = lane >> 4;
  int oc = (g >> 1) * 64 + (g & 1) * 32 + q * 16 + l15;
  int kc = c0 + l4 * 8;
  unsigned short o8[8];
#pragma unroll
  for (int j = 0; j < 8; ++j)
    o8[j] = f2bf(w[((size_t)oc * C + kc + j) * 9 + off]);
  *(uint4*)(bp + (size_t)idx * 8) = *(uint4*)o8;
}

// ---- prep: adjacency (block 0) + bprep2 (1..9) + bprep3 (10..45) +
//      bprep4 (46..117) in one launch ---------------------------------------
__global__ __launch_bounds__(256) void prep_k(
    const float* __restrict__ w2, const float* __restrict__ w3,
    const float* __restrict__ w4, unsigned short* __restrict__ bp2,
    unsigned short* __restrict__ bp3, unsigned short* __restrict__ bp4,
    float* __restrict__ adj) {
  const int bx = blockIdx.x, t = threadIdx.x;
  if (bx == 0) {
    __shared__ float A[19][19];
    for (int e = t; e < 361; e += 256) {
      int i = e / 19, j = e % 19;
      float v = 0.f;
      const int MIDN = 3, N = 19, MID = 10, WIDTH = 2;
      if (i < MIDN) {
        if (i == MIDN - 1) { if (j > MIDN - 1) v = 1.f; }
        else if (j == i + 1 || (j > MID - (i + 1) * WIDTH && j < MID + (i + 1) * WIDTH)) v = 1.f;
      } else {
        if (i == MIDN) { if (j == MIDN + 1) v = 1.f; }
        else if (i == N - 1) { if (j == N - 2) v = 1.f; }
        else if (j == i - 1 || j == i + 1) v = 1.f;
      }
      if (i == j) v += 1.f;
      A[i][j] = v;
    }
    __syncthreads();
    for (int e = t; e < 361; e += 256) {
      int i = e / 19;
      float rs = 0.f;
      for (int j = 0; j < 19; ++j) rs += A[i][j];
      float rinv = rs > 0.f ? 1.f / rs : 0.f;
      adj[e] = A[i][e % 19] * rinv;
    }
  } else if (bx <= 9) {
    bprep_dev<32, 64>(w2, bp2, (bx - 1) * 256 + t);
  } else if (bx <= 45) {
    bprep_dev<64, 128>(w3, bp3, (bx - 10) * 256 + t);
  } else {
    bprep_dev<128, 128>(w4, bp4, (bx - 46) * 256 + t);
  }
}

// ---- conv12: conv1 (1->32, SGPR weights) in-LDS, conv2 MFMA (32->64) -------
// R=4 two-tile: 6-row patch, two sequential MFMA tiles reuse acc[4][2].
// grid (16, 1, imgs). conv1 thread = (px = t&63, ocg = t>>6 wave-uniform).
__global__ __launch_bounds__(256) void conv12_k(
    const float* __restrict__ in, const float* __restrict__ w1,
    const float* __restrict__ b1, const unsigned short* __restrict__ bprep,
    const float* __restrict__ bias, unsigned short* __restrict__ outH) {
  constexpr int C = 32, OC = 64, W = 64;
  constexpr int PW = W + 2, OH = W / 2;
  constexpr int NSTEP = 9;
  __shared__ float sr[14][132];
  __shared__ __align__(16) unsigned short patchH[6 * PW * C];
  const int t = threadIdx.x;
  const int img = blockIdx.z;
  const int y0 = blockIdx.x * 4;        // base padded pooled row / conv-row base
  const int pr0 = blockIdx.x * 2;       // base unpadded pooled-out row
  const size_t out_img = (size_t)img * 34 * 34 * OC;

  // stage raw image rows 2*y0-3 .. 2*y0+10 (col c = x+1, zero OOB)
  const float* ip = in + (size_t)img * 16384;
  for (int e = t; e < 14 * 130; e += 256) {
    int s = e / 130, c = e - s * 130;
    int y = 2 * y0 - 3 + s, x = c - 1;
    sr[s][c] = (y >= 0 && y < 128 && x >= 0 && x < 128) ? ip[y * 128 + x] : 0.f;
  }
  __syncthreads();

  // conv1+relu+pool 6 rows into swizzled HI patch; weights/bias via SGPR
  {
    const int px = t & 63, ocg = t >> 6;
    const int gx = px + 1;
    const int ssl = swz<C>(ocg, gx);
    const int ocg_s = __builtin_amdgcn_readfirstlane(ocg);
    const float* wg = w1 + ocg_s * 72;   // 8 oc x 9 taps
    const float* bg = b1 + ocg_s * 8;
#pragma unroll
    for (int r = 0; r < 6; ++r) {
      int rp = y0 + r;                   // padded pooled row
      unsigned short h8[8];
      if (rp == 0 || rp == 65) {
#pragma unroll
        for (int i = 0; i < 8; ++i) h8[i] = 0;
      } else {
        float v[4][4];
#pragma unroll
        for (int dy = 0; dy < 4; ++dy)
#pragma unroll
          for (int dx = 0; dx < 4; ++dx) v[dy][dx] = sr[2 * r + dy][2 * px + dx];
#pragma unroll
        for (int i = 0; i < 8; ++i) {
          float m = -1e30f;
#pragma unroll
          for (int dy = 0; dy < 2; ++dy)
#pragma unroll
            for (int dx = 0; dx < 2; ++dx) {
              float a = 0.f;
#pragma unroll
              for (int ky = 0; ky < 3; ++ky)
#pragma unroll
                for (int kx = 0; kx < 3; ++kx)
                  a = fmaf(v[dy + ky][dx + kx], wg[i * 9 + ky * 3 + kx], a);
              m = fmaxf(m, a);
            }
          h8[i] = f2bf(fmaxf(m + bg[i], 0.f));
        }
      }
      *(uint4*)(patchH + (r * PW + gx) * C + ssl * 8) = *(uint4*)h8;
    }
    if (t < 48) {   // left/right pad pixels: 6 rows x 2 sides x 4 slots (H only)
      int r = t >> 3, rem = t & 7;
      int side = rem >> 2, q = rem & 3;
      const uint4 z4 = {0u, 0u, 0u, 0u};
      *(uint4*)(patchH + (r * PW + side * (PW - 1)) * C + q * 8) = z4;
    }
  }
  __syncthreads();

  // MFMA: two sequential tiles (conv rows y0+2tt .. y0+2tt+1), acc reused
  const int lane = t & 63, wid = t >> 6;
  const int wm = wid >> 1, wn = wid & 1;
  const int l15 = lane & 15, l4 = lane >> 4;
  const int nbase = wn * 32;
  const unsigned short* bpw = bprep + ((size_t)wn * NSTEP * 64 + lane) * 16;
  const float bb0 = bias[nbase + l15], bb1 = bias[nbase + 16 + l15];

#pragma unroll
  for (int tt = 0; tt < 2; ++tt) {
    f32x4 acc[4][2] = {};
    for (int s = 0; s < NSTEP; ++s) {
      const frag8* bp = (const frag8*)(bpw + (size_t)s * 1024);
      frag8 bh0 = bp[0], bh1 = bp[1];
      const int ky = s / 3, kx = s - ky * 3;
      frag8 ah[4];
#pragma unroll
      for (int f = 0; f < 4; ++f) {
        int m0 = wm * 32 + (f & 1) * 16 + (f >> 1) * 64;
        int ry = m0 / W + 2 * tt + ky;
        int px = (m0 % W) + l15 + kx;
        ah[f] = *(const frag8*)(patchH + ((size_t)ry * PW + px) * C + swz<C>(l4, px) * 8);
      }
#pragma unroll
      for (int f = 0; f < 4; ++f) {
        acc[f][0] = __builtin_amdgcn_mfma_f32_16x16x32_bf16(ah[f], bh0, acc[f][0], 0, 0, 0);
        acc[f][1] = __builtin_amdgcn_mfma_f32_16x16x32_bf16(ah[f], bh1, acc[f][1], 0, 0, 0);
      }
    }
    // epilogue tile tt: bias + relu + 2x2 pool, HI-only write (row pr0+tt)
#pragma unroll
    for (int pi = 0; pi < 2; ++pi) {
      const int fa = pi, fb = pi + 2;
      const int pxb = wm * 16 + pi * 8;
#pragma unroll
      for (int n = 0; n < 2; ++n) {
        const float bb = n ? bb1 : bb0;
#pragma unroll
        for (int xp = 0; xp < 2; ++xp) {
          float v = fmaxf(fmaxf(acc[fa][n][2 * xp], acc[fa][n][2 * xp + 1]),
                          fmaxf(acc[fb][n][2 * xp], acc[fb][n][2 * xp + 1]));
          outH[out_img + ((size_t)(pr0 + tt + 1) * 34 + pxb + 2 * l4 + xp + 1) * OC +
               nbase + n * 16 + l15] = f2bf(fmaxf(v + bb, 0.f));
        }
      }
    }
  }

  // zero pad borders (H plane)
  const uint4 z4 = {0u, 0u, 0u, 0u};
  if (t < 32) {
    int r = t >> 4, side = (t >> 3) & 1, q = t & 7;
    *(uint4*)(outH + out_img + ((size_t)(pr0 + r + 1) * 34 + side * 33) * OC + q * 8) = z4;
  }
  if (pr0 == 0)
    for (int e = t; e < 272; e += 256)
      *(uint4*)(outH + out_img + (size_t)e * 8) = z4;
  if (pr0 + 2 == OH)
    for (int e = t; e < 272; e += 256)
      *(uint4*)(outH + out_img + (size_t)33 * 34 * OC + (size_t)e * 8) = z4;
}

// ------- implicit-GEMM bf16 MFMA conv+relu+pool, HI-only act ----------------
// One block covers ALL OC=128: wave wn -> 64 oc = 4 n-frags. DMA staging.
// PAD=false skips border-pad writes (interior-only consumers, e.g. conv4).
template <int C, int OC, int W, int R, bool PAD = true>
__global__ __launch_bounds__(256) void conv_mfma_k(
    const unsigned short* __restrict__ inH,
    const unsigned short* __restrict__ bprep, const float* __restrict__ bias,
    unsigned short* __restrict__ outH) {
  constexpr int SL = C / 8;
  constexpr int PW = W + 2;
  constexpr int OW = W / 2, OH = W / 2;
  constexpr int PR = R / 2;
  constexpr int CS = C / 32;
  constexpr int NSTEP = 9 * CS;
  constexpr int M = R * W;
  constexpr int MF = M / 32;
  constexpr int E = (R + 2) * PW * SL;
  constexpr int EP = (E + 63) & ~63;
  __shared__ __align__(16) unsigned short patchH[(R + 2) * PW * C + 256];
  const int t = threadIdx.x;
  const int img = blockIdx.z;
  const int y0 = blockIdx.x * R;
  const int pr0 = blockIdx.x * PR;
  const size_t in_img = (size_t)img * (W + 2) * (W + 2) * C;
  const size_t out_img = (size_t)img * (OW + 2) * (OW + 2) * OC;

  {
    const unsigned short* gH = inH + in_img + (size_t)y0 * PW * C;
    for (int e0 = t; e0 < EP; e0 += 256) {
      int e = e0 < E ? e0 : E - 1;
      int row = e / (PW * SL);
      int rem = e - row * (PW * SL);
      int px = rem / SL, sl = rem & (SL - 1);
      int goff = row * PW * C + px * C + swz<C>(sl, px) * 8;
      int lbase = __builtin_amdgcn_readfirstlane(e0 & ~63) * 8;
      __builtin_amdgcn_global_load_lds((GasV*)(gH + goff), (LasV*)(patchH + lbase), 16, 0, 0);
    }
  }
  __syncthreads();

  const int lane = t & 63, wid = t >> 6;
  const int wm = wid >> 1, wn = wid & 1;
  const int l15 = lane & 15, l4 = lane >> 4;
  const int nbase = wn * 64;

  f32x4 acc[MF][4] = {};
  const unsigned short* bpw0 =
      bprep + (((size_t)(wn * 2 + 0) * NSTEP) * 64 + lane) * 16;
  const unsigned short* bpw1 =
      bprep + (((size_t)(wn * 2 + 1) * NSTEP) * 64 + lane) * 16;

  for (int s = 0; s < NSTEP; ++s) {
    const frag8* bp0 = (const frag8*)(bpw0 + (size_t)s * 1024);
    const frag8* bp1 = (const frag8*)(bpw1 + (size_t)s * 1024);
    frag8 bh0 = bp0[0], bh1 = bp0[1], bh2 = bp1[0], bh3 = bp1[1];
    const int off = s / CS, c0 = (s % CS) * 32;
    const int ky = off / 3, kx = off - ky * 3;
    const int slin = (c0 >> 3) + l4;
    frag8 ah[MF];
#pragma unroll
    for (int f = 0; f < MF; ++f) {
      int m0 = wm * (M / 2) + f * 16;
      int ry = m0 / W + ky;
      int px = (m0 % W) + l15 + kx;
      ah[f] = *(const frag8*)(patchH + ((size_t)ry * PW + px) * C + swz<C>(slin, px) * 8);
    }
#pragma unroll
    for (int f = 0; f < MF; ++f) {
      acc[f][0] = __builtin_amdgcn_mfma_f32_16x16x32_bf16(ah[f], bh0, acc[f][0], 0, 0, 0);
      acc[f][1] = __builtin_amdgcn_mfma_f32_16x16x32_bf16(ah[f], bh1, acc[f][1], 0, 0, 0);
      acc[f][2] = __builtin_amdgcn_mfma_f32_16x16x32_bf16(ah[f], bh2, acc[f][2], 0, 0, 0);
      acc[f][3] = __builtin_amdgcn_mfma_f32_16x16x32_bf16(ah[f], bh3, acc[f][3], 0, 0, 0);
    }
  }

  float bb[4];
#pragma unroll
  for (int n = 0; n < 4; ++n) bb[n] = bias[nbase + n * 16 + l15];
#pragma unroll
  for (int pi = 0; pi < MF / 2; ++pi) {
    const int fa = (W == 16) ? (pi * 2) : pi;
    const int fb = (W == 16) ? (pi * 2 + 1) : (pi + 2);
    const int m0a = wm * (M / 2) + fa * 16;
    const int prow = (y0 + m0a / W) >> 1;
    const int pxb = (m0a % W) >> 1;
#pragma unroll
    for (int n = 0; n < 4; ++n) {
#pragma unroll
      for (int xp = 0; xp < 2; ++xp) {
        float v = fmaxf(fmaxf(acc[fa][n][2 * xp], acc[fa][n][2 * xp + 1]),
                        fmaxf(acc[fb][n][2 * xp], acc[fb][n][2 * xp + 1]));
        outH[out_img + ((size_t)(prow + 1) * (OW + 2) + pxb + 2 * l4 + xp + 1) * OC +
             nbase + n * 16 + l15] = f2bf(fmaxf(v + bb[n], 0.f));
      }
    }
  }

  if constexpr (PAD) {
    const uint4 z4 = {0u, 0u, 0u, 0u};
    if (t < PR * 32) {
      int r = t >> 5, rem = t & 31;
      int side = rem >> 4, q = rem & 15;
      *(uint4*)(outH + out_img + ((size_t)(pr0 + r + 1) * (OW + 2) + side * (OW + 1)) * OC +
                q * 8) = z4;
    }
    if (pr0 == 0)
      for (int e = t; e < (OW + 2) * 16; e += 256)
        *(uint4*)(outH + out_img + (size_t)(e >> 4) * OC + (e & 15) * 8) = z4;
    if (pr0 + PR == OH)
      for (int e = t; e < (OW + 2) * 16; e += 256)
        *(uint4*)(outH + out_img + ((size_t)(OH + 1) * (OW + 2) + (e >> 4)) * OC +
                  (e & 15) * 8) = z4;
  }
}

// ---------------- spatial mean (8x8 interior, HI plane) + fc ----------------
__global__ __launch_bounds__(128) void meanfc_k(
    const unsigned short* __restrict__ c4H, const float* __restrict__ fcw,
    const float* __restrict__ fcb, float* __restrict__ feats, int img0) {
  int img = blockIdx.x, t = threadIdx.x;
  __shared__ float sM[128];
  const unsigned short* pH = c4H + (size_t)img * 12800;
  float s0 = 0.f, s1 = 0.f;
  for (int pix = 0; pix < 64; pix += 2) {
    int py0 = pix >> 3, px0 = pix & 7;
    int py1 = (pix + 1) >> 3, px1 = (pix + 1) & 7;
    s0 += bf2f(pH[((size_t)(py0 + 1) * 10 + px0 + 1) * 128 + t]);
    s1 += bf2f(pH[((size_t)(py1 + 1) * 10 + px1 + 1) * 128 + t]);
  }
  sM[t] = (s0 + s1) * (1.f / 64.f);
  __syncthreads();
  float a0 = 0.f, a1 = 0.f, a2 = 0.f, a3 = 0.f;
  for (int c = 0; c < 128; c += 4) {
    a0 = fmaf(sM[c], fcw[c * 128 + t], a0);
    a1 = fmaf(sM[c + 1], fcw[(c + 1) * 128 + t], a1);
    a2 = fmaf(sM[c + 2], fcw[(c + 2) * 128 + t], a2);
    a3 = fmaf(sM[c + 3], fcw[(c + 3) * 128 + t], a3);
  }
  feats[(size_t)(img0 + img) * 128 + t] = fcb[t] + ((a0 + a1) + (a2 + a3));
}

// ---------------- Wh = slices @ att_W, plus f1/f2 projections ---------------
__global__ __launch_bounds__(64) void wh_k(
    const float* __restrict__ feats, const float* __restrict__ attW,
    const float* __restrict__ atta, float* __restrict__ Wh,
    float* __restrict__ f1, float* __restrict__ f2) {
  int bid = blockIdx.x;           // b*152 + k*19 + n
  int n = bid % 19;
  int k = (bid / 19) % 8;
  int b = bid / 152;
  int h = threadIdx.x;
  float acc = 0.f;
  if (n >= 3) {
    const float* s = feats + (size_t)(b * 16 + n - 3) * 128;
    const float* W = attW + (size_t)k * 8192 + h;
    float a0 = 0.f, a1 = 0.f, a2 = 0.f, a3 = 0.f;
    for (int f = 0; f < 128; f += 4) {
      a0 = fmaf(s[f], W[f * 64], a0);
      a1 = fmaf(s[f + 1], W[(f + 1) * 64], a1);
      a2 = fmaf(s[f + 2], W[(f + 2) * 64], a2);
      a3 = fmaf(s[f + 3], W[(f + 3) * 64], a3);
    }
    acc = (a0 + a1) + (a2 + a3);
  }
  Wh[(size_t)bid * 64 + h] = acc;
  float p1 = acc * atta[k * 128 + h];
  float p2 = acc * atta[k * 128 + 64 + h];
#pragma unroll
  for (int off = 32; off > 0; off >>= 1) {
    p1 += __shfl_down(p1, off);
    p2 += __shfl_down(p2, off);
  }
  if (h == 0) { f1[bid] = p1; f2[bid] = p2; }
}

// ---- fused GAT layer 1 + slices head: softmax + head-mean + h=att@Wh + elu
//      + slices_hidden/slices_out (absorbed sh_k) ---------------------------
__global__ __launch_bounds__(256) void gat1_k(
    const float* __restrict__ f1, const float* __restrict__ f2,
    const float* __restrict__ adj, const float* __restrict__ Wh,
    const float* __restrict__ feats, const float* __restrict__ sfcw,
    const float* __restrict__ sfcb, float* __restrict__ out,
    float* __restrict__ xb) {
  int b = blockIdx.x, t = threadIdx.x;
  __shared__ float satt[8][19][19];
  __shared__ float sadj[361], sf1[152], sf2[152];
  __shared__ float shh[128];
  for (int e = t; e < 361; e += 256) sadj[e] = adj[e];
  if (t < 152) { sf1[t] = f1[b * 152 + t]; sf2[t] = f2[b * 152 + t]; }
  __syncthreads();
  if (t < 152) {
    int k = t / 19, i = t % 19;
    float fi = sf1[t];
    float v[19];
    float mx = -1e30f;
#pragma unroll
    for (int j = 0; j < 19; ++j) {
      float e = fi + sf2[k * 19 + j];
      e = e >= 0.f ? e : 0.2f * e;
      e = sadj[i * 19 + j] > 0.f ? e : NEG_INF_F;
      v[j] = e;
      mx = fmaxf(mx, e);
    }
    float sum = 0.f;
#pragma unroll
    for (int j = 0; j < 19; ++j) { v[j] = expf(v[j] - mx); sum += v[j]; }
    float inv = 1.f / sum;
#pragma unroll
    for (int j = 0; j < 19; ++j) satt[k][i][j] = v[j] * inv;
  }
  __syncthreads();
  for (int e = t; e < 361; e += 256) {
    int i = e / 19, j = e - i * 19;
    float s = 0.f;
#pragma unroll
    for (int k = 0; k < 8; ++k) s += satt[k][i][j];
    out[3104 + b * 361 + e] = s * 0.125f;
  }
  int h = t & 63, g = t >> 6;
  for (int row = g; row < 152; row += 4) {
    int k = row / 19, i = row - k * 19;
    const float* whp = Wh + ((size_t)(b * 152 + k * 19)) * 64 + h;
    float s = 0.f;
#pragma unroll
    for (int j = 0; j < 19; ++j) s = fmaf(satt[k][i][j], whp[j * 64], s);
    xb[((size_t)b * 19 + i) * 512 + k * 64 + h] = s > 0.f ? s : expm1f(s);
  }
  // absorbed sh_k: slices_hidden + slices_out
  if (t < 128) {
    float s = 0.f;
    for (int c = 0; c < 16; ++c) s += feats[(size_t)(b * 16 + c) * 128 + t];
    s *= (1.f / 16.f);
    out[b * 128 + t] = s;
    shh[t] = s;
  }
  __syncthreads();
  if (t < 2) {
    float a0 = 0.f, a1 = 0.f, a2 = 0.f, a3 = 0.f;
    for (int e = 0; e < 128; e += 4) {
      a0 = fmaf(shh[e], sfcw[e * 2 + t], a0);
      a1 = fmaf(shh[e + 1], sfcw[(e + 1) * 2 + t], a1);
      a2 = fmaf(shh[e + 2], sfcw[(e + 2) * 2 + t], a2);
      a3 = fmaf(shh[e + 3], sfcw[(e + 3) * 2 + t], a3);
    }
    out[3088 + b * 2 + t] = sfcb[t] + ((a0 + a1) + (a2 + a3));
  }
}

// ---------------- Wh2 = x @ out_W, plus o1/o2 projections -------------------
__global__ __launch_bounds__(128) void wh2_k(
    const float* __restrict__ xb, const float* __restrict__ outW,
    const float* __restrict__ oa, float* __restrict__ Wh2,
    float* __restrict__ o1, float* __restrict__ o2) {
  int bn = blockIdx.x, t = threadIdx.x;  // bn = b*19+n
  __shared__ float sx[512];
  __shared__ float r1[128], r2[128];
  for (int m = t; m < 512; m += 128) sx[m] = xb[(size_t)bn * 512 + m];
  __syncthreads();
  float a0 = 0.f, a1 = 0.f, a2 = 0.f, a3 = 0.f;
  for (int m = 0; m < 512; m += 4) {
    a0 = fmaf(sx[m], outW[m * 128 + t], a0);
    a1 = fmaf(sx[m + 1], outW[(m + 1) * 128 + t], a1);
    a2 = fmaf(sx[m + 2], outW[(m + 2) * 128 + t], a2);
    a3 = fmaf(sx[m + 3], outW[(m + 3) * 128 + t], a3);
  }
  float a = (a0 + a1) + (a2 + a3);
  Wh2[(size_t)bn * 128 + t] = a;
  r1[t] = a * oa[t];
  r2[t] = a * oa[128 + t];
  __syncthreads();
  for (int s = 64; s > 0; s >>= 1) {
    if (t < s) { r1[t] += r1[t + s]; r2[t] += r2[t + s]; }
    __syncthreads();
  }
  if (t == 0) { o1[bn] = r1[0]; o2[bn] = r2[0]; }
}

// ---------------- layer-2 attention row 0 + heads ---------------------------
__global__ __launch_bounds__(256) void final_k(
    const float* __restrict__ adj, const float* __restrict__ o1,
    const float* __restrict__ o2, const float* __restrict__ Wh2,
    const float* __restrict__ llw, const float* __restrict__ llb,
    const float* __restrict__ fcw, const float* __restrict__ fcb,
    float* __restrict__ out) {
  int b = blockIdx.x, t = threadIdx.x;
  __shared__ float sA[19], sF[128], sG[256];
  if (t < 19) {
    float e = o1[b * 19] + o2[b * 19 + t];
    e = e >= 0.f ? e : 0.2f * e;
    sA[t] = adj[t] > 0.f ? e : NEG_INF_F;  // adj row 0
  }
  __syncthreads();
  if (t == 0) {
    float mx = -1e30f;
    for (int j = 0; j < 19; ++j) mx = fmaxf(mx, sA[j]);
    float sum = 0.f;
    for (int j = 0; j < 19; ++j) { sA[j] = expf(sA[j] - mx); sum += sA[j]; }
    float inv = 1.f / sum;
    for (int j = 0; j < 19; ++j) sA[j] *= inv;
  }
  __syncthreads();
  if (t < 128) {
    float s = 0.f;
    for (int j = 0; j < 19; ++j) s = fmaf(sA[j], Wh2[(size_t)(b * 19 + j) * 128 + t], s);
    sF[t] = s > 0.f ? s : expm1f(s);
  }
  __syncthreads();
  {
    float a0 = 0.f, a1 = 0.f, a2 = 0.f, a3 = 0.f;
    for (int e = 0; e < 128; e += 4) {
      a0 = fmaf(sF[e], llw[e * 256 + t], a0);
      a1 = fmaf(sF[e + 1], llw[(e + 1) * 256 + t], a1);
      a2 = fmaf(sF[e + 2], llw[(e + 2) * 256 + t], a2);
      a3 = fmaf(sF[e + 3], llw[(e + 3) * 256 + t], a3);
    }
    float a = fmaxf(llb[t] + ((a0 + a1) + (a2 + a3)), 0.f);
    sG[t] = a;
    out[1024 + b * 256 + t] = a;
  }
  __syncthreads();
  if (t < 2) {
    float a0 = 0.f, a1 = 0.f, a2 = 0.f, a3 = 0.f;
    for (int o = 0; o < 256; o += 4) {
      a0 = fmaf(sG[o], fcw[o * 2 + t], a0);
      a1 = fmaf(sG[o + 1], fcw[(o + 1) * 2 + t], a1);
      a2 = fmaf(sG[o + 2], fcw[(o + 2) * 2 + t], a2);
      a3 = fmaf(sG[o + 3], fcw[(o + 3) * 2 + t], a3);
    }
    out[3072 + b * 2 + t] = fcb[t] + ((a0 + a1) + (a2 + a3));
  }
}

// ---------------------------------------------------------------------------
extern "C" void kernel_launch(void* const* d_in, const int* in_sizes, int n_in,
                              void* d_out, int out_size, void* d_ws, size_t ws_size,
                              hipStream_t stream) {
  const float* in_img   = (const float*)d_in[0];
  const float* w1       = (const float*)d_in[1];
  const float* b1       = (const float*)d_in[2];
  const float* w2       = (const float*)d_in[3];
  const float* b2       = (const float*)d_in[4];
  const float* w3       = (const float*)d_in[5];
  const float* b3       = (const float*)d_in[6];
  const float* w4       = (const float*)d_in[7];
  const float* b4       = (const float*)d_in[8];
  const float* fc_cnn_w = (const float*)d_in[9];
  const float* fc_cnn_b = (const float*)d_in[10];
  const float* att_W    = (const float*)d_in[11];
  const float* att_a    = (const float*)d_in[12];
  const float* out_W    = (const float*)d_in[13];
  const float* out_a    = (const float*)d_in[14];
  const float* ll_w     = (const float*)d_in[15];
  const float* ll_b     = (const float*)d_in[16];
  const float* fc_w     = (const float*)d_in[17];
  const float* fc_b     = (const float*)d_in[18];
  const float* sfc_w    = (const float*)d_in[19];
  const float* sfc_b    = (const float*)d_in[20];
  float* out = (float*)d_out;

  // ---- workspace layout ----------------------------------------------------
  float* p = (float*)d_ws;
  float* adj   = p; p += 361;
  float* feats = p; p += 16384;
  float* Wh    = p; p += 77824;
  float* f1    = p; p += 1216;
  float* f2    = p; p += 1216;
  float* xb    = p; p += 77824;
  float* Wh2   = p; p += 19456;
  float* o1    = p; p += 152;
  float* o2    = p; p += 152;
  char* base = (char*)p;
  auto align16 = [&]() { base = (char*)(((uintptr_t)base + 15) & ~(uintptr_t)15); };
  align16();
  auto aus = [&](size_t n) { unsigned short* q = (unsigned short*)base; base += n * 2; return q; };
  unsigned short* bp2 = aus((size_t)2 * 9 * 64 * 2 * 8);
  unsigned short* bp3 = aus((size_t)4 * 18 * 64 * 2 * 8);
  unsigned short* bp4 = aus((size_t)4 * 36 * 64 * 2 * 8);
  align16();
  size_t fixed_bytes = (size_t)(base - (char*)d_ws);
  // per-image (ushort elems, single plane): c2o 73984, c3o 41472, c4o 12800
  constexpr size_t PER_IMG_SH = 73984 + 41472 + 12800;
  int chunk = 128;
  while (chunk > 1 && fixed_bytes + (size_t)chunk * PER_IMG_SH * 2 > ws_size)
    chunk >>= 1;
  unsigned short* buf2H = (unsigned short*)base;
  unsigned short* buf3H = buf2H + (size_t)chunk * 73984;
  unsigned short* buf4H = buf3H + (size_t)chunk * 41472;

  prep_k<<<118, 256, 0, stream>>>(w2, w3, w4, bp2, bp3, bp4, adj);

  for (int c0 = 0; c0 < 128; c0 += chunk) {
    conv12_k<<<dim3(16, 1, chunk), 256, 0, stream>>>(
        in_img + (size_t)c0 * 16384, w1, b1, bp2, b2, buf2H);
    conv_mfma_k<64, 128, 32, 4><<<dim3(8, 1, chunk), 256, 0, stream>>>(
        buf2H, bp3, b3, buf3H);
    conv_mfma_k<128, 128, 16, 4, false><<<dim3(4, 1, chunk), 256, 0, stream>>>(
        buf3H, bp4, b4, buf4H);
    meanfc_k<<<chunk, 128, 0, stream>>>(buf4H, fc_cnn_w, fc_cnn_b, feats, c0);
  }

  wh_k<<<1216, 64, 0, stream>>>(feats, att_W, att_a, Wh, f1, f2);
  gat1_k<<<8, 256, 0, stream>>>(f1, f2, adj, Wh, feats, sfc_w, sfc_b, out, xb);
  wh2_k<<<152, 128, 0, stream>>>(xb, out_W, out_a, Wh2, o1, o2);
  final_k<<<8, 256, 0, stream>>>(adj, o1, o2, Wh2, ll_w, ll_b, fc_w, fc_b, out);
}